// Round 1
// baseline (12005.788 us; speedup 1.0000x reference)
//
#include <hip/hip_runtime.h>
#include <math.h>

#define NTOK 12544
#define DIM 768
#define HID 3072

// ---------------------------------------------------------------- reductions
__device__ __forceinline__ float block_reduce_sum(float v, float* red) {
    int lane = threadIdx.x & 63;
    int wid  = threadIdx.x >> 6;
    #pragma unroll
    for (int o = 32; o > 0; o >>= 1) v += __shfl_down(v, o, 64);
    if (lane == 0) red[wid] = v;
    __syncthreads();
    float s = red[0] + red[1] + red[2] + red[3];
    __syncthreads();
    return s;
}

// ---------------------------------------------------------------- LayerNorm
__global__ void ln_kernel(const float* __restrict__ x, const float* __restrict__ g,
                          const float* __restrict__ b, float* __restrict__ xn) {
    __shared__ float red[4];
    int t = blockIdx.x;
    const float* xr = x + (size_t)t * DIM;
    float*       xo = xn + (size_t)t * DIM;
    int tid = threadIdx.x;
    float v[3];
    #pragma unroll
    for (int i = 0; i < 3; ++i) v[i] = xr[tid + 256 * i];
    float s = v[0] + v[1] + v[2];
    s = block_reduce_sum(s, red);
    float mean = s * (1.0f / 768.0f);
    float sq = 0.0f;
    #pragma unroll
    for (int i = 0; i < 3; ++i) { float d = v[i] - mean; sq += d * d; }
    sq = block_reduce_sum(sq, red);
    float rstd = rsqrtf(sq * (1.0f / 768.0f) + 1e-5f);
    #pragma unroll
    for (int i = 0; i < 3; ++i) {
        int c = tid + 256 * i;
        xo[c] = (v[i] - mean) * rstd * g[c] + b[c];
    }
}

// ---------------------------------------------------------------- Router
// one wave per token: 6 dot products of length 768, softmax + top-2
__global__ void router_kernel(const float* __restrict__ xn,
                              const float* __restrict__ srw, const float* __restrict__ srb,
                              const float* __restrict__ shw, const float* __restrict__ shb,
                              float* __restrict__ spec_logits, float* __restrict__ spec_probs,
                              float* __restrict__ topk_idx, float* __restrict__ topk_probs,
                              float* __restrict__ sh_logits, float* __restrict__ sh_probs,
                              float* __restrict__ gates) {
    int t = blockIdx.x * 4 + (threadIdx.x >> 6);
    int lane = threadIdx.x & 63;
    const float* xr = xn + (size_t)t * DIM;
    float acc[6] = {0, 0, 0, 0, 0, 0};
    #pragma unroll 4
    for (int i = 0; i < 12; ++i) {
        int d = lane + 64 * i;
        float xv = xr[d];
        #pragma unroll
        for (int j = 0; j < 4; ++j) acc[j] += xv * srw[d * 4 + j];
        #pragma unroll
        for (int j = 0; j < 2; ++j) acc[4 + j] += xv * shw[d * 2 + j];
    }
    #pragma unroll
    for (int j = 0; j < 6; ++j) {
        #pragma unroll
        for (int o = 32; o > 0; o >>= 1) acc[j] += __shfl_down(acc[j], o, 64);
    }
    if (lane == 0) {
        float l[4];
        #pragma unroll
        for (int j = 0; j < 4; ++j) l[j] = acc[j] + srb[j];
        float m = fmaxf(fmaxf(l[0], l[1]), fmaxf(l[2], l[3]));
        float e[4], ssum = 0.0f;
        #pragma unroll
        for (int j = 0; j < 4; ++j) { e[j] = expf(l[j] - m); ssum += e[j]; }
        float inv = 1.0f / ssum;
        float p[4];
        #pragma unroll
        for (int j = 0; j < 4; ++j) p[j] = e[j] * inv;
        // top-2, ties -> lower index (strict >)
        int i0 = 0;
        for (int j = 1; j < 4; ++j) if (p[j] > p[i0]) i0 = j;
        int i1 = -1;
        for (int j = 0; j < 4; ++j) {
            if (j == i0) continue;
            if (i1 < 0 || p[j] > p[i1]) i1 = j;
        }
        float sl[2];
        sl[0] = acc[4] + shb[0];
        sl[1] = acc[5] + shb[1];
        float sm = fmaxf(sl[0], sl[1]);
        float se0 = expf(sl[0] - sm), se1 = expf(sl[1] - sm);
        float sinv = 1.0f / (se0 + se1);
        float sp0 = se0 * sinv, sp1 = se1 * sinv;

        #pragma unroll
        for (int j = 0; j < 4; ++j) {
            spec_logits[t * 4 + j] = l[j];
            spec_probs[t * 4 + j]  = p[j];
        }
        topk_idx[t * 2 + 0]   = (float)i0;
        topk_idx[t * 2 + 1]   = (float)i1;
        topk_probs[t * 2 + 0] = p[i0];
        topk_probs[t * 2 + 1] = p[i1];
        sh_logits[t * 2 + 0]  = sl[0];
        sh_logits[t * 2 + 1]  = sl[1];
        sh_probs[t * 2 + 0]   = sp0;
        sh_probs[t * 2 + 1]   = sp1;
        float gg[6] = {0, 0, 0, 0, sp0, sp1};
        gg[i0] = p[i0];
        gg[i1] = p[i1];
        #pragma unroll
        for (int j = 0; j < 6; ++j) gates[t * 6 + j] = gg[j];
    }
}

// ---------------------------------------------------------------- GEMM 1: H = gelu(xn @ w1 + b1)
// A [M x K] row-major, B [K x N] row-major. BM=BN=128, BK=8, 256 thr, 8x8 micro.
__global__ __launch_bounds__(256) void gemm_gelu_kernel(
    const float* __restrict__ A, const float* __restrict__ B,
    const float* __restrict__ bias, float* __restrict__ C,
    int M, int N, int K) {
    __shared__ float As[8][128];
    __shared__ float Bs[8][128];
    int tid = threadIdx.x;
    int bx = blockIdx.x, by = blockIdx.y;
    int arow = tid >> 1, acol = (tid & 1) * 4;
    int brow = tid >> 5, bcol = (tid & 31) * 4;
    const float* Ag = A + (size_t)(by * 128 + arow) * K + acol;
    const float* Bg = B + (size_t)brow * N + bx * 128 + bcol;
    int tx = tid & 15, ty = tid >> 4;
    float acc[8][8];
    #pragma unroll
    for (int i = 0; i < 8; ++i)
        #pragma unroll
        for (int j = 0; j < 8; ++j) acc[i][j] = 0.0f;

    for (int k0 = 0; k0 < K; k0 += 8) {
        float4 av = *(const float4*)(Ag + k0);
        float4 bv = *(const float4*)(Bg + (size_t)k0 * N);
        As[acol + 0][arow] = av.x;
        As[acol + 1][arow] = av.y;
        As[acol + 2][arow] = av.z;
        As[acol + 3][arow] = av.w;
        *(float4*)&Bs[brow][bcol] = bv;
        __syncthreads();
        #pragma unroll
        for (int kk = 0; kk < 8; ++kk) {
            float a[8], b[8];
            *(float4*)(a)     = *(const float4*)&As[kk][ty * 8];
            *(float4*)(a + 4) = *(const float4*)&As[kk][ty * 8 + 4];
            *(float4*)(b)     = *(const float4*)&Bs[kk][tx * 8];
            *(float4*)(b + 4) = *(const float4*)&Bs[kk][tx * 8 + 4];
            #pragma unroll
            for (int i = 0; i < 8; ++i)
                #pragma unroll
                for (int j = 0; j < 8; ++j) acc[i][j] += a[i] * b[j];
        }
        __syncthreads();
    }
    int rbase = by * 128 + ty * 8, cbase = bx * 128 + tx * 8;
    float bvals[8];
    #pragma unroll
    for (int j = 0; j < 8; ++j) bvals[j] = bias[cbase + j];
    #pragma unroll
    for (int i = 0; i < 8; ++i) {
        float o[8];
        #pragma unroll
        for (int j = 0; j < 8; ++j) {
            float v = acc[i][j] + bvals[j];
            o[j] = 0.5f * v * (1.0f + erff(v * 0.70710678118654752f));  // exact GELU
        }
        float* Cp = C + (size_t)(rbase + i) * N + cbase;
        *(float4*)(Cp)     = *(const float4*)(o);
        *(float4*)(Cp + 4) = *(const float4*)(o + 4);
    }
}

// ---------------------------------------------------------------- GEMM 2: out (+)= gate * (H @ w2 + b2)
__global__ __launch_bounds__(256) void gemm_out_kernel(
    const float* __restrict__ A, const float* __restrict__ B,
    const float* __restrict__ bias, const float* __restrict__ gates,
    float* __restrict__ out, int M, int N, int K, int gidx, int accum) {
    __shared__ float As[8][128];
    __shared__ float Bs[8][128];
    int tid = threadIdx.x;
    int bx = blockIdx.x, by = blockIdx.y;
    int arow = tid >> 1, acol = (tid & 1) * 4;
    int brow = tid >> 5, bcol = (tid & 31) * 4;
    const float* Ag = A + (size_t)(by * 128 + arow) * K + acol;
    const float* Bg = B + (size_t)brow * N + bx * 128 + bcol;
    int tx = tid & 15, ty = tid >> 4;
    float acc[8][8];
    #pragma unroll
    for (int i = 0; i < 8; ++i)
        #pragma unroll
        for (int j = 0; j < 8; ++j) acc[i][j] = 0.0f;

    for (int k0 = 0; k0 < K; k0 += 8) {
        float4 av = *(const float4*)(Ag + k0);
        float4 bv = *(const float4*)(Bg + (size_t)k0 * N);
        As[acol + 0][arow] = av.x;
        As[acol + 1][arow] = av.y;
        As[acol + 2][arow] = av.z;
        As[acol + 3][arow] = av.w;
        *(float4*)&Bs[brow][bcol] = bv;
        __syncthreads();
        #pragma unroll
        for (int kk = 0; kk < 8; ++kk) {
            float a[8], b[8];
            *(float4*)(a)     = *(const float4*)&As[kk][ty * 8];
            *(float4*)(a + 4) = *(const float4*)&As[kk][ty * 8 + 4];
            *(float4*)(b)     = *(const float4*)&Bs[kk][tx * 8];
            *(float4*)(b + 4) = *(const float4*)&Bs[kk][tx * 8 + 4];
            #pragma unroll
            for (int i = 0; i < 8; ++i)
                #pragma unroll
                for (int j = 0; j < 8; ++j) acc[i][j] += a[i] * b[j];
        }
        __syncthreads();
    }
    int rbase = by * 128 + ty * 8, cbase = bx * 128 + tx * 8;
    float bvals[8];
    #pragma unroll
    for (int j = 0; j < 8; ++j) bvals[j] = bias[cbase + j];
    #pragma unroll
    for (int i = 0; i < 8; ++i) {
        int row = rbase + i;
        float g = gates[(size_t)row * 6 + gidx];
        float* Op = out + (size_t)row * N + cbase;
        if (accum) {
            #pragma unroll
            for (int j = 0; j < 8; ++j) Op[j] += g * (acc[i][j] + bvals[j]);
        } else {
            #pragma unroll
            for (int j = 0; j < 8; ++j) Op[j] = g * (acc[i][j] + bvals[j]);
        }
    }
}

// ---------------------------------------------------------------- launch
extern "C" void kernel_launch(void* const* d_in, const int* in_sizes, int n_in,
                              void* d_out, int out_size, void* d_ws, size_t ws_size,
                              hipStream_t stream) {
    const float* x      = (const float*)d_in[0];
    const float* gamma  = (const float*)d_in[1];
    const float* beta   = (const float*)d_in[2];
    const float* srw    = (const float*)d_in[3];
    const float* srb    = (const float*)d_in[4];
    const float* spec_w1 = (const float*)d_in[5];
    const float* spec_b1 = (const float*)d_in[6];
    const float* spec_w2 = (const float*)d_in[7];
    const float* spec_b2 = (const float*)d_in[8];
    const float* shw    = (const float*)d_in[9];
    const float* shb    = (const float*)d_in[10];
    const float* sh_w1  = (const float*)d_in[11];
    const float* sh_b1  = (const float*)d_in[12];
    const float* sh_w2  = (const float*)d_in[13];
    const float* sh_b2  = (const float*)d_in[14];

    // workspace layout (floats)
    float* xn    = (float*)d_ws;                       // NTOK*DIM   = 9,633,792
    float* gates = xn + (size_t)NTOK * DIM;            // NTOK*6     = 75,264
    float* Hbuf  = gates + (size_t)NTOK * 6;           // NTOK*HID   = 38,535,168

    // d_out layout (flat concat, all f32)
    float* out         = (float*)d_out;
    float* spec_logits = out + (size_t)NTOK * DIM;
    float* spec_probs  = spec_logits + (size_t)NTOK * 4;
    float* topk_idx    = spec_probs  + (size_t)NTOK * 4;
    float* topk_probs  = topk_idx    + (size_t)NTOK * 2;
    float* sh_logits   = topk_probs  + (size_t)NTOK * 2;
    float* sh_probs    = sh_logits   + (size_t)NTOK * 2;

    ln_kernel<<<NTOK, 256, 0, stream>>>(x, gamma, beta, xn);
    router_kernel<<<NTOK / 4, 256, 0, stream>>>(xn, srw, srb, shw, shb,
                                                spec_logits, spec_probs, topk_idx,
                                                topk_probs, sh_logits, sh_probs, gates);

    dim3 block(256);
    dim3 grid1(HID / 128, NTOK / 128);   // 24 x 98
    dim3 grid2(DIM / 128, NTOK / 128);   // 6 x 98
    for (int e = 0; e < 6; ++e) {
        const float *w1p, *b1p, *w2p, *b2p;
        if (e < 4) {
            w1p = spec_w1 + (size_t)e * DIM * HID;
            b1p = spec_b1 + (size_t)e * HID;
            w2p = spec_w2 + (size_t)e * HID * DIM;
            b2p = spec_b2 + (size_t)e * DIM;
        } else {
            int s = e - 4;
            w1p = sh_w1 + (size_t)s * DIM * HID;
            b1p = sh_b1 + (size_t)s * HID;
            w2p = sh_w2 + (size_t)s * HID * DIM;
            b2p = sh_b2 + (size_t)s * DIM;
        }
        gemm_gelu_kernel<<<grid1, block, 0, stream>>>(xn, w1p, b1p, Hbuf, NTOK, HID, DIM);
        gemm_out_kernel<<<grid2, block, 0, stream>>>(Hbuf, w2p, b2p, gates, out,
                                                     NTOK, DIM, HID, e, e > 0);
    }
}

// Round 2
// 1845.854 us; speedup vs baseline: 6.5042x; 6.5042x over previous
//
#include <hip/hip_runtime.h>
#include <hip/hip_bf16.h>
#include <math.h>

#define NTOK 12544
#define DIM 768
#define HID 3072

typedef __hip_bfloat16 bf16;
typedef __attribute__((ext_vector_type(8))) short short8v;
typedef __attribute__((ext_vector_type(4))) float f32x4;

#define GPTR(p)  ((const __attribute__((address_space(1))) void*)(p))
#define LDSPTR(p) ((__attribute__((address_space(3))) void*)(p))

// ---------------------------------------------------------------- reductions
__device__ __forceinline__ float block_reduce_sum(float v, float* red) {
    int lane = threadIdx.x & 63;
    int wid  = threadIdx.x >> 6;
    #pragma unroll
    for (int o = 32; o > 0; o >>= 1) v += __shfl_down(v, o, 64);
    if (lane == 0) red[wid] = v;
    __syncthreads();
    float s = red[0] + red[1] + red[2] + red[3];
    __syncthreads();
    return s;
}

// ---------------------------------------------------------------- LayerNorm (f32 out + bf16 out)
__global__ void ln_kernel(const float* __restrict__ x, const float* __restrict__ g,
                          const float* __restrict__ b, float* __restrict__ xn,
                          bf16* __restrict__ xnb) {
    __shared__ float red[4];
    int t = blockIdx.x;
    const float* xr = x + (size_t)t * DIM;
    float*       xo = xn + (size_t)t * DIM;
    bf16*        xb = xnb + (size_t)t * DIM;
    int tid = threadIdx.x;
    float v[3];
    #pragma unroll
    for (int i = 0; i < 3; ++i) v[i] = xr[tid + 256 * i];
    float s = v[0] + v[1] + v[2];
    s = block_reduce_sum(s, red);
    float mean = s * (1.0f / 768.0f);
    float sq = 0.0f;
    #pragma unroll
    for (int i = 0; i < 3; ++i) { float d = v[i] - mean; sq += d * d; }
    sq = block_reduce_sum(sq, red);
    float rstd = rsqrtf(sq * (1.0f / 768.0f) + 1e-5f);
    #pragma unroll
    for (int i = 0; i < 3; ++i) {
        int c = tid + 256 * i;
        float o = (v[i] - mean) * rstd * g[c] + b[c];
        xo[c] = o;
        xb[c] = __float2bfloat16(o);
    }
}

// ---------------------------------------------------------------- Router (unchanged, f32)
__global__ void router_kernel(const float* __restrict__ xn,
                              const float* __restrict__ srw, const float* __restrict__ srb,
                              const float* __restrict__ shw, const float* __restrict__ shb,
                              float* __restrict__ spec_logits, float* __restrict__ spec_probs,
                              float* __restrict__ topk_idx, float* __restrict__ topk_probs,
                              float* __restrict__ sh_logits, float* __restrict__ sh_probs,
                              float* __restrict__ gates) {
    int t = blockIdx.x * 4 + (threadIdx.x >> 6);
    int lane = threadIdx.x & 63;
    const float* xr = xn + (size_t)t * DIM;
    float acc[6] = {0, 0, 0, 0, 0, 0};
    #pragma unroll 4
    for (int i = 0; i < 12; ++i) {
        int d = lane + 64 * i;
        float xv = xr[d];
        #pragma unroll
        for (int j = 0; j < 4; ++j) acc[j] += xv * srw[d * 4 + j];
        #pragma unroll
        for (int j = 0; j < 2; ++j) acc[4 + j] += xv * shw[d * 2 + j];
    }
    #pragma unroll
    for (int j = 0; j < 6; ++j) {
        #pragma unroll
        for (int o = 32; o > 0; o >>= 1) acc[j] += __shfl_down(acc[j], o, 64);
    }
    if (lane == 0) {
        float l[4];
        #pragma unroll
        for (int j = 0; j < 4; ++j) l[j] = acc[j] + srb[j];
        float m = fmaxf(fmaxf(l[0], l[1]), fmaxf(l[2], l[3]));
        float e[4], ssum = 0.0f;
        #pragma unroll
        for (int j = 0; j < 4; ++j) { e[j] = expf(l[j] - m); ssum += e[j]; }
        float inv = 1.0f / ssum;
        float p[4];
        #pragma unroll
        for (int j = 0; j < 4; ++j) p[j] = e[j] * inv;
        int i0 = 0;
        for (int j = 1; j < 4; ++j) if (p[j] > p[i0]) i0 = j;
        int i1 = -1;
        for (int j = 0; j < 4; ++j) {
            if (j == i0) continue;
            if (i1 < 0 || p[j] > p[i1]) i1 = j;
        }
        float sl[2];
        sl[0] = acc[4] + shb[0];
        sl[1] = acc[5] + shb[1];
        float sm = fmaxf(sl[0], sl[1]);
        float se0 = expf(sl[0] - sm), se1 = expf(sl[1] - sm);
        float sinv = 1.0f / (se0 + se1);
        float sp0 = se0 * sinv, sp1 = se1 * sinv;

        #pragma unroll
        for (int j = 0; j < 4; ++j) {
            spec_logits[t * 4 + j] = l[j];
            spec_probs[t * 4 + j]  = p[j];
        }
        topk_idx[t * 2 + 0]   = (float)i0;
        topk_idx[t * 2 + 1]   = (float)i1;
        topk_probs[t * 2 + 0] = p[i0];
        topk_probs[t * 2 + 1] = p[i1];
        sh_logits[t * 2 + 0]  = sl[0];
        sh_logits[t * 2 + 1]  = sl[1];
        sh_probs[t * 2 + 0]   = sp0;
        sh_probs[t * 2 + 1]   = sp1;
        float gg[6] = {0, 0, 0, 0, sp0, sp1};
        gg[i0] = p[i0];
        gg[i1] = p[i1];
        #pragma unroll
        for (int j = 0; j < 6; ++j) gates[t * 6 + j] = gg[j];
    }
}

// ---------------------------------------------------------------- transpose + f32->bf16
// in: [R][C] f32 (matrix blockIdx.z), out: [C][R] bf16
__global__ __launch_bounds__(256) void conv_t_kernel(const float* __restrict__ in,
                                                     bf16* __restrict__ out, int R, int C) {
    __shared__ float tile[32][33];
    const float* ip = in + (size_t)blockIdx.z * R * C;
    bf16* op = out + (size_t)blockIdx.z * R * C;
    int r0 = blockIdx.y * 32, c0 = blockIdx.x * 32;
    int tx = threadIdx.x & 31, ty = threadIdx.x >> 5;   // 32 x 8
    #pragma unroll
    for (int i = 0; i < 32; i += 8)
        tile[ty + i][tx] = ip[(size_t)(r0 + ty + i) * C + c0 + tx];
    __syncthreads();
    #pragma unroll
    for (int i = 0; i < 32; i += 8)
        op[(size_t)(c0 + ty + i) * R + r0 + tx] = __float2bfloat16(tile[tx][ty + i]);
}

// ---------------------------------------------------------------- MFMA GEMM (m97 structure)
// A [M][K] bf16 row-major, BT [N][K] bf16 row-major. 128x128 tile, BK=32,
// 256 thr = 4 waves (2x2), 64x64 per wave, global_load_lds width 16.
__device__ __forceinline__ void stage_tile(const bf16* __restrict__ g, int ldg,
                                           bf16* lds, int tid) {
    int wave = tid >> 6, lane = tid & 63;
    #pragma unroll
    for (int q = 0; q < 2; ++q) {
        int chunk = wave * 2 + q;                 // 8 chunks of 16 rows
        int row = chunk * 16 + (lane >> 2);
        int col = (lane & 3) * 8;
        __builtin_amdgcn_global_load_lds(GPTR(g + (size_t)row * ldg + col),
                                         LDSPTR(lds + chunk * 512), 16, 0, 0);
    }
}

__global__ __launch_bounds__(256) void gemm_gelu_bf16(
    const bf16* __restrict__ A, const bf16* __restrict__ BT,
    const float* __restrict__ bias, bf16* __restrict__ H, int M, int N, int K) {
    __shared__ bf16 As[128 * 32];
    __shared__ bf16 Bs[128 * 32];
    int tid = threadIdx.x;
    int wid = tid >> 6, lane = tid & 63;
    int wr = wid >> 1, wc = wid & 1;
    int fr = lane & 15, fq = lane >> 4;
    const bf16* Ag = A + (size_t)(blockIdx.y * 128) * K;
    const bf16* Bg = BT + (size_t)(blockIdx.x * 128) * K;
    f32x4 acc[4][4] = {};

    for (int k0 = 0; k0 < K; k0 += 32) {
        stage_tile(Ag + k0, K, As, tid);
        stage_tile(Bg + k0, K, Bs, tid);
        __syncthreads();
        short8v a[4], b[4];
        #pragma unroll
        for (int i = 0; i < 4; ++i) {
            a[i] = *(const short8v*)&As[(wr * 64 + i * 16 + fr) * 32 + fq * 8];
            b[i] = *(const short8v*)&Bs[(wc * 64 + i * 16 + fr) * 32 + fq * 8];
        }
        #pragma unroll
        for (int i = 0; i < 4; ++i)
            #pragma unroll
            for (int j = 0; j < 4; ++j)
                acc[i][j] = __builtin_amdgcn_mfma_f32_16x16x32_bf16(a[i], b[j], acc[i][j], 0, 0, 0);
        __syncthreads();
    }

    int rbase = blockIdx.y * 128 + wr * 64;
    int cbase = blockIdx.x * 128 + wc * 64;
    #pragma unroll
    for (int j = 0; j < 4; ++j) {
        int col = cbase + j * 16 + fr;
        float bv = bias[col];
        #pragma unroll
        for (int i = 0; i < 4; ++i) {
            #pragma unroll
            for (int r = 0; r < 4; ++r) {
                int row = rbase + i * 16 + fq * 4 + r;
                float v = acc[i][j][r] + bv;
                v = 0.5f * v * (1.0f + erff(v * 0.70710678118654752f));
                H[(size_t)row * N + col] = __float2bfloat16(v);
            }
        }
    }
}

__global__ __launch_bounds__(256) void gemm_out_bf16(
    const bf16* __restrict__ A, const bf16* __restrict__ BT,
    const float* __restrict__ bias, const float* __restrict__ gates,
    float* __restrict__ out, int M, int N, int K, int gidx, int accum) {
    __shared__ bf16 As[128 * 32];
    __shared__ bf16 Bs[128 * 32];
    int tid = threadIdx.x;
    int wid = tid >> 6, lane = tid & 63;
    int wr = wid >> 1, wc = wid & 1;
    int fr = lane & 15, fq = lane >> 4;
    const bf16* Ag = A + (size_t)(blockIdx.y * 128) * K;
    const bf16* Bg = BT + (size_t)(blockIdx.x * 128) * K;
    f32x4 acc[4][4] = {};

    for (int k0 = 0; k0 < K; k0 += 32) {
        stage_tile(Ag + k0, K, As, tid);
        stage_tile(Bg + k0, K, Bs, tid);
        __syncthreads();
        short8v a[4], b[4];
        #pragma unroll
        for (int i = 0; i < 4; ++i) {
            a[i] = *(const short8v*)&As[(wr * 64 + i * 16 + fr) * 32 + fq * 8];
            b[i] = *(const short8v*)&Bs[(wc * 64 + i * 16 + fr) * 32 + fq * 8];
        }
        #pragma unroll
        for (int i = 0; i < 4; ++i)
            #pragma unroll
            for (int j = 0; j < 4; ++j)
                acc[i][j] = __builtin_amdgcn_mfma_f32_16x16x32_bf16(a[i], b[j], acc[i][j], 0, 0, 0);
        __syncthreads();
    }

    int rbase = blockIdx.y * 128 + wr * 64;
    int cbase = blockIdx.x * 128 + wc * 64;
    #pragma unroll
    for (int j = 0; j < 4; ++j) {
        int col = cbase + j * 16 + fr;
        float bv = bias[col];
        #pragma unroll
        for (int i = 0; i < 4; ++i) {
            #pragma unroll
            for (int r = 0; r < 4; ++r) {
                int row = rbase + i * 16 + fq * 4 + r;
                float g = gates[(size_t)row * 6 + gidx];
                float v = g * (acc[i][j][r] + bv);
                size_t idx = (size_t)row * N + col;
                out[idx] = accum ? out[idx] + v : v;
            }
        }
    }
}

// ---------------------------------------------------------------- launch
extern "C" void kernel_launch(void* const* d_in, const int* in_sizes, int n_in,
                              void* d_out, int out_size, void* d_ws, size_t ws_size,
                              hipStream_t stream) {
    const float* x      = (const float*)d_in[0];
    const float* gamma  = (const float*)d_in[1];
    const float* beta   = (const float*)d_in[2];
    const float* srw    = (const float*)d_in[3];
    const float* srb    = (const float*)d_in[4];
    const float* spec_w1 = (const float*)d_in[5];
    const float* spec_b1 = (const float*)d_in[6];
    const float* spec_w2 = (const float*)d_in[7];
    const float* spec_b2 = (const float*)d_in[8];
    const float* shw    = (const float*)d_in[9];
    const float* shb    = (const float*)d_in[10];
    const float* sh_w1  = (const float*)d_in[11];
    const float* sh_b1  = (const float*)d_in[12];
    const float* sh_w2  = (const float*)d_in[13];
    const float* sh_b2  = (const float*)d_in[14];

    // workspace layout
    float* xn    = (float*)d_ws;                            // NTOK*DIM f32
    float* gates = xn + (size_t)NTOK * DIM;                 // NTOK*6 f32
    bf16*  xnb   = (bf16*)(gates + (size_t)NTOK * 6);       // NTOK*DIM bf16
    bf16*  Hbf   = xnb + (size_t)NTOK * DIM;                // NTOK*HID bf16
    bf16*  w1t   = Hbf + (size_t)NTOK * HID;                // 6*HID*DIM bf16
    bf16*  w2t   = w1t + (size_t)6 * HID * DIM;             // 6*DIM*HID bf16

    // d_out layout (flat concat, all f32)
    float* out         = (float*)d_out;
    float* spec_logits = out + (size_t)NTOK * DIM;
    float* spec_probs  = spec_logits + (size_t)NTOK * 4;
    float* topk_idx    = spec_probs  + (size_t)NTOK * 4;
    float* topk_probs  = topk_idx    + (size_t)NTOK * 2;
    float* sh_logits   = topk_probs  + (size_t)NTOK * 2;
    float* sh_probs    = sh_logits   + (size_t)NTOK * 2;

    // weight transpose+convert: w1 [e][DIM][HID] -> w1t [e][HID][DIM]
    conv_t_kernel<<<dim3(HID / 32, DIM / 32, 4), 256, 0, stream>>>(spec_w1, w1t, DIM, HID);
    conv_t_kernel<<<dim3(HID / 32, DIM / 32, 2), 256, 0, stream>>>(sh_w1, w1t + (size_t)4 * HID * DIM, DIM, HID);
    // w2 [e][HID][DIM] -> w2t [e][DIM][HID]
    conv_t_kernel<<<dim3(DIM / 32, HID / 32, 4), 256, 0, stream>>>(spec_w2, w2t, HID, DIM);
    conv_t_kernel<<<dim3(DIM / 32, HID / 32, 2), 256, 0, stream>>>(sh_w2, w2t + (size_t)4 * DIM * HID, HID, DIM);

    ln_kernel<<<NTOK, 256, 0, stream>>>(x, gamma, beta, xn, xnb);
    router_kernel<<<NTOK / 4, 256, 0, stream>>>(xn, srw, srb, shw, shb,
                                                spec_logits, spec_probs, topk_idx,
                                                topk_probs, sh_logits, sh_probs, gates);

    dim3 block(256);
    dim3 grid1(HID / 128, NTOK / 128);   // 24 x 98
    dim3 grid2(DIM / 128, NTOK / 128);   // 6 x 98
    for (int e = 0; e < 6; ++e) {
        const bf16* w1p = w1t + (size_t)e * HID * DIM;
        const bf16* w2p = w2t + (size_t)e * DIM * HID;
        const float* b1p = (e < 4) ? spec_b1 + (size_t)e * HID : sh_b1 + (size_t)(e - 4) * HID;
        const float* b2p = (e < 4) ? spec_b2 + (size_t)e * DIM : sh_b2 + (size_t)(e - 4) * DIM;
        gemm_gelu_bf16<<<grid1, block, 0, stream>>>(xnb, w1p, b1p, Hbf, NTOK, HID, DIM);
        gemm_out_bf16<<<grid2, block, 0, stream>>>(Hbf, w2p, b2p, gates, out,
                                                   NTOK, DIM, HID, e, e > 0);
    }
}

// Round 3
// 1727.899 us; speedup vs baseline: 6.9482x; 1.0683x over previous
//
#include <hip/hip_runtime.h>
#include <hip/hip_bf16.h>
#include <math.h>

#define NTOK 12544
#define DIM 768
#define HID 3072
#define NSLOT_MAX 25600     // 2*NTOK + 4*127 rounded up to 128
#define NTILE_MAX 200       // NSLOT_MAX/128

typedef __hip_bfloat16 bf16;
typedef __attribute__((ext_vector_type(8))) short short8v;
typedef __attribute__((ext_vector_type(4))) float f32x4;

#define GPTR(p)  ((const __attribute__((address_space(1))) void*)(p))
#define LDSPTR(p) ((__attribute__((address_space(3))) void*)(p))

// ---------------------------------------------------------------- LayerNorm -> bf16
__global__ void ln_kernel(const float* __restrict__ x, const float* __restrict__ g,
                          const float* __restrict__ b, bf16* __restrict__ xnb) {
    __shared__ float red[4];
    int t = blockIdx.x;
    const float* xr = x + (size_t)t * DIM;
    bf16*        xb = xnb + (size_t)t * DIM;
    int tid = threadIdx.x, lane = tid & 63, wid = tid >> 6;
    float v[3];
    #pragma unroll
    for (int i = 0; i < 3; ++i) v[i] = xr[tid + 256 * i];
    float s = v[0] + v[1] + v[2];
    #pragma unroll
    for (int o = 32; o > 0; o >>= 1) s += __shfl_down(s, o, 64);
    if (lane == 0) red[wid] = s;
    __syncthreads();
    s = red[0] + red[1] + red[2] + red[3];
    __syncthreads();
    float mean = s * (1.0f / 768.0f);
    float sq = 0.0f;
    #pragma unroll
    for (int i = 0; i < 3; ++i) { float d = v[i] - mean; sq += d * d; }
    #pragma unroll
    for (int o = 32; o > 0; o >>= 1) sq += __shfl_down(sq, o, 64);
    if (lane == 0) red[wid] = sq;
    __syncthreads();
    sq = red[0] + red[1] + red[2] + red[3];
    float rstd = rsqrtf(sq * (1.0f / 768.0f) + 1e-5f);
    #pragma unroll
    for (int i = 0; i < 3; ++i) {
        int c = tid + 256 * i;
        xb[c] = __float2bfloat16((v[i] - mean) * rstd * g[c] + b[c]);
    }
}

// ---------------------------------------------------------------- Router (own f32 LN) + routing lists
__global__ void router_kernel(const float* __restrict__ x,
                              const float* __restrict__ lng, const float* __restrict__ lnb,
                              const float* __restrict__ srw, const float* __restrict__ srb,
                              const float* __restrict__ shw, const float* __restrict__ shb,
                              float* __restrict__ spec_logits, float* __restrict__ spec_probs,
                              float* __restrict__ topk_idx, float* __restrict__ topk_probs,
                              float* __restrict__ sh_logits, float* __restrict__ sh_probs,
                              float* __restrict__ gates,
                              int* __restrict__ cnt, int* __restrict__ tok_of,
                              float* __restrict__ gate_of) {
    int t = blockIdx.x * 4 + (threadIdx.x >> 6);
    int lane = threadIdx.x & 63;
    const float* xr = x + (size_t)t * DIM;
    float v[12];
    float s = 0.0f;
    #pragma unroll
    for (int i = 0; i < 12; ++i) { v[i] = xr[lane + 64 * i]; s += v[i]; }
    #pragma unroll
    for (int o = 32; o > 0; o >>= 1) s += __shfl_xor(s, o, 64);
    float mean = s * (1.0f / 768.0f);
    float sq = 0.0f;
    #pragma unroll
    for (int i = 0; i < 12; ++i) { float d = v[i] - mean; sq += d * d; }
    #pragma unroll
    for (int o = 32; o > 0; o >>= 1) sq += __shfl_xor(sq, o, 64);
    float rstd = rsqrtf(sq * (1.0f / 768.0f) + 1e-5f);

    float acc[6] = {0, 0, 0, 0, 0, 0};
    #pragma unroll 4
    for (int i = 0; i < 12; ++i) {
        int d = lane + 64 * i;
        float xv = (v[i] - mean) * rstd * lng[d] + lnb[d];
        #pragma unroll
        for (int j = 0; j < 4; ++j) acc[j] += xv * srw[d * 4 + j];
        #pragma unroll
        for (int j = 0; j < 2; ++j) acc[4 + j] += xv * shw[d * 2 + j];
    }
    #pragma unroll
    for (int j = 0; j < 6; ++j) {
        #pragma unroll
        for (int o = 32; o > 0; o >>= 1) acc[j] += __shfl_xor(acc[j], o, 64);
    }
    if (lane == 0) {
        float l[4];
        #pragma unroll
        for (int j = 0; j < 4; ++j) l[j] = acc[j] + srb[j];
        float m = fmaxf(fmaxf(l[0], l[1]), fmaxf(l[2], l[3]));
        float e[4], ssum = 0.0f;
        #pragma unroll
        for (int j = 0; j < 4; ++j) { e[j] = expf(l[j] - m); ssum += e[j]; }
        float inv = 1.0f / ssum;
        float p[4];
        #pragma unroll
        for (int j = 0; j < 4; ++j) p[j] = e[j] * inv;
        int i0 = 0;
        for (int j = 1; j < 4; ++j) if (p[j] > p[i0]) i0 = j;
        int i1 = -1;
        for (int j = 0; j < 4; ++j) {
            if (j == i0) continue;
            if (i1 < 0 || p[j] > p[i1]) i1 = j;
        }
        float sl0 = acc[4] + shb[0], sl1 = acc[5] + shb[1];
        float sm = fmaxf(sl0, sl1);
        float se0 = expf(sl0 - sm), se1 = expf(sl1 - sm);
        float sinv = 1.0f / (se0 + se1);
        float sp0 = se0 * sinv, sp1 = se1 * sinv;

        #pragma unroll
        for (int j = 0; j < 4; ++j) {
            spec_logits[t * 4 + j] = l[j];
            spec_probs[t * 4 + j]  = p[j];
        }
        topk_idx[t * 2 + 0]   = (float)i0;
        topk_idx[t * 2 + 1]   = (float)i1;
        topk_probs[t * 2 + 0] = p[i0];
        topk_probs[t * 2 + 1] = p[i1];
        sh_logits[t * 2 + 0]  = sl0;
        sh_logits[t * 2 + 1]  = sl1;
        sh_probs[t * 2 + 0]   = sp0;
        sh_probs[t * 2 + 1]   = sp1;
        float gg[6] = {0, 0, 0, 0, sp0, sp1};
        gg[i0] = p[i0];
        gg[i1] = p[i1];
        #pragma unroll
        for (int j = 0; j < 6; ++j) gates[t * 6 + j] = gg[j];
        // routing lists (order within expert is irrelevant to final values)
        int pos0 = atomicAdd(&cnt[i0], 1);
        tok_of[i0 * NTOK + pos0] = t * 2 + 0;
        gate_of[i0 * NTOK + pos0] = p[i0];
        int pos1 = atomicAdd(&cnt[i1], 1);
        tok_of[i1 * NTOK + pos1] = t * 2 + 1;
        gate_of[i1 * NTOK + pos1] = p[i1];
    }
}

// ---------------------------------------------------------------- plan: offsets, tiles, slot fill
__global__ void plan_kernel(const int* __restrict__ cnt, int* __restrict__ e_of_tile,
                            const int* __restrict__ tok_of, const float* __restrict__ gate_of,
                            int* __restrict__ slot_tok, float* __restrict__ slot_gate,
                            int* __restrict__ back) {
    __shared__ int offs[5];
    int tid = threadIdx.x;
    if (tid == 0) {
        int o = 0;
        for (int e = 0; e < 4; ++e) { offs[e] = o; o += (cnt[e] + 127) & ~127; }
        offs[4] = o;
    }
    __syncthreads();
    for (int idx = tid; idx < NTILE_MAX; idx += 256) {
        int s = idx * 128, e = -1;
        for (int j = 0; j < 4; ++j)
            if (s >= offs[j] && s < offs[j + 1]) e = j;
        e_of_tile[idx] = e;
    }
    for (int e = 0; e < 4; ++e) {
        int c = cnt[e];
        int padded = (c + 127) & ~127;
        for (int i = tid; i < padded; i += 256) {
            int gs = offs[e] + i;
            if (i < c) {
                int tk = tok_of[e * NTOK + i];
                slot_tok[gs] = tk >> 1;
                slot_gate[gs] = gate_of[e * NTOK + i];
                back[tk] = gs;
            } else {
                slot_tok[gs] = 0;
                slot_gate[gs] = 0.0f;
            }
        }
    }
}

// ---------------------------------------------------------------- transpose + f32->bf16
__global__ __launch_bounds__(256) void conv_t_kernel(const float* __restrict__ in,
                                                     bf16* __restrict__ out, int R, int C) {
    __shared__ float tile[32][33];
    const float* ip = in + (size_t)blockIdx.z * R * C;
    bf16* op = out + (size_t)blockIdx.z * R * C;
    int r0 = blockIdx.y * 32, c0 = blockIdx.x * 32;
    int tx = threadIdx.x & 31, ty = threadIdx.x >> 5;
    #pragma unroll
    for (int i = 0; i < 32; i += 8)
        tile[ty + i][tx] = ip[(size_t)(r0 + ty + i) * C + c0 + tx];
    __syncthreads();
    #pragma unroll
    for (int i = 0; i < 32; i += 8)
        op[(size_t)(c0 + ty + i) * R + r0 + tx] = __float2bfloat16(tile[tx][ty + i]);
}

// ---------------------------------------------------------------- MFMA helpers
__device__ __forceinline__ void stage_tile(const bf16* __restrict__ g, int ldg,
                                           bf16* lds, int tid) {
    int wave = tid >> 6, lane = tid & 63;
    #pragma unroll
    for (int q = 0; q < 2; ++q) {
        int chunk = wave * 2 + q;
        int row = chunk * 16 + (lane >> 2);
        int col = (lane & 3) * 8;
        __builtin_amdgcn_global_load_lds(GPTR(g + (size_t)row * ldg + col),
                                         LDSPTR(lds + chunk * 512), 16, 0, 0);
    }
}

__device__ __forceinline__ void mfma_step(const bf16* As, const bf16* Bs,
                                          int wr, int wc, int fr, int fq, f32x4 acc[4][4]) {
    short8v a[4], b[4];
    #pragma unroll
    for (int i = 0; i < 4; ++i) {
        a[i] = *(const short8v*)&As[(wr * 64 + i * 16 + fr) * 32 + fq * 8];
        b[i] = *(const short8v*)&Bs[(wc * 64 + i * 16 + fr) * 32 + fq * 8];
    }
    #pragma unroll
    for (int i = 0; i < 4; ++i)
        #pragma unroll
        for (int j = 0; j < 4; ++j)
            acc[i][j] = __builtin_amdgcn_mfma_f32_16x16x32_bf16(a[i], b[j], acc[i][j], 0, 0, 0);
}

__device__ __forceinline__ float gelu_exact(float v) {
    return 0.5f * v * (1.0f + erff(v * 0.70710678118654752f));
}

// ---------------------------------------------------------------- GEMM1 grouped (specific experts)
__global__ __launch_bounds__(256) void gemm1_grouped(
    const bf16* __restrict__ xnb, const bf16* __restrict__ w1t,
    const float* __restrict__ b1, const int* __restrict__ e_of_tile,
    const int* __restrict__ slot_tok, bf16* __restrict__ H) {
    int rt = blockIdx.y;
    int e = e_of_tile[rt];
    if (e < 0) return;
    __shared__ bf16 As[128 * 32];
    __shared__ bf16 Bs[128 * 32];
    int tid = threadIdx.x;
    int wid = tid >> 6, lane = tid & 63;
    int wr = wid >> 1, wc = wid & 1;
    int fr = lane & 15, fq = lane >> 4;
    // per-lane gathered A source pointers
    const bf16* asrc[2];
    #pragma unroll
    for (int q = 0; q < 2; ++q) {
        int chunk = wid * 2 + q;
        int r = chunk * 16 + (lane >> 2);
        int tok = slot_tok[rt * 128 + r];
        asrc[q] = xnb + (size_t)tok * DIM + (lane & 3) * 8;
    }
    const bf16* Bg = w1t + (size_t)e * HID * DIM + (size_t)(blockIdx.x * 128) * DIM;
    const float* bias = b1 + (e < 4 ? 0 : 0);  // b1 already offset per expert set by caller arrays
    f32x4 acc[4][4] = {};
    for (int k0 = 0; k0 < DIM; k0 += 32) {
        #pragma unroll
        for (int q = 0; q < 2; ++q)
            __builtin_amdgcn_global_load_lds(GPTR(asrc[q] + k0),
                                             LDSPTR(As + (wid * 2 + q) * 512), 16, 0, 0);
        stage_tile(Bg + k0, DIM, Bs, tid);
        __syncthreads();
        mfma_step(As, Bs, wr, wc, fr, fq, acc);
        __syncthreads();
    }
    const float* b1e = b1 + (size_t)e * HID;
    int rbase = rt * 128 + wr * 64;
    int cbase = blockIdx.x * 128 + wc * 64;
    #pragma unroll
    for (int j = 0; j < 4; ++j) {
        int col = cbase + j * 16 + fr;
        float bv = b1e[col];
        #pragma unroll
        for (int i = 0; i < 4; ++i)
            #pragma unroll
            for (int r = 0; r < 4; ++r) {
                int row = rbase + i * 16 + fq * 4 + r;
                H[(size_t)row * HID + col] = __float2bfloat16(gelu_exact(acc[i][j][r] + bv));
            }
    }
}

// ---------------------------------------------------------------- GEMM2 grouped -> gathered bf16 partials
__global__ __launch_bounds__(256) void gemm2_grouped(
    const bf16* __restrict__ H, const bf16* __restrict__ w2t,
    const float* __restrict__ b2, const int* __restrict__ e_of_tile,
    const float* __restrict__ slot_gate, bf16* __restrict__ outg) {
    int rt = blockIdx.y;
    int e = e_of_tile[rt];
    if (e < 0) return;
    __shared__ bf16 As[128 * 32];
    __shared__ bf16 Bs[128 * 32];
    int tid = threadIdx.x;
    int wid = tid >> 6, lane = tid & 63;
    int wr = wid >> 1, wc = wid & 1;
    int fr = lane & 15, fq = lane >> 4;
    const bf16* Ag = H + (size_t)(rt * 128) * HID;
    const bf16* Bg = w2t + (size_t)e * DIM * HID + (size_t)(blockIdx.x * 128) * HID;
    f32x4 acc[4][4] = {};
    for (int k0 = 0; k0 < HID; k0 += 32) {
        stage_tile(Ag + k0, HID, As, tid);
        stage_tile(Bg + k0, HID, Bs, tid);
        __syncthreads();
        mfma_step(As, Bs, wr, wc, fr, fq, acc);
        __syncthreads();
    }
    const float* b2e = b2 + (size_t)e * DIM;
    int rbase = rt * 128 + wr * 64;
    int cbase = blockIdx.x * 128 + wc * 64;
    #pragma unroll
    for (int j = 0; j < 4; ++j) {
        int col = cbase + j * 16 + fr;
        float bv = b2e[col];
        #pragma unroll
        for (int i = 0; i < 4; ++i)
            #pragma unroll
            for (int r = 0; r < 4; ++r) {
                int row = rbase + i * 16 + fq * 4 + r;
                float g = slot_gate[row];
                outg[(size_t)row * DIM + col] = __float2bfloat16(g * (acc[i][j][r] + bv));
            }
    }
}

// ---------------------------------------------------------------- GEMM1 dense (z = expert offset)
__global__ __launch_bounds__(256) void gemm1_dense(
    const bf16* __restrict__ A, const bf16* __restrict__ w1t_base, size_t w_es,
    const float* __restrict__ b1_base, size_t b_es,
    bf16* __restrict__ H_base, size_t h_es) {
    int z = blockIdx.z;
    __shared__ bf16 As[128 * 32];
    __shared__ bf16 Bs[128 * 32];
    int tid = threadIdx.x;
    int wid = tid >> 6, lane = tid & 63;
    int wr = wid >> 1, wc = wid & 1;
    int fr = lane & 15, fq = lane >> 4;
    const bf16* Ag = A + (size_t)(blockIdx.y * 128) * DIM;
    const bf16* Bg = w1t_base + (size_t)z * w_es + (size_t)(blockIdx.x * 128) * DIM;
    f32x4 acc[4][4] = {};
    for (int k0 = 0; k0 < DIM; k0 += 32) {
        stage_tile(Ag + k0, DIM, As, tid);
        stage_tile(Bg + k0, DIM, Bs, tid);
        __syncthreads();
        mfma_step(As, Bs, wr, wc, fr, fq, acc);
        __syncthreads();
    }
    const float* bias = b1_base + (size_t)z * b_es;
    bf16* H = H_base + (size_t)z * h_es;
    int rbase = blockIdx.y * 128 + wr * 64;
    int cbase = blockIdx.x * 128 + wc * 64;
    #pragma unroll
    for (int j = 0; j < 4; ++j) {
        int col = cbase + j * 16 + fr;
        float bv = bias[col];
        #pragma unroll
        for (int i = 0; i < 4; ++i)
            #pragma unroll
            for (int r = 0; r < 4; ++r) {
                int row = rbase + i * 16 + fq * 4 + r;
                H[(size_t)row * HID + col] = __float2bfloat16(gelu_exact(acc[i][j][r] + bv));
            }
    }
}

// ---------------------------------------------------------------- GEMM2 dense shared -> bf16 partials (z batched)
__global__ __launch_bounds__(256) void gemm2_dense_sh(
    const bf16* __restrict__ H_base, size_t h_es,
    const bf16* __restrict__ w2t_base, size_t w_es,
    const float* __restrict__ b2_base, size_t b_es,
    const float* __restrict__ sh_probs, bf16* __restrict__ outg_base, size_t o_es) {
    int z = blockIdx.z;
    __shared__ bf16 As[128 * 32];
    __shared__ bf16 Bs[128 * 32];
    int tid = threadIdx.x;
    int wid = tid >> 6, lane = tid & 63;
    int wr = wid >> 1, wc = wid & 1;
    int fr = lane & 15, fq = lane >> 4;
    const bf16* Ag = H_base + (size_t)z * h_es + (size_t)(blockIdx.y * 128) * HID;
    const bf16* Bg = w2t_base + (size_t)z * w_es + (size_t)(blockIdx.x * 128) * HID;
    f32x4 acc[4][4] = {};
    for (int k0 = 0; k0 < HID; k0 += 32) {
        stage_tile(Ag + k0, HID, As, tid);
        stage_tile(Bg + k0, HID, Bs, tid);
        __syncthreads();
        mfma_step(As, Bs, wr, wc, fr, fq, acc);
        __syncthreads();
    }
    const float* bias = b2_base + (size_t)z * b_es;
    bf16* outg = outg_base + (size_t)z * o_es;
    int rbase = blockIdx.y * 128 + wr * 64;
    int cbase = blockIdx.x * 128 + wc * 64;
    #pragma unroll
    for (int j = 0; j < 4; ++j) {
        int col = cbase + j * 16 + fr;
        float bv = bias[col];
        #pragma unroll
        for (int i = 0; i < 4; ++i)
            #pragma unroll
            for (int r = 0; r < 4; ++r) {
                int row = rbase + i * 16 + fq * 4 + r;
                float g = sh_probs[row * 2 + z];
                outg[(size_t)row * DIM + col] = __float2bfloat16(g * (acc[i][j][r] + bv));
            }
    }
}

// ---------------------------------------------------------------- GEMM2 dense -> f32 out (plan B fallback)
__global__ __launch_bounds__(256) void gemm2_dense_out(
    const bf16* __restrict__ A, const bf16* __restrict__ BT,
    const float* __restrict__ bias, const float* __restrict__ gates,
    float* __restrict__ out, int gidx, int accum) {
    __shared__ bf16 As[128 * 32];
    __shared__ bf16 Bs[128 * 32];
    int tid = threadIdx.x;
    int wid = tid >> 6, lane = tid & 63;
    int wr = wid >> 1, wc = wid & 1;
    int fr = lane & 15, fq = lane >> 4;
    const bf16* Ag = A + (size_t)(blockIdx.y * 128) * HID;
    const bf16* Bg = BT + (size_t)(blockIdx.x * 128) * HID;
    f32x4 acc[4][4] = {};
    for (int k0 = 0; k0 < HID; k0 += 32) {
        stage_tile(Ag + k0, HID, As, tid);
        stage_tile(Bg + k0, HID, Bs, tid);
        __syncthreads();
        mfma_step(As, Bs, wr, wc, fr, fq, acc);
        __syncthreads();
    }
    int rbase = blockIdx.y * 128 + wr * 64;
    int cbase = blockIdx.x * 128 + wc * 64;
    #pragma unroll
    for (int j = 0; j < 4; ++j) {
        int col = cbase + j * 16 + fr;
        float bv = bias[col];
        #pragma unroll
        for (int i = 0; i < 4; ++i)
            #pragma unroll
            for (int r = 0; r < 4; ++r) {
                int row = rbase + i * 16 + fq * 4 + r;
                float g = gates[(size_t)row * 6 + gidx];
                float v = g * (acc[i][j][r] + bv);
                size_t idx = (size_t)row * DIM + col;
                out[idx] = accum ? out[idx] + v : v;
            }
    }
}

// ---------------------------------------------------------------- combine (plan A)
__global__ void combine_kernel(const bf16* __restrict__ spec_g, const bf16* __restrict__ shg,
                               const int* __restrict__ back, float* __restrict__ out) {
    int t = blockIdx.x;
    int b0 = back[2 * t], b1 = back[2 * t + 1];
    const bf16* p0 = spec_g + (size_t)b0 * DIM;
    const bf16* p1 = spec_g + (size_t)b1 * DIM;
    const bf16* s0 = shg + (size_t)t * DIM;
    const bf16* s1 = shg + (size_t)NTOK * DIM + (size_t)t * DIM;
    #pragma unroll
    for (int i = 0; i < 3; ++i) {
        int c = threadIdx.x + 256 * i;
        out[(size_t)t * DIM + c] = __bfloat162float(p0[c]) + __bfloat162float(p1[c]) +
                                   __bfloat162float(s0[c]) + __bfloat162float(s1[c]);
    }
}

// ---------------------------------------------------------------- launch
static inline size_t align256(size_t x) { return (x + 255) & ~(size_t)255; }

extern "C" void kernel_launch(void* const* d_in, const int* in_sizes, int n_in,
                              void* d_out, int out_size, void* d_ws, size_t ws_size,
                              hipStream_t stream) {
    const float* x      = (const float*)d_in[0];
    const float* gamma  = (const float*)d_in[1];
    const float* beta   = (const float*)d_in[2];
    const float* srw    = (const float*)d_in[3];
    const float* srb    = (const float*)d_in[4];
    const float* spec_w1 = (const float*)d_in[5];
    const float* spec_b1 = (const float*)d_in[6];
    const float* spec_w2 = (const float*)d_in[7];
    const float* spec_b2 = (const float*)d_in[8];
    const float* shw    = (const float*)d_in[9];
    const float* shb    = (const float*)d_in[10];
    const float* sh_w1  = (const float*)d_in[11];
    const float* sh_b1  = (const float*)d_in[12];
    const float* sh_w2  = (const float*)d_in[13];
    const float* sh_b2  = (const float*)d_in[14];

    // ---- workspace carve-up
    char* p = (char*)d_ws;
    size_t off = 0;
    bf16* xnb = (bf16*)(p + off);       off = align256(off + (size_t)NTOK * DIM * 2);
    bf16* w1t = (bf16*)(p + off);       off = align256(off + (size_t)6 * HID * DIM * 2);
    bf16* w2t = (bf16*)(p + off);       off = align256(off + (size_t)6 * DIM * HID * 2);
    int*  cnt = (int*)(p + off);        off = align256(off + 16);
    float* gates = (float*)(p + off);   off = align256(off + (size_t)NTOK * 6 * 4);
    int*  tok_of = (int*)(p + off);     off = align256(off + (size_t)4 * NTOK * 4);
    float* gate_of = (float*)(p + off); off = align256(off + (size_t)4 * NTOK * 4);
    int*  slot_tok = (int*)(p + off);   off = align256(off + (size_t)NSLOT_MAX * 4);
    float* slot_gate = (float*)(p + off); off = align256(off + (size_t)NSLOT_MAX * 4);
    int*  back = (int*)(p + off);       off = align256(off + (size_t)2 * NTOK * 4);
    int*  e_of_tile = (int*)(p + off);  off = align256(off + (size_t)NTILE_MAX * 4);
    size_t off_common = off;
    // plan A tail
    bf16* Hreg = (bf16*)(p + off);      off = align256(off + (size_t)NSLOT_MAX * HID * 2);
    bf16* spec_g = (bf16*)(p + off);    off = align256(off + (size_t)NSLOT_MAX * DIM * 2);
    bf16* shg = (bf16*)(p + off);       off = align256(off + (size_t)2 * NTOK * DIM * 2);
    size_t need_A = off;
    // plan B tail (reuses Hreg region start)
    size_t need_B = align256(off_common + (size_t)NTOK * HID * 2);
    bf16* HB = Hreg;

    // d_out layout (flat concat, all f32)
    float* out         = (float*)d_out;
    float* spec_logits = out + (size_t)NTOK * DIM;
    float* spec_probs  = spec_logits + (size_t)NTOK * 4;
    float* topk_idx    = spec_probs  + (size_t)NTOK * 4;
    float* topk_probs  = topk_idx    + (size_t)NTOK * 2;
    float* sh_logits   = topk_probs  + (size_t)NTOK * 2;
    float* sh_probs    = sh_logits   + (size_t)NTOK * 2;

    hipMemsetAsync(cnt, 0, 16, stream);

    // weights: transpose + bf16
    conv_t_kernel<<<dim3(HID / 32, DIM / 32, 4), 256, 0, stream>>>(spec_w1, w1t, DIM, HID);
    conv_t_kernel<<<dim3(HID / 32, DIM / 32, 2), 256, 0, stream>>>(sh_w1, w1t + (size_t)4 * HID * DIM, DIM, HID);
    conv_t_kernel<<<dim3(DIM / 32, HID / 32, 4), 256, 0, stream>>>(spec_w2, w2t, HID, DIM);
    conv_t_kernel<<<dim3(DIM / 32, HID / 32, 2), 256, 0, stream>>>(sh_w2, w2t + (size_t)4 * DIM * HID, HID, DIM);

    ln_kernel<<<NTOK, 256, 0, stream>>>(x, gamma, beta, xnb);
    router_kernel<<<NTOK / 4, 256, 0, stream>>>(x, gamma, beta, srw, srb, shw, shb,
                                                spec_logits, spec_probs, topk_idx,
                                                topk_probs, sh_logits, sh_probs, gates,
                                                cnt, tok_of, gate_of);

    if (ws_size >= need_A) {
        plan_kernel<<<1, 256, 0, stream>>>(cnt, e_of_tile, tok_of, gate_of,
                                           slot_tok, slot_gate, back);
        // specific experts, grouped (only selected tokens)
        gemm1_grouped<<<dim3(HID / 128, NTILE_MAX), 256, 0, stream>>>(
            xnb, w1t, spec_b1, e_of_tile, slot_tok, Hreg);
        gemm2_grouped<<<dim3(DIM / 128, NTILE_MAX), 256, 0, stream>>>(
            Hreg, w2t, spec_b2, e_of_tile, slot_gate, spec_g);
        // shared experts, z-batched (reuse Hreg)
        gemm1_dense<<<dim3(HID / 128, NTOK / 128, 2), 256, 0, stream>>>(
            xnb, w1t + (size_t)4 * HID * DIM, (size_t)HID * DIM,
            sh_b1, (size_t)HID, Hreg, (size_t)NTOK * HID);
        gemm2_dense_sh<<<dim3(DIM / 128, NTOK / 128, 2), 256, 0, stream>>>(
            Hreg, (size_t)NTOK * HID, w2t + (size_t)4 * DIM * HID, (size_t)DIM * HID,
            sh_b2, (size_t)DIM, sh_probs, shg, (size_t)NTOK * DIM);
        combine_kernel<<<NTOK, 256, 0, stream>>>(spec_g, shg, back, out);
    } else {
        // fallback: dense 6-expert loop (round-2 flow)
        for (int e = 0; e < 6; ++e) {
            const bf16* w1p = w1t + (size_t)e * HID * DIM;
            const bf16* w2p = w2t + (size_t)e * DIM * HID;
            const float* b1p = (e < 4) ? spec_b1 + (size_t)e * HID : sh_b1 + (size_t)(e - 4) * HID;
            const float* b2p = (e < 4) ? spec_b2 + (size_t)e * DIM : sh_b2 + (size_t)(e - 4) * DIM;
            gemm1_dense<<<dim3(HID / 128, NTOK / 128, 1), 256, 0, stream>>>(
                xnb, w1p, 0, b1p, 0, HB, 0);
            gemm2_dense_out<<<dim3(DIM / 128, NTOK / 128, 1), 256, 0, stream>>>(
                HB, w2p, b2p, gates, out, e, e > 0);
        }
    }
}

// Round 4
// 1472.574 us; speedup vs baseline: 8.1529x; 1.1734x over previous
//
#include <hip/hip_runtime.h>
#include <hip/hip_bf16.h>
#include <math.h>

#define NTOK 12544
#define DIM 768
#define HID 3072
#define NSLOT_MAX 25600     // 2*NTOK + 4*127 rounded up to 128
#define NTILE_MAX 200       // NSLOT_MAX/128
#define NBKT 64
#define BKTCAP 256

typedef __hip_bfloat16 bf16;
typedef __attribute__((ext_vector_type(8))) short short8v;
typedef __attribute__((ext_vector_type(4))) float f32x4;

#define GPTR(p)  ((const __attribute__((address_space(1))) void*)(p))
#define LDSPTR(p) ((__attribute__((address_space(3))) void*)(p))

// ---------------------------------------------------------------- LayerNorm -> bf16
__global__ void ln_kernel(const float* __restrict__ x, const float* __restrict__ g,
                          const float* __restrict__ b, bf16* __restrict__ xnb) {
    __shared__ float red[4];
    int t = blockIdx.x;
    const float* xr = x + (size_t)t * DIM;
    bf16*        xb = xnb + (size_t)t * DIM;
    int tid = threadIdx.x, lane = tid & 63, wid = tid >> 6;
    float v[3];
    #pragma unroll
    for (int i = 0; i < 3; ++i) v[i] = xr[tid + 256 * i];
    float s = v[0] + v[1] + v[2];
    #pragma unroll
    for (int o = 32; o > 0; o >>= 1) s += __shfl_down(s, o, 64);
    if (lane == 0) red[wid] = s;
    __syncthreads();
    s = red[0] + red[1] + red[2] + red[3];
    __syncthreads();
    float mean = s * (1.0f / 768.0f);
    float sq = 0.0f;
    #pragma unroll
    for (int i = 0; i < 3; ++i) { float d = v[i] - mean; sq += d * d; }
    #pragma unroll
    for (int o = 32; o > 0; o >>= 1) sq += __shfl_down(sq, o, 64);
    if (lane == 0) red[wid] = sq;
    __syncthreads();
    sq = red[0] + red[1] + red[2] + red[3];
    float rstd = rsqrtf(sq * (1.0f / 768.0f) + 1e-5f);
    #pragma unroll
    for (int i = 0; i < 3; ++i) {
        int c = tid + 256 * i;
        xb[c] = __float2bfloat16((v[i] - mean) * rstd * g[c] + b[c]);
    }
}

// ---------------------------------------------------------------- Router (own f32 LN) + bucketed routing lists
__global__ void router_kernel(const float* __restrict__ x,
                              const float* __restrict__ lng, const float* __restrict__ lnb,
                              const float* __restrict__ srw, const float* __restrict__ srb,
                              const float* __restrict__ shw, const float* __restrict__ shb,
                              float* __restrict__ spec_logits, float* __restrict__ spec_probs,
                              float* __restrict__ topk_idx, float* __restrict__ topk_probs,
                              float* __restrict__ sh_logits, float* __restrict__ sh_probs,
                              float* __restrict__ gates,
                              int* __restrict__ cnt2, int* __restrict__ tok2,
                              float* __restrict__ gate2) {
    int t = blockIdx.x * 4 + (threadIdx.x >> 6);
    int bucket = blockIdx.x & (NBKT - 1);
    int lane = threadIdx.x & 63;
    const float* xr = x + (size_t)t * DIM;
    float v[12];
    float s = 0.0f;
    #pragma unroll
    for (int i = 0; i < 12; ++i) { v[i] = xr[lane + 64 * i]; s += v[i]; }
    #pragma unroll
    for (int o = 32; o > 0; o >>= 1) s += __shfl_xor(s, o, 64);
    float mean = s * (1.0f / 768.0f);
    float sq = 0.0f;
    #pragma unroll
    for (int i = 0; i < 12; ++i) { float d = v[i] - mean; sq += d * d; }
    #pragma unroll
    for (int o = 32; o > 0; o >>= 1) sq += __shfl_xor(sq, o, 64);
    float rstd = rsqrtf(sq * (1.0f / 768.0f) + 1e-5f);

    float acc[6] = {0, 0, 0, 0, 0, 0};
    #pragma unroll 4
    for (int i = 0; i < 12; ++i) {
        int d = lane + 64 * i;
        float xv = (v[i] - mean) * rstd * lng[d] + lnb[d];
        #pragma unroll
        for (int j = 0; j < 4; ++j) acc[j] += xv * srw[d * 4 + j];
        #pragma unroll
        for (int j = 0; j < 2; ++j) acc[4 + j] += xv * shw[d * 2 + j];
    }
    #pragma unroll
    for (int j = 0; j < 6; ++j) {
        #pragma unroll
        for (int o = 32; o > 0; o >>= 1) acc[j] += __shfl_xor(acc[j], o, 64);
    }
    if (lane == 0) {
        float l[4];
        #pragma unroll
        for (int j = 0; j < 4; ++j) l[j] = acc[j] + srb[j];
        float m = fmaxf(fmaxf(l[0], l[1]), fmaxf(l[2], l[3]));
        float e[4], ssum = 0.0f;
        #pragma unroll
        for (int j = 0; j < 4; ++j) { e[j] = expf(l[j] - m); ssum += e[j]; }
        float inv = 1.0f / ssum;
        float p[4];
        #pragma unroll
        for (int j = 0; j < 4; ++j) p[j] = e[j] * inv;
        int i0 = 0;
        for (int j = 1; j < 4; ++j) if (p[j] > p[i0]) i0 = j;
        int i1 = -1;
        for (int j = 0; j < 4; ++j) {
            if (j == i0) continue;
            if (i1 < 0 || p[j] > p[i1]) i1 = j;
        }
        float sl0 = acc[4] + shb[0], sl1 = acc[5] + shb[1];
        float sm = fmaxf(sl0, sl1);
        float se0 = expf(sl0 - sm), se1 = expf(sl1 - sm);
        float sinv = 1.0f / (se0 + se1);
        float sp0 = se0 * sinv, sp1 = se1 * sinv;

        #pragma unroll
        for (int j = 0; j < 4; ++j) {
            spec_logits[t * 4 + j] = l[j];
            spec_probs[t * 4 + j]  = p[j];
        }
        topk_idx[t * 2 + 0]   = (float)i0;
        topk_idx[t * 2 + 1]   = (float)i1;
        topk_probs[t * 2 + 0] = p[i0];
        topk_probs[t * 2 + 1] = p[i1];
        sh_logits[t * 2 + 0]  = sl0;
        sh_logits[t * 2 + 1]  = sl1;
        sh_probs[t * 2 + 0]   = sp0;
        sh_probs[t * 2 + 1]   = sp1;
        float gg[6] = {0, 0, 0, 0, sp0, sp1};
        gg[i0] = p[i0];
        gg[i1] = p[i1];
        #pragma unroll
        for (int j = 0; j < 6; ++j) gates[t * 6 + j] = gg[j];
        // bucketed routing lists: 256 counters instead of 4 -> ~64x less contention
        int c0 = i0 * NBKT + bucket;
        int pos0 = atomicAdd(&cnt2[c0], 1);
        tok2[c0 * BKTCAP + pos0]  = t * 2 + 0;
        gate2[c0 * BKTCAP + pos0] = p[i0];
        int c1 = i1 * NBKT + bucket;
        int pos1 = atomicAdd(&cnt2[c1], 1);
        tok2[c1 * BKTCAP + pos1]  = t * 2 + 1;
        gate2[c1 * BKTCAP + pos1] = p[i1];
    }
}

// ---------------------------------------------------------------- plan: scan buckets, fill slots
__global__ void plan_kernel(const int* __restrict__ cnt2, int* __restrict__ e_of_tile,
                            const int* __restrict__ tok2, const float* __restrict__ gate2,
                            int* __restrict__ slot_tok, float* __restrict__ slot_gate,
                            int* __restrict__ back) {
    __shared__ int base[4 * NBKT];
    __shared__ int offsE[5];
    int tid = threadIdx.x;
    if (tid == 0) {
        int o = 0;
        for (int e = 0; e < 4; ++e) {
            offsE[e] = o;
            int run = o;
            for (int b = 0; b < NBKT; ++b) {
                base[e * NBKT + b] = run;
                run += cnt2[e * NBKT + b];
            }
            int tot = run - o;
            o += (tot + 127) & ~127;
        }
        offsE[4] = o;
    }
    __syncthreads();
    // zero-fill all slots (padding defaults)
    for (int i = tid; i < NSLOT_MAX; i += 256) {
        slot_tok[i] = 0;
        slot_gate[i] = 0.0f;
    }
    // tile -> expert map
    for (int idx = tid; idx < NTILE_MAX; idx += 256) {
        int s = idx * 128, e = -1;
        for (int j = 0; j < 4; ++j)
            if (s >= offsE[j] && s < offsE[j + 1]) e = j;
        e_of_tile[idx] = e;
    }
    __syncthreads();
    // compact each bucket (thread tid owns bucket tid)
    int c = cnt2[tid];
    int bs = base[tid];
    for (int i = 0; i < c; ++i) {
        int gs = bs + i;
        int tk = tok2[tid * BKTCAP + i];
        slot_tok[gs] = tk >> 1;
        slot_gate[gs] = gate2[tid * BKTCAP + i];
        back[tk] = gs;
    }
}

// ---------------------------------------------------------------- transpose + f32->bf16
__global__ __launch_bounds__(256) void conv_t_kernel(const float* __restrict__ in,
                                                     bf16* __restrict__ out, int R, int C) {
    __shared__ float tile[32][33];
    const float* ip = in + (size_t)blockIdx.z * R * C;
    bf16* op = out + (size_t)blockIdx.z * R * C;
    int r0 = blockIdx.y * 32, c0 = blockIdx.x * 32;
    int tx = threadIdx.x & 31, ty = threadIdx.x >> 5;
    #pragma unroll
    for (int i = 0; i < 32; i += 8)
        tile[ty + i][tx] = ip[(size_t)(r0 + ty + i) * C + c0 + tx];
    __syncthreads();
    #pragma unroll
    for (int i = 0; i < 32; i += 8)
        op[(size_t)(c0 + ty + i) * R + r0 + tx] = __float2bfloat16(tile[tx][ty + i]);
}

// ---------------------------------------------------------------- MFMA helpers
__device__ __forceinline__ void stage_tile(const bf16* __restrict__ g, int ldg,
                                           bf16* lds, int tid) {
    int wave = tid >> 6, lane = tid & 63;
    #pragma unroll
    for (int q = 0; q < 2; ++q) {
        int chunk = wave * 2 + q;
        int row = chunk * 16 + (lane >> 2);
        int col = (lane & 3) * 8;
        __builtin_amdgcn_global_load_lds(GPTR(g + (size_t)row * ldg + col),
                                         LDSPTR(lds + chunk * 512), 16, 0, 0);
    }
}

__device__ __forceinline__ void mfma_step(const bf16* As, const bf16* Bs,
                                          int wr, int wc, int fr, int fq, f32x4 acc[4][4]) {
    short8v a[4], b[4];
    #pragma unroll
    for (int i = 0; i < 4; ++i) {
        a[i] = *(const short8v*)&As[(wr * 64 + i * 16 + fr) * 32 + fq * 8];
        b[i] = *(const short8v*)&Bs[(wc * 64 + i * 16 + fr) * 32 + fq * 8];
    }
    #pragma unroll
    for (int i = 0; i < 4; ++i)
        #pragma unroll
        for (int j = 0; j < 4; ++j)
            acc[i][j] = __builtin_amdgcn_mfma_f32_16x16x32_bf16(a[i], b[j], acc[i][j], 0, 0, 0);
}

__device__ __forceinline__ float gelu_exact(float v) {
    return 0.5f * v * (1.0f + erff(v * 0.70710678118654752f));
}

// ---------------------------------------------------------------- GEMM1 grouped (specific experts)
__global__ __launch_bounds__(256) void gemm1_grouped(
    const bf16* __restrict__ xnb, const bf16* __restrict__ w1t,
    const float* __restrict__ b1, const int* __restrict__ e_of_tile,
    const int* __restrict__ slot_tok, bf16* __restrict__ H) {
    int rt = blockIdx.y;
    int e = e_of_tile[rt];
    if (e < 0) return;
    __shared__ bf16 As[128 * 32];
    __shared__ bf16 Bs[128 * 32];
    int tid = threadIdx.x;
    int wid = tid >> 6, lane = tid & 63;
    int wr = wid >> 1, wc = wid & 1;
    int fr = lane & 15, fq = lane >> 4;
    const bf16* asrc[2];
    #pragma unroll
    for (int q = 0; q < 2; ++q) {
        int chunk = wid * 2 + q;
        int r = chunk * 16 + (lane >> 2);
        int tok = slot_tok[rt * 128 + r];
        asrc[q] = xnb + (size_t)tok * DIM + (lane & 3) * 8;
    }
    const bf16* Bg = w1t + (size_t)e * HID * DIM + (size_t)(blockIdx.x * 128) * DIM;
    f32x4 acc[4][4] = {};
    for (int k0 = 0; k0 < DIM; k0 += 32) {
        #pragma unroll
        for (int q = 0; q < 2; ++q)
            __builtin_amdgcn_global_load_lds(GPTR(asrc[q] + k0),
                                             LDSPTR(As + (wid * 2 + q) * 512), 16, 0, 0);
        stage_tile(Bg + k0, DIM, Bs, tid);
        __syncthreads();
        mfma_step(As, Bs, wr, wc, fr, fq, acc);
        __syncthreads();
    }
    const float* b1e = b1 + (size_t)e * HID;
    int rbase = rt * 128 + wr * 64;
    int cbase = blockIdx.x * 128 + wc * 64;
    #pragma unroll
    for (int j = 0; j < 4; ++j) {
        int col = cbase + j * 16 + fr;
        float bv = b1e[col];
        #pragma unroll
        for (int i = 0; i < 4; ++i)
            #pragma unroll
            for (int r = 0; r < 4; ++r) {
                int row = rbase + i * 16 + fq * 4 + r;
                H[(size_t)row * HID + col] = __float2bfloat16(gelu_exact(acc[i][j][r] + bv));
            }
    }
}

// ---------------------------------------------------------------- GEMM2 grouped -> gathered bf16 partials
__global__ __launch_bounds__(256) void gemm2_grouped(
    const bf16* __restrict__ H, const bf16* __restrict__ w2t,
    const float* __restrict__ b2, const int* __restrict__ e_of_tile,
    const float* __restrict__ slot_gate, bf16* __restrict__ outg) {
    int rt = blockIdx.y;
    int e = e_of_tile[rt];
    if (e < 0) return;
    __shared__ bf16 As[128 * 32];
    __shared__ bf16 Bs[128 * 32];
    int tid = threadIdx.x;
    int wid = tid >> 6, lane = tid & 63;
    int wr = wid >> 1, wc = wid & 1;
    int fr = lane & 15, fq = lane >> 4;
    const bf16* Ag = H + (size_t)(rt * 128) * HID;
    const bf16* Bg = w2t + (size_t)e * DIM * HID + (size_t)(blockIdx.x * 128) * HID;
    f32x4 acc[4][4] = {};
    for (int k0 = 0; k0 < HID; k0 += 32) {
        stage_tile(Ag + k0, HID, As, tid);
        stage_tile(Bg + k0, HID, Bs, tid);
        __syncthreads();
        mfma_step(As, Bs, wr, wc, fr, fq, acc);
        __syncthreads();
    }
    const float* b2e = b2 + (size_t)e * DIM;
    int rbase = rt * 128 + wr * 64;
    int cbase = blockIdx.x * 128 + wc * 64;
    #pragma unroll
    for (int j = 0; j < 4; ++j) {
        int col = cbase + j * 16 + fr;
        float bv = b2e[col];
        #pragma unroll
        for (int i = 0; i < 4; ++i)
            #pragma unroll
            for (int r = 0; r < 4; ++r) {
                int row = rbase + i * 16 + fq * 4 + r;
                float g = slot_gate[row];
                outg[(size_t)row * DIM + col] = __float2bfloat16(g * (acc[i][j][r] + bv));
            }
    }
}

// ---------------------------------------------------------------- GEMM1 dense (z = expert offset)
__global__ __launch_bounds__(256) void gemm1_dense(
    const bf16* __restrict__ A, const bf16* __restrict__ w1t_base, size_t w_es,
    const float* __restrict__ b1_base, size_t b_es,
    bf16* __restrict__ H_base, size_t h_es) {
    int z = blockIdx.z;
    __shared__ bf16 As[128 * 32];
    __shared__ bf16 Bs[128 * 32];
    int tid = threadIdx.x;
    int wid = tid >> 6, lane = tid & 63;
    int wr = wid >> 1, wc = wid & 1;
    int fr = lane & 15, fq = lane >> 4;
    const bf16* Ag = A + (size_t)(blockIdx.y * 128) * DIM;
    const bf16* Bg = w1t_base + (size_t)z * w_es + (size_t)(blockIdx.x * 128) * DIM;
    f32x4 acc[4][4] = {};
    for (int k0 = 0; k0 < DIM; k0 += 32) {
        stage_tile(Ag + k0, DIM, As, tid);
        stage_tile(Bg + k0, DIM, Bs, tid);
        __syncthreads();
        mfma_step(As, Bs, wr, wc, fr, fq, acc);
        __syncthreads();
    }
    const float* bias = b1_base + (size_t)z * b_es;
    bf16* H = H_base + (size_t)z * h_es;
    int rbase = blockIdx.y * 128 + wr * 64;
    int cbase = blockIdx.x * 128 + wc * 64;
    #pragma unroll
    for (int j = 0; j < 4; ++j) {
        int col = cbase + j * 16 + fr;
        float bv = bias[col];
        #pragma unroll
        for (int i = 0; i < 4; ++i)
            #pragma unroll
            for (int r = 0; r < 4; ++r) {
                int row = rbase + i * 16 + fq * 4 + r;
                H[(size_t)row * HID + col] = __float2bfloat16(gelu_exact(acc[i][j][r] + bv));
            }
    }
}

// ---------------------------------------------------------------- GEMM2 dense shared -> bf16 partials (z batched)
__global__ __launch_bounds__(256) void gemm2_dense_sh(
    const bf16* __restrict__ H_base, size_t h_es,
    const bf16* __restrict__ w2t_base, size_t w_es,
    const float* __restrict__ b2_base, size_t b_es,
    const float* __restrict__ sh_probs, bf16* __restrict__ outg_base, size_t o_es) {
    int z = blockIdx.z;
    __shared__ bf16 As[128 * 32];
    __shared__ bf16 Bs[128 * 32];
    int tid = threadIdx.x;
    int wid = tid >> 6, lane = tid & 63;
    int wr = wid >> 1, wc = wid & 1;
    int fr = lane & 15, fq = lane >> 4;
    const bf16* Ag = H_base + (size_t)z * h_es + (size_t)(blockIdx.y * 128) * HID;
    const bf16* Bg = w2t_base + (size_t)z * w_es + (size_t)(blockIdx.x * 128) * HID;
    f32x4 acc[4][4] = {};
    for (int k0 = 0; k0 < HID; k0 += 32) {
        stage_tile(Ag + k0, HID, As, tid);
        stage_tile(Bg + k0, HID, Bs, tid);
        __syncthreads();
        mfma_step(As, Bs, wr, wc, fr, fq, acc);
        __syncthreads();
    }
    const float* bias = b2_base + (size_t)z * b_es;
    bf16* outg = outg_base + (size_t)z * o_es;
    int rbase = blockIdx.y * 128 + wr * 64;
    int cbase = blockIdx.x * 128 + wc * 64;
    #pragma unroll
    for (int j = 0; j < 4; ++j) {
        int col = cbase + j * 16 + fr;
        float bv = bias[col];
        #pragma unroll
        for (int i = 0; i < 4; ++i)
            #pragma unroll
            for (int r = 0; r < 4; ++r) {
                int row = rbase + i * 16 + fq * 4 + r;
                float g = sh_probs[row * 2 + z];
                outg[(size_t)row * DIM + col] = __float2bfloat16(g * (acc[i][j][r] + bv));
            }
    }
}

// ---------------------------------------------------------------- GEMM2 dense -> f32 out (plan B fallback)
__global__ __launch_bounds__(256) void gemm2_dense_out(
    const bf16* __restrict__ A, const bf16* __restrict__ BT,
    const float* __restrict__ bias, const float* __restrict__ gates,
    float* __restrict__ out, int gidx, int accum) {
    __shared__ bf16 As[128 * 32];
    __shared__ bf16 Bs[128 * 32];
    int tid = threadIdx.x;
    int wid = tid >> 6, lane = tid & 63;
    int wr = wid >> 1, wc = wid & 1;
    int fr = lane & 15, fq = lane >> 4;
    const bf16* Ag = A + (size_t)(blockIdx.y * 128) * HID;
    const bf16* Bg = BT + (size_t)(blockIdx.x * 128) * HID;
    f32x4 acc[4][4] = {};
    for (int k0 = 0; k0 < HID; k0 += 32) {
        stage_tile(Ag + k0, HID, As, tid);
        stage_tile(Bg + k0, HID, Bs, tid);
        __syncthreads();
        mfma_step(As, Bs, wr, wc, fr, fq, acc);
        __syncthreads();
    }
    int rbase = blockIdx.y * 128 + wr * 64;
    int cbase = blockIdx.x * 128 + wc * 64;
    #pragma unroll
    for (int j = 0; j < 4; ++j) {
        int col = cbase + j * 16 + fr;
        float bv = bias[col];
        #pragma unroll
        for (int i = 0; i < 4; ++i)
            #pragma unroll
            for (int r = 0; r < 4; ++r) {
                int row = rbase + i * 16 + fq * 4 + r;
                float g = gates[(size_t)row * 6 + gidx];
                float v = g * (acc[i][j][r] + bv);
                size_t idx = (size_t)row * DIM + col;
                out[idx] = accum ? out[idx] + v : v;
            }
    }
}

// ---------------------------------------------------------------- combine (plan A)
__global__ void combine_kernel(const bf16* __restrict__ spec_g, const bf16* __restrict__ shg,
                               const int* __restrict__ back, float* __restrict__ out) {
    int t = blockIdx.x;
    int b0 = back[2 * t], b1 = back[2 * t + 1];
    const bf16* p0 = spec_g + (size_t)b0 * DIM;
    const bf16* p1 = spec_g + (size_t)b1 * DIM;
    const bf16* s0 = shg + (size_t)t * DIM;
    const bf16* s1 = shg + (size_t)NTOK * DIM + (size_t)t * DIM;
    #pragma unroll
    for (int i = 0; i < 3; ++i) {
        int c = threadIdx.x + 256 * i;
        out[(size_t)t * DIM + c] = __bfloat162float(p0[c]) + __bfloat162float(p1[c]) +
                                   __bfloat162float(s0[c]) + __bfloat162float(s1[c]);
    }
}

// ---------------------------------------------------------------- launch
static inline size_t align256(size_t x) { return (x + 255) & ~(size_t)255; }

extern "C" void kernel_launch(void* const* d_in, const int* in_sizes, int n_in,
                              void* d_out, int out_size, void* d_ws, size_t ws_size,
                              hipStream_t stream) {
    const float* x      = (const float*)d_in[0];
    const float* gamma  = (const float*)d_in[1];
    const float* beta   = (const float*)d_in[2];
    const float* srw    = (const float*)d_in[3];
    const float* srb    = (const float*)d_in[4];
    const float* spec_w1 = (const float*)d_in[5];
    const float* spec_b1 = (const float*)d_in[6];
    const float* spec_w2 = (const float*)d_in[7];
    const float* spec_b2 = (const float*)d_in[8];
    const float* shw    = (const float*)d_in[9];
    const float* shb    = (const float*)d_in[10];
    const float* sh_w1  = (const float*)d_in[11];
    const float* sh_b1  = (const float*)d_in[12];
    const float* sh_w2  = (const float*)d_in[13];
    const float* sh_b2  = (const float*)d_in[14];

    // ---- workspace carve-up
    char* p = (char*)d_ws;
    size_t off = 0;
    bf16* xnb = (bf16*)(p + off);       off = align256(off + (size_t)NTOK * DIM * 2);
    bf16* w1t = (bf16*)(p + off);       off = align256(off + (size_t)6 * HID * DIM * 2);
    bf16* w2t = (bf16*)(p + off);       off = align256(off + (size_t)6 * DIM * HID * 2);
    int*  cnt2 = (int*)(p + off);       off = align256(off + (size_t)4 * NBKT * 4);
    float* gates = (float*)(p + off);   off = align256(off + (size_t)NTOK * 6 * 4);
    int*  tok2 = (int*)(p + off);       off = align256(off + (size_t)4 * NBKT * BKTCAP * 4);
    float* gate2 = (float*)(p + off);   off = align256(off + (size_t)4 * NBKT * BKTCAP * 4);
    int*  slot_tok = (int*)(p + off);   off = align256(off + (size_t)NSLOT_MAX * 4);
    float* slot_gate = (float*)(p + off); off = align256(off + (size_t)NSLOT_MAX * 4);
    int*  back = (int*)(p + off);       off = align256(off + (size_t)2 * NTOK * 4);
    int*  e_of_tile = (int*)(p + off);  off = align256(off + (size_t)NTILE_MAX * 4);
    size_t off_common = off;
    // plan A tail
    bf16* Hreg = (bf16*)(p + off);      off = align256(off + (size_t)NSLOT_MAX * HID * 2);
    bf16* spec_g = (bf16*)(p + off);    off = align256(off + (size_t)NSLOT_MAX * DIM * 2);
    bf16* shg = (bf16*)(p + off);       off = align256(off + (size_t)2 * NTOK * DIM * 2);
    size_t need_A = off;
    // plan B tail (reuses Hreg region start)
    bf16* HB = Hreg;

    // d_out layout (flat concat, all f32)
    float* out         = (float*)d_out;
    float* spec_logits = out + (size_t)NTOK * DIM;
    float* spec_probs  = spec_logits + (size_t)NTOK * 4;
    float* topk_idx    = spec_probs  + (size_t)NTOK * 4;
    float* topk_probs  = topk_idx    + (size_t)NTOK * 2;
    float* sh_logits   = topk_probs  + (size_t)NTOK * 2;
    float* sh_probs    = sh_logits   + (size_t)NTOK * 2;

    hipMemsetAsync(cnt2, 0, (size_t)4 * NBKT * 4, stream);

    // weights: transpose + bf16
    conv_t_kernel<<<dim3(HID / 32, DIM / 32, 4), 256, 0, stream>>>(spec_w1, w1t, DIM, HID);
    conv_t_kernel<<<dim3(HID / 32, DIM / 32, 2), 256, 0, stream>>>(sh_w1, w1t + (size_t)4 * HID * DIM, DIM, HID);
    conv_t_kernel<<<dim3(DIM / 32, HID / 32, 4), 256, 0, stream>>>(spec_w2, w2t, HID, DIM);
    conv_t_kernel<<<dim3(DIM / 32, HID / 32, 2), 256, 0, stream>>>(sh_w2, w2t + (size_t)4 * DIM * HID, HID, DIM);

    ln_kernel<<<NTOK, 256, 0, stream>>>(x, gamma, beta, xnb);
    router_kernel<<<NTOK / 4, 256, 0, stream>>>(x, gamma, beta, srw, srb, shw, shb,
                                                spec_logits, spec_probs, topk_idx,
                                                topk_probs, sh_logits, sh_probs, gates,
                                                cnt2, tok2, gate2);

    if (ws_size >= need_A) {
        plan_kernel<<<1, 256, 0, stream>>>(cnt2, e_of_tile, tok2, gate2,
                                           slot_tok, slot_gate, back);
        // specific experts, grouped (only selected tokens)
        gemm1_grouped<<<dim3(HID / 128, NTILE_MAX), 256, 0, stream>>>(
            xnb, w1t, spec_b1, e_of_tile, slot_tok, Hreg);
        gemm2_grouped<<<dim3(DIM / 128, NTILE_MAX), 256, 0, stream>>>(
            Hreg, w2t, spec_b2, e_of_tile, slot_gate, spec_g);
        // shared experts, z-batched (reuse Hreg)
        gemm1_dense<<<dim3(HID / 128, NTOK / 128, 2), 256, 0, stream>>>(
            xnb, w1t + (size_t)4 * HID * DIM, (size_t)HID * DIM,
            sh_b1, (size_t)HID, Hreg, (size_t)NTOK * HID);
        gemm2_dense_sh<<<dim3(DIM / 128, NTOK / 128, 2), 256, 0, stream>>>(
            Hreg, (size_t)NTOK * HID, w2t + (size_t)4 * DIM * HID, (size_t)DIM * HID,
            sh_b2, (size_t)DIM, sh_probs, shg, (size_t)NTOK * DIM);
        combine_kernel<<<NTOK, 256, 0, stream>>>(spec_g, shg, back, out);
    } else {
        // fallback: dense 6-expert loop (round-2 flow)
        for (int e = 0; e < 6; ++e) {
            const bf16* w1p = w1t + (size_t)e * HID * DIM;
            const bf16* w2p = w2t + (size_t)e * DIM * HID;
            const float* b1p = (e < 4) ? spec_b1 + (size_t)e * HID : sh_b1 + (size_t)(e - 4) * HID;
            const float* b2p = (e < 4) ? spec_b2 + (size_t)e * DIM : sh_b2 + (size_t)(e - 4) * DIM;
            gemm1_dense<<<dim3(HID / 128, NTOK / 128, 1), 256, 0, stream>>>(
                xnb, w1p, 0, b1p, 0, HB, 0);
            gemm2_dense_out<<<dim3(DIM / 128, NTOK / 128, 1), 256, 0, stream>>>(
                HB, w2p, b2p, gates, out, e, e > 0);
        }
    }
}

// Round 5
// 1456.869 us; speedup vs baseline: 8.2408x; 1.0108x over previous
//
#include <hip/hip_runtime.h>
#include <hip/hip_bf16.h>
#include <math.h>

#define NTOK 12544
#define DIM 768
#define HID 3072
#define NSLOT_MAX 25600     // spec slots: 2*NTOK + pad
#define NTILE_MAX 200       // NSLOT_MAX/128
#define NDT 98              // NTOK/128 dense row tiles per shared expert
#define NBKT 64
#define BKTCAP 256

typedef __hip_bfloat16 bf16;
typedef __attribute__((ext_vector_type(8))) short short8v;
typedef __attribute__((ext_vector_type(4))) float f32x4;

#define GPTR(p)  ((const __attribute__((address_space(1))) void*)(p))
#define LDSPTR(p) ((__attribute__((address_space(3))) void*)(p))

// ---------------------------------------------------------------- Router + LN(bf16 out) + bucketed routing lists
__global__ void router_ln_kernel(const float* __restrict__ x,
                                 const float* __restrict__ lng, const float* __restrict__ lnb,
                                 const float* __restrict__ srw, const float* __restrict__ srb,
                                 const float* __restrict__ shw, const float* __restrict__ shb,
                                 bf16* __restrict__ xnb,
                                 float* __restrict__ spec_logits, float* __restrict__ spec_probs,
                                 float* __restrict__ topk_idx, float* __restrict__ topk_probs,
                                 float* __restrict__ sh_logits, float* __restrict__ sh_probs,
                                 float* __restrict__ gates,
                                 int* __restrict__ cnt2, int* __restrict__ tok2,
                                 float* __restrict__ gate2) {
    int t = blockIdx.x * 4 + (threadIdx.x >> 6);
    int bucket = blockIdx.x & (NBKT - 1);
    int lane = threadIdx.x & 63;
    const float* xr = x + (size_t)t * DIM;
    bf16* xb = xnb + (size_t)t * DIM;
    float v[12];
    float s = 0.0f;
    #pragma unroll
    for (int i = 0; i < 12; ++i) { v[i] = xr[lane + 64 * i]; s += v[i]; }
    #pragma unroll
    for (int o = 32; o > 0; o >>= 1) s += __shfl_xor(s, o, 64);
    float mean = s * (1.0f / 768.0f);
    float sq = 0.0f;
    #pragma unroll
    for (int i = 0; i < 12; ++i) { float d = v[i] - mean; sq += d * d; }
    #pragma unroll
    for (int o = 32; o > 0; o >>= 1) sq += __shfl_xor(sq, o, 64);
    float rstd = rsqrtf(sq * (1.0f / 768.0f) + 1e-5f);

    float acc[6] = {0, 0, 0, 0, 0, 0};
    #pragma unroll 4
    for (int i = 0; i < 12; ++i) {
        int d = lane + 64 * i;
        float xv = (v[i] - mean) * rstd * lng[d] + lnb[d];
        xb[d] = __float2bfloat16(xv);
        #pragma unroll
        for (int j = 0; j < 4; ++j) acc[j] += xv * srw[d * 4 + j];
        #pragma unroll
        for (int j = 0; j < 2; ++j) acc[4 + j] += xv * shw[d * 2 + j];
    }
    #pragma unroll
    for (int j = 0; j < 6; ++j) {
        #pragma unroll
        for (int o = 32; o > 0; o >>= 1) acc[j] += __shfl_xor(acc[j], o, 64);
    }
    if (lane == 0) {
        float l[4];
        #pragma unroll
        for (int j = 0; j < 4; ++j) l[j] = acc[j] + srb[j];
        float m = fmaxf(fmaxf(l[0], l[1]), fmaxf(l[2], l[3]));
        float e[4], ssum = 0.0f;
        #pragma unroll
        for (int j = 0; j < 4; ++j) { e[j] = expf(l[j] - m); ssum += e[j]; }
        float inv = 1.0f / ssum;
        float p[4];
        #pragma unroll
        for (int j = 0; j < 4; ++j) p[j] = e[j] * inv;
        int i0 = 0;
        for (int j = 1; j < 4; ++j) if (p[j] > p[i0]) i0 = j;
        int i1 = -1;
        for (int j = 0; j < 4; ++j) {
            if (j == i0) continue;
            if (i1 < 0 || p[j] > p[i1]) i1 = j;
        }
        float sl0 = acc[4] + shb[0], sl1 = acc[5] + shb[1];
        float sm = fmaxf(sl0, sl1);
        float se0 = expf(sl0 - sm), se1 = expf(sl1 - sm);
        float sinv = 1.0f / (se0 + se1);
        float sp0 = se0 * sinv, sp1 = se1 * sinv;

        #pragma unroll
        for (int j = 0; j < 4; ++j) {
            spec_logits[t * 4 + j] = l[j];
            spec_probs[t * 4 + j]  = p[j];
        }
        topk_idx[t * 2 + 0]   = (float)i0;
        topk_idx[t * 2 + 1]   = (float)i1;
        topk_probs[t * 2 + 0] = p[i0];
        topk_probs[t * 2 + 1] = p[i1];
        sh_logits[t * 2 + 0]  = sl0;
        sh_logits[t * 2 + 1]  = sl1;
        sh_probs[t * 2 + 0]   = sp0;
        sh_probs[t * 2 + 1]   = sp1;
        float gg[6] = {0, 0, 0, 0, sp0, sp1};
        gg[i0] = p[i0];
        gg[i1] = p[i1];
        #pragma unroll
        for (int j = 0; j < 6; ++j) gates[t * 6 + j] = gg[j];
        int c0 = i0 * NBKT + bucket;
        int pos0 = atomicAdd(&cnt2[c0], 1);
        tok2[c0 * BKTCAP + pos0]  = t * 2 + 0;
        gate2[c0 * BKTCAP + pos0] = p[i0];
        int c1 = i1 * NBKT + bucket;
        int pos1 = atomicAdd(&cnt2[c1], 1);
        tok2[c1 * BKTCAP + pos1]  = t * 2 + 1;
        gate2[c1 * BKTCAP + pos1] = p[i1];
    }
}

// ---------------------------------------------------------------- plan: parallel bucket scan, fill slots
__global__ void plan_kernel(const int* __restrict__ cnt2, int* __restrict__ e_of_tile,
                            const int* __restrict__ tok2, const float* __restrict__ gate2,
                            int* __restrict__ slot_tok, float* __restrict__ slot_gate,
                            int* __restrict__ back) {
    __shared__ int sbase[4 * NBKT];
    __shared__ int offsE[5];
    __shared__ int etot[4];
    int tid = threadIdx.x, lane = tid & 63, wid = tid >> 6;
    // wave `wid` scans expert `wid`'s 64 buckets
    int c = cnt2[wid * NBKT + lane];
    int inc = c;
    #pragma unroll
    for (int o = 1; o < 64; o <<= 1) {
        int tv = __shfl_up(inc, o, 64);
        if (lane >= o) inc += tv;
    }
    int exc = inc - c;
    if (lane == 63) etot[wid] = inc;
    __syncthreads();
    if (tid == 0) {
        int o = 0;
        for (int e = 0; e < 4; ++e) { offsE[e] = o; o += (etot[e] + 127) & ~127; }
        offsE[4] = o;
    }
    __syncthreads();
    sbase[tid] = offsE[wid] + exc;
    // zero-fill slots
    for (int i = tid; i < NSLOT_MAX; i += 256) {
        slot_tok[i] = 0;
        slot_gate[i] = 0.0f;
    }
    for (int idx = tid; idx < NTILE_MAX; idx += 256) {
        int s0 = idx * 128, e = -1;
        for (int j = 0; j < 4; ++j)
            if (s0 >= offsE[j] && s0 < offsE[j + 1]) e = j;
        e_of_tile[idx] = e;
    }
    __syncthreads();
    // compact bucket tid
    int bs = sbase[tid];
    int cc = cnt2[tid];
    for (int i = 0; i < cc; ++i) {
        int gs = bs + i;
        int tk = tok2[tid * BKTCAP + i];
        slot_tok[gs] = tk >> 1;
        slot_gate[gs] = gate2[tid * BKTCAP + i];
        back[tk] = gs;
    }
}

// ---------------------------------------------------------------- transpose + f32->bf16 (6 experts in one launch)
__global__ __launch_bounds__(256) void conv_w_kernel(const float* __restrict__ spec,
                                                     const float* __restrict__ sh,
                                                     bf16* __restrict__ dst, int R, int C) {
    __shared__ float tile[32][33];
    int z = blockIdx.z;
    const float* ip = (z < 4) ? spec + (size_t)z * R * C : sh + (size_t)(z - 4) * R * C;
    bf16* op = dst + (size_t)z * R * C;
    int r0 = blockIdx.y * 32, c0 = blockIdx.x * 32;
    int tx = threadIdx.x & 31, ty = threadIdx.x >> 5;
    #pragma unroll
    for (int i = 0; i < 32; i += 8)
        tile[ty + i][tx] = ip[(size_t)(r0 + ty + i) * C + c0 + tx];
    __syncthreads();
    #pragma unroll
    for (int i = 0; i < 32; i += 8)
        op[(size_t)(c0 + ty + i) * R + r0 + tx] = __float2bfloat16(tile[tx][ty + i]);
}

// ---------------------------------------------------------------- MFMA helpers
__device__ __forceinline__ void stage_tile(const bf16* __restrict__ g, int ldg,
                                           bf16* lds, int tid) {
    int wave = tid >> 6, lane = tid & 63;
    #pragma unroll
    for (int q = 0; q < 2; ++q) {
        int chunk = wave * 2 + q;
        int row = chunk * 16 + (lane >> 2);
        int col = (lane & 3) * 8;
        __builtin_amdgcn_global_load_lds(GPTR(g + (size_t)row * ldg + col),
                                         LDSPTR(lds + chunk * 512), 16, 0, 0);
    }
}

__device__ __forceinline__ void mfma_step(const bf16* As, const bf16* Bs,
                                          int wr, int wc, int fr, int fq, f32x4 acc[4][4]) {
    short8v a[4], b[4];
    #pragma unroll
    for (int i = 0; i < 4; ++i) {
        a[i] = *(const short8v*)&As[(wr * 64 + i * 16 + fr) * 32 + fq * 8];
        b[i] = *(const short8v*)&Bs[(wc * 64 + i * 16 + fr) * 32 + fq * 8];
    }
    #pragma unroll
    for (int i = 0; i < 4; ++i)
        #pragma unroll
        for (int j = 0; j < 4; ++j)
            acc[i][j] = __builtin_amdgcn_mfma_f32_16x16x32_bf16(a[i], b[j], acc[i][j], 0, 0, 0);
}

__device__ __forceinline__ float gelu_exact(float v) {
    return 0.5f * v * (1.0f + erff(v * 0.70710678118654752f));
}

// ---------------------------------------------------------------- GEMM1 unified: y<NTILE_MAX -> grouped spec, else dense shared
__global__ __launch_bounds__(256) void gemm1_all(
    const bf16* __restrict__ xnb, const bf16* __restrict__ w1t,
    const float* __restrict__ spec_b1, const float* __restrict__ sh_b1,
    const int* __restrict__ e_of_tile, const int* __restrict__ slot_tok,
    bf16* __restrict__ Hspec, bf16* __restrict__ Hsh, int y_base) {
    int y = blockIdx.y + y_base;
    int tid = threadIdx.x;
    int wid = tid >> 6, lane = tid & 63;
    int wr = wid >> 1, wc = wid & 1;
    int fr = lane & 15, fq = lane >> 4;

    const bf16* Bg;
    const float* bias;
    bf16* hbase;
    bool grouped = (y < NTILE_MAX);
    int tokbase = 0;
    int e;
    if (grouped) {
        e = e_of_tile[y];
        if (e < 0) return;
        Bg = w1t + (size_t)e * HID * DIM + (size_t)(blockIdx.x * 128) * DIM;
        bias = spec_b1 + (size_t)e * HID;
        hbase = Hspec + (size_t)y * 128 * HID;
    } else {
        int ys = y - NTILE_MAX;
        int z = ys / NDT, ry = ys % NDT;
        Bg = w1t + (size_t)(4 + z) * HID * DIM + (size_t)(blockIdx.x * 128) * DIM;
        bias = sh_b1 + (size_t)z * HID;
        hbase = Hsh + (size_t)(z * NTOK + ry * 128) * HID;
        tokbase = ry * 128;
    }

    __shared__ bf16 As[128 * 32];
    __shared__ bf16 Bs[128 * 32];
    // per-lane A gather sources (grouped: via slot_tok; dense: identity)
    const bf16* asrc[2];
    #pragma unroll
    for (int q = 0; q < 2; ++q) {
        int r = (wid * 2 + q) * 16 + (lane >> 2);
        int tok = grouped ? slot_tok[y * 128 + r] : tokbase + r;
        asrc[q] = xnb + (size_t)tok * DIM + (lane & 3) * 8;
    }
    f32x4 acc[4][4] = {};
    for (int k0 = 0; k0 < DIM; k0 += 32) {
        #pragma unroll
        for (int q = 0; q < 2; ++q)
            __builtin_amdgcn_global_load_lds(GPTR(asrc[q] + k0),
                                             LDSPTR(As + (wid * 2 + q) * 512), 16, 0, 0);
        stage_tile(Bg + k0, DIM, Bs, tid);
        __syncthreads();
        mfma_step(As, Bs, wr, wc, fr, fq, acc);
        __syncthreads();
    }
    int rbase = wr * 64;
    int cbase = blockIdx.x * 128 + wc * 64;
    #pragma unroll
    for (int j = 0; j < 4; ++j) {
        int col = cbase + j * 16 + fr;
        float bv = bias[col];
        #pragma unroll
        for (int i = 0; i < 4; ++i)
            #pragma unroll
            for (int r = 0; r < 4; ++r) {
                int row = rbase + i * 16 + fq * 4 + r;
                hbase[(size_t)row * HID + col] = __float2bfloat16(gelu_exact(acc[i][j][r] + bv));
            }
    }
}

// ---------------------------------------------------------------- GEMM2 unified -> gated bf16 partials
__global__ __launch_bounds__(256) void gemm2_all(
    const bf16* __restrict__ Hspec, const bf16* __restrict__ Hsh,
    const bf16* __restrict__ w2t,
    const float* __restrict__ spec_b2, const float* __restrict__ sh_b2,
    const int* __restrict__ e_of_tile, const float* __restrict__ slot_gate,
    const float* __restrict__ sh_probs,
    bf16* __restrict__ spec_g, bf16* __restrict__ shg, int y_base) {
    int y = blockIdx.y + y_base;
    int tid = threadIdx.x;
    int wid = tid >> 6, lane = tid & 63;
    int wr = wid >> 1, wc = wid & 1;
    int fr = lane & 15, fq = lane >> 4;

    const bf16* Ag;
    const bf16* Bg;
    const float* bias;
    bf16* obase;
    bool grouped = (y < NTILE_MAX);
    int z = 0, ry = 0;
    if (grouped) {
        int e = e_of_tile[y];
        if (e < 0) return;
        Ag = Hspec + (size_t)y * 128 * HID;
        Bg = w2t + (size_t)e * DIM * HID + (size_t)(blockIdx.x * 128) * HID;
        bias = spec_b2 + (size_t)e * DIM;
        obase = spec_g + (size_t)y * 128 * DIM;
    } else {
        int ys = y - NTILE_MAX;
        z = ys / NDT; ry = ys % NDT;
        Ag = Hsh + (size_t)(z * NTOK + ry * 128) * HID;
        Bg = w2t + (size_t)(4 + z) * DIM * HID + (size_t)(blockIdx.x * 128) * HID;
        bias = sh_b2 + (size_t)z * DIM;
        obase = shg + (size_t)(z * NTOK + ry * 128) * DIM;
    }

    __shared__ bf16 As[128 * 32];
    __shared__ bf16 Bs[128 * 32];
    f32x4 acc[4][4] = {};
    for (int k0 = 0; k0 < HID; k0 += 32) {
        stage_tile(Ag + k0, HID, As, tid);
        stage_tile(Bg + k0, HID, Bs, tid);
        __syncthreads();
        mfma_step(As, Bs, wr, wc, fr, fq, acc);
        __syncthreads();
    }
    int rbase = wr * 64;
    int cbase = blockIdx.x * 128 + wc * 64;
    #pragma unroll
    for (int j = 0; j < 4; ++j) {
        int col = cbase + j * 16 + fr;
        float bv = bias[col];
        #pragma unroll
        for (int i = 0; i < 4; ++i)
            #pragma unroll
            for (int r = 0; r < 4; ++r) {
                int row = rbase + i * 16 + fq * 4 + r;
                float g = grouped ? slot_gate[y * 128 + row]
                                  : sh_probs[(size_t)(ry * 128 + row) * 2 + z];
                obase[(size_t)row * DIM + col] = __float2bfloat16(g * (acc[i][j][r] + bv));
            }
    }
}

// ---------------------------------------------------------------- plan-B dense kernels (fallback only)
__global__ __launch_bounds__(256) void gemm1_dense(
    const bf16* __restrict__ A, const bf16* __restrict__ BT,
    const float* __restrict__ bias, bf16* __restrict__ H) {
    __shared__ bf16 As[128 * 32];
    __shared__ bf16 Bs[128 * 32];
    int tid = threadIdx.x;
    int wid = tid >> 6, lane = tid & 63;
    int wr = wid >> 1, wc = wid & 1;
    int fr = lane & 15, fq = lane >> 4;
    const bf16* Ag = A + (size_t)(blockIdx.y * 128) * DIM;
    const bf16* Bg = BT + (size_t)(blockIdx.x * 128) * DIM;
    f32x4 acc[4][4] = {};
    for (int k0 = 0; k0 < DIM; k0 += 32) {
        stage_tile(Ag + k0, DIM, As, tid);
        stage_tile(Bg + k0, DIM, Bs, tid);
        __syncthreads();
        mfma_step(As, Bs, wr, wc, fr, fq, acc);
        __syncthreads();
    }
    int rbase = blockIdx.y * 128 + wr * 64;
    int cbase = blockIdx.x * 128 + wc * 64;
    #pragma unroll
    for (int j = 0; j < 4; ++j) {
        int col = cbase + j * 16 + fr;
        float bv = bias[col];
        #pragma unroll
        for (int i = 0; i < 4; ++i)
            #pragma unroll
            for (int r = 0; r < 4; ++r) {
                int row = rbase + i * 16 + fq * 4 + r;
                H[(size_t)row * HID + col] = __float2bfloat16(gelu_exact(acc[i][j][r] + bv));
            }
    }
}

__global__ __launch_bounds__(256) void gemm2_dense_out(
    const bf16* __restrict__ A, const bf16* __restrict__ BT,
    const float* __restrict__ bias, const float* __restrict__ gates,
    float* __restrict__ out, int gidx, int accum) {
    __shared__ bf16 As[128 * 32];
    __shared__ bf16 Bs[128 * 32];
    int tid = threadIdx.x;
    int wid = tid >> 6, lane = tid & 63;
    int wr = wid >> 1, wc = wid & 1;
    int fr = lane & 15, fq = lane >> 4;
    const bf16* Ag = A + (size_t)(blockIdx.y * 128) * HID;
    const bf16* Bg = BT + (size_t)(blockIdx.x * 128) * HID;
    f32x4 acc[4][4] = {};
    for (int k0 = 0; k0 < HID; k0 += 32) {
        stage_tile(Ag + k0, HID, As, tid);
        stage_tile(Bg + k0, HID, Bs, tid);
        __syncthreads();
        mfma_step(As, Bs, wr, wc, fr, fq, acc);
        __syncthreads();
    }
    int rbase = blockIdx.y * 128 + wr * 64;
    int cbase = blockIdx.x * 128 + wc * 64;
    #pragma unroll
    for (int j = 0; j < 4; ++j) {
        int col = cbase + j * 16 + fr;
        float bv = bias[col];
        #pragma unroll
        for (int i = 0; i < 4; ++i)
            #pragma unroll
            for (int r = 0; r < 4; ++r) {
                int row = rbase + i * 16 + fq * 4 + r;
                float g = gates[(size_t)row * 6 + gidx];
                float v = g * (acc[i][j][r] + bv);
                size_t idx = (size_t)row * DIM + col;
                out[idx] = accum ? out[idx] + v : v;
            }
    }
}

// ---------------------------------------------------------------- combine
__global__ void combine_kernel(const bf16* __restrict__ spec_g, const bf16* __restrict__ shg,
                               const int* __restrict__ back, float* __restrict__ out) {
    int t = blockIdx.x;
    int b0 = back[2 * t], b1 = back[2 * t + 1];
    const bf16* p0 = spec_g + (size_t)b0 * DIM;
    const bf16* p1 = spec_g + (size_t)b1 * DIM;
    const bf16* s0 = shg + (size_t)t * DIM;
    const bf16* s1 = shg + (size_t)NTOK * DIM + (size_t)t * DIM;
    #pragma unroll
    for (int i = 0; i < 3; ++i) {
        int c = threadIdx.x + 256 * i;
        out[(size_t)t * DIM + c] = __bfloat162float(p0[c]) + __bfloat162float(p1[c]) +
                                   __bfloat162float(s0[c]) + __bfloat162float(s1[c]);
    }
}

// ---------------------------------------------------------------- launch
static inline size_t align256(size_t x) { return (x + 255) & ~(size_t)255; }

extern "C" void kernel_launch(void* const* d_in, const int* in_sizes, int n_in,
                              void* d_out, int out_size, void* d_ws, size_t ws_size,
                              hipStream_t stream) {
    const float* x      = (const float*)d_in[0];
    const float* gamma  = (const float*)d_in[1];
    const float* beta   = (const float*)d_in[2];
    const float* srw    = (const float*)d_in[3];
    const float* srb    = (const float*)d_in[4];
    const float* spec_w1 = (const float*)d_in[5];
    const float* spec_b1 = (const float*)d_in[6];
    const float* spec_w2 = (const float*)d_in[7];
    const float* spec_b2 = (const float*)d_in[8];
    const float* shw    = (const float*)d_in[9];
    const float* shb    = (const float*)d_in[10];
    const float* sh_w1  = (const float*)d_in[11];
    const float* sh_b1  = (const float*)d_in[12];
    const float* sh_w2  = (const float*)d_in[13];
    const float* sh_b2  = (const float*)d_in[14];

    // ---- workspace carve-up (common head)
    char* p = (char*)d_ws;
    size_t off = 0;
    bf16* xnb = (bf16*)(p + off);       off = align256(off + (size_t)NTOK * DIM * 2);
    bf16* w1t = (bf16*)(p + off);       off = align256(off + (size_t)6 * HID * DIM * 2);
    bf16* w2t = (bf16*)(p + off);       off = align256(off + (size_t)6 * DIM * HID * 2);
    int*  cnt2 = (int*)(p + off);       off = align256(off + (size_t)4 * NBKT * 4);
    float* gates = (float*)(p + off);   off = align256(off + (size_t)NTOK * 6 * 4);
    int*  tok2 = (int*)(p + off);       off = align256(off + (size_t)4 * NBKT * BKTCAP * 4);
    float* gate2 = (float*)(p + off);   off = align256(off + (size_t)4 * NBKT * BKTCAP * 4);
    int*  slot_tok = (int*)(p + off);   off = align256(off + (size_t)NSLOT_MAX * 4);
    float* slot_gate = (float*)(p + off); off = align256(off + (size_t)NSLOT_MAX * 4);
    int*  back = (int*)(p + off);       off = align256(off + (size_t)2 * NTOK * 4);
    int*  e_of_tile = (int*)(p + off);  off = align256(off + (size_t)NTILE_MAX * 4);
    size_t off_common = off;

    // plan A2: Hspec and Hsh coexist (2 merged GEMM launches)
    size_t offA2 = off_common;
    bf16* Hspec2 = (bf16*)(p + offA2);  offA2 = align256(offA2 + (size_t)NSLOT_MAX * HID * 2);
    bf16* Hsh2   = (bf16*)(p + offA2);  offA2 = align256(offA2 + (size_t)2 * NTOK * HID * 2);
    bf16* spec_g2 = (bf16*)(p + offA2); offA2 = align256(offA2 + (size_t)NSLOT_MAX * DIM * 2);
    bf16* shg2   = (bf16*)(p + offA2);  offA2 = align256(offA2 + (size_t)2 * NTOK * DIM * 2);
    size_t need_A2 = offA2;

    // plan A: Hsh aliases Hspec (4 GEMM launches, serialized reuse)
    size_t offA = off_common;
    bf16* HspecA = (bf16*)(p + offA);   offA = align256(offA + (size_t)NSLOT_MAX * HID * 2);
    bf16* spec_gA = (bf16*)(p + offA);  offA = align256(offA + (size_t)NSLOT_MAX * DIM * 2);
    bf16* shgA   = (bf16*)(p + offA);   offA = align256(offA + (size_t)2 * NTOK * DIM * 2);
    size_t need_A = offA;

    // d_out layout (flat concat, all f32)
    float* out         = (float*)d_out;
    float* spec_logits = out + (size_t)NTOK * DIM;
    float* spec_probs  = spec_logits + (size_t)NTOK * 4;
    float* topk_idx    = spec_probs  + (size_t)NTOK * 4;
    float* topk_probs  = topk_idx    + (size_t)NTOK * 2;
    float* sh_logits   = topk_probs  + (size_t)NTOK * 2;
    float* sh_probs    = sh_logits   + (size_t)NTOK * 2;

    hipMemsetAsync(cnt2, 0, (size_t)4 * NBKT * 4, stream);

    // weights: transpose + bf16 (2 launches)
    conv_w_kernel<<<dim3(HID / 32, DIM / 32, 6), 256, 0, stream>>>(spec_w1, sh_w1, w1t, DIM, HID);
    conv_w_kernel<<<dim3(DIM / 32, HID / 32, 6), 256, 0, stream>>>(spec_w2, sh_w2, w2t, HID, DIM);

    router_ln_kernel<<<NTOK / 4, 256, 0, stream>>>(x, gamma, beta, srw, srb, shw, shb, xnb,
                                                   spec_logits, spec_probs, topk_idx,
                                                   topk_probs, sh_logits, sh_probs, gates,
                                                   cnt2, tok2, gate2);

    if (ws_size >= need_A2) {
        plan_kernel<<<1, 256, 0, stream>>>(cnt2, e_of_tile, tok2, gate2,
                                           slot_tok, slot_gate, back);
        gemm1_all<<<dim3(HID / 128, NTILE_MAX + 2 * NDT), 256, 0, stream>>>(
            xnb, w1t, spec_b1, sh_b1, e_of_tile, slot_tok, Hspec2, Hsh2, 0);
        gemm2_all<<<dim3(DIM / 128, NTILE_MAX + 2 * NDT), 256, 0, stream>>>(
            Hspec2, Hsh2, w2t, spec_b2, sh_b2, e_of_tile, slot_gate, sh_probs,
            spec_g2, shg2, 0);
        combine_kernel<<<NTOK, 256, 0, stream>>>(spec_g2, shg2, back, out);
    } else if (ws_size >= need_A) {
        plan_kernel<<<1, 256, 0, stream>>>(cnt2, e_of_tile, tok2, gate2,
                                           slot_tok, slot_gate, back);
        // grouped spec chain, then shared chain reusing Hspec
        gemm1_all<<<dim3(HID / 128, NTILE_MAX), 256, 0, stream>>>(
            xnb, w1t, spec_b1, sh_b1, e_of_tile, slot_tok, HspecA, HspecA, 0);
        gemm2_all<<<dim3(DIM / 128, NTILE_MAX), 256, 0, stream>>>(
            HspecA, HspecA, w2t, spec_b2, sh_b2, e_of_tile, slot_gate, sh_probs,
            spec_gA, shgA, 0);
        gemm1_all<<<dim3(HID / 128, 2 * NDT), 256, 0, stream>>>(
            xnb, w1t, spec_b1, sh_b1, e_of_tile, slot_tok, HspecA, HspecA, NTILE_MAX);
        gemm2_all<<<dim3(DIM / 128, 2 * NDT), 256, 0, stream>>>(
            HspecA, HspecA, w2t, spec_b2, sh_b2, e_of_tile, slot_gate, sh_probs,
            spec_gA, shgA, NTILE_MAX);
        combine_kernel<<<NTOK, 256, 0, stream>>>(spec_gA, shgA, back, out);
    } else {
        // plan B: dense 6-expert loop
        bf16* HB = (bf16*)(p + off_common);
        for (int e = 0; e < 6; ++e) {
            const bf16* w1p = w1t + (size_t)e * HID * DIM;
            const bf16* w2p = w2t + (size_t)e * DIM * HID;
            const float* b1p = (e < 4) ? spec_b1 + (size_t)e * HID : sh_b1 + (size_t)(e - 4) * HID;
            const float* b2p = (e < 4) ? spec_b2 + (size_t)e * DIM : sh_b2 + (size_t)(e - 4) * DIM;
            gemm1_dense<<<dim3(HID / 128, NTOK / 128), 256, 0, stream>>>(xnb, w1p, b1p, HB);
            gemm2_dense_out<<<dim3(DIM / 128, NTOK / 128), 256, 0, stream>>>(
                HB, w2p, b2p, gates, out, e, e > 0);
        }
    }
}

// Round 6
// 1436.226 us; speedup vs baseline: 8.3593x; 1.0144x over previous
//
#include <hip/hip_runtime.h>
#include <hip/hip_bf16.h>
#include <math.h>

#define NTOK 12544
#define DIM 768
#define HID 3072
#define NSLOT_MAX 25600     // spec slots: 2*NTOK + pad
#define NTILE_MAX 200       // NSLOT_MAX/128
#define NDT 98              // NTOK/128 dense row tiles per shared expert
#define NBKT 64
#define BKTCAP 256

typedef __hip_bfloat16 bf16;
typedef __attribute__((ext_vector_type(8))) short short8v;
typedef __attribute__((ext_vector_type(4))) float f32x4;

#define GPTR(p)  ((const __attribute__((address_space(1))) void*)(p))
#define LDSPTR(p) ((__attribute__((address_space(3))) void*)(p))

// ---------------------------------------------------------------- conv: all 12 weight matrices, transpose + f32->bf16
// z<6: w1[e] [DIM][HID] -> w1t[e] [HID][DIM]; z>=6: w2[e] [HID][DIM] -> w2t[e] [DIM][HID]
// also zero-fills cnt2 and slot arrays (replaces memset + plan zero-fill)
__global__ __launch_bounds__(256) void conv_all_kernel(
    const float* __restrict__ spec_w1, const float* __restrict__ sh_w1,
    const float* __restrict__ spec_w2, const float* __restrict__ sh_w2,
    bf16* __restrict__ w1t, bf16* __restrict__ w2t,
    int* __restrict__ cnt2, int* __restrict__ slot_tok, float* __restrict__ slot_gate) {
    int z = blockIdx.y;
    int ti = blockIdx.x;
    int t = threadIdx.x;
    if (z == 0) {
        if (ti == 0) cnt2[t] = 0;
        if (ti < 100) {
            int s = ti * 256 + t;
            if (s < NSLOT_MAX) { slot_tok[s] = 0; slot_gate[s] = 0.0f; }
        }
    }
    const float* src; bf16* dst; int R, C, tr, tc;
    if (z < 6) {
        R = DIM; C = HID;
        src = (z < 4) ? spec_w1 + (size_t)z * R * C : sh_w1 + (size_t)(z - 4) * R * C;
        dst = w1t + (size_t)z * R * C;
        tr = ti % 12; tc = ti / 12;
    } else {
        int e = z - 6;
        R = HID; C = DIM;
        src = (e < 4) ? spec_w2 + (size_t)e * R * C : sh_w2 + (size_t)(e - 4) * R * C;
        dst = w2t + (size_t)e * R * C;
        tr = ti % 48; tc = ti / 48;
    }
    __shared__ float tile[64][65];
    int r0 = tr * 64, c0 = tc * 64;
    int lr = t >> 4, lc = (t & 15) * 4;
    #pragma unroll
    for (int ii = 0; ii < 4; ++ii) {
        float4 v = *(const float4*)&src[(size_t)(r0 + lr + 16 * ii) * C + c0 + lc];
        tile[lc + 0][lr + 16 * ii] = v.x;   // store transposed into LDS
        tile[lc + 1][lr + 16 * ii] = v.y;
        tile[lc + 2][lr + 16 * ii] = v.z;
        tile[lc + 3][lr + 16 * ii] = v.w;
    }
    __syncthreads();
    // output row = original col; thread writes 4 consecutive output elems (orig rows)
    int oc = t >> 4, orr = (t & 15) * 4;
    #pragma unroll
    for (int ii = 0; ii < 4; ++ii) {
        union { ushort4 u4; bf16 h[4]; } pk;
        #pragma unroll
        for (int k = 0; k < 4; ++k)
            pk.h[k] = __float2bfloat16(tile[oc + 16 * ii][orr + k]);
        *(ushort4*)&dst[(size_t)(c0 + oc + 16 * ii) * R + r0 + orr] = pk.u4;
    }
}

// ---------------------------------------------------------------- Router + LN(bf16 out) + bucketed routing lists
__global__ void router_ln_kernel(const float* __restrict__ x,
                                 const float* __restrict__ lng, const float* __restrict__ lnb,
                                 const float* __restrict__ srw, const float* __restrict__ srb,
                                 const float* __restrict__ shw, const float* __restrict__ shb,
                                 bf16* __restrict__ xnb,
                                 float* __restrict__ spec_logits, float* __restrict__ spec_probs,
                                 float* __restrict__ topk_idx, float* __restrict__ topk_probs,
                                 float* __restrict__ sh_logits, float* __restrict__ sh_probs,
                                 float* __restrict__ gates,
                                 int* __restrict__ cnt2, int* __restrict__ tok2,
                                 float* __restrict__ gate2) {
    int t = blockIdx.x * 4 + (threadIdx.x >> 6);
    int bucket = blockIdx.x & (NBKT - 1);
    int lane = threadIdx.x & 63;
    const float* xr = x + (size_t)t * DIM;
    bf16* xb = xnb + (size_t)t * DIM;
    float v[12];
    float s = 0.0f;
    #pragma unroll
    for (int i = 0; i < 6; ++i) {
        float2 xv = *(const float2*)&xr[lane * 2 + 128 * i];
        v[2 * i] = xv.x; v[2 * i + 1] = xv.y;
        s += xv.x + xv.y;
    }
    #pragma unroll
    for (int o = 32; o > 0; o >>= 1) s += __shfl_xor(s, o, 64);
    float mean = s * (1.0f / 768.0f);
    float sq = 0.0f;
    #pragma unroll
    for (int i = 0; i < 12; ++i) { float d = v[i] - mean; sq += d * d; }
    #pragma unroll
    for (int o = 32; o > 0; o >>= 1) sq += __shfl_xor(sq, o, 64);
    float rstd = rsqrtf(sq * (1.0f / 768.0f) + 1e-5f);

    float acc[6] = {0, 0, 0, 0, 0, 0};
    #pragma unroll
    for (int i = 0; i < 6; ++i) {
        int d0 = lane * 2 + 128 * i;
        float xn0 = (v[2 * i]     - mean) * rstd * lng[d0]     + lnb[d0];
        float xn1 = (v[2 * i + 1] - mean) * rstd * lng[d0 + 1] + lnb[d0 + 1];
        union { unsigned u; bf16 h[2]; } pk;
        pk.h[0] = __float2bfloat16(xn0);
        pk.h[1] = __float2bfloat16(xn1);
        *(unsigned*)&xb[d0] = pk.u;
        float4 a = *(const float4*)&srw[d0 * 4];
        float4 b = *(const float4*)&srw[d0 * 4 + 4];
        acc[0] += xn0 * a.x + xn1 * b.x;
        acc[1] += xn0 * a.y + xn1 * b.y;
        acc[2] += xn0 * a.z + xn1 * b.z;
        acc[3] += xn0 * a.w + xn1 * b.w;
        float4 sw = *(const float4*)&shw[d0 * 2];
        acc[4] += xn0 * sw.x + xn1 * sw.z;
        acc[5] += xn0 * sw.y + xn1 * sw.w;
    }
    #pragma unroll
    for (int j = 0; j < 6; ++j) {
        #pragma unroll
        for (int o = 32; o > 0; o >>= 1) acc[j] += __shfl_xor(acc[j], o, 64);
    }
    if (lane == 0) {
        float l[4];
        #pragma unroll
        for (int j = 0; j < 4; ++j) l[j] = acc[j] + srb[j];
        float m = fmaxf(fmaxf(l[0], l[1]), fmaxf(l[2], l[3]));
        float e[4], ssum = 0.0f;
        #pragma unroll
        for (int j = 0; j < 4; ++j) { e[j] = expf(l[j] - m); ssum += e[j]; }
        float inv = 1.0f / ssum;
        float p[4];
        #pragma unroll
        for (int j = 0; j < 4; ++j) p[j] = e[j] * inv;
        int i0 = 0;
        for (int j = 1; j < 4; ++j) if (p[j] > p[i0]) i0 = j;
        int i1 = -1;
        for (int j = 0; j < 4; ++j) {
            if (j == i0) continue;
            if (i1 < 0 || p[j] > p[i1]) i1 = j;
        }
        float sl0 = acc[4] + shb[0], sl1 = acc[5] + shb[1];
        float sm = fmaxf(sl0, sl1);
        float se0 = expf(sl0 - sm), se1 = expf(sl1 - sm);
        float sinv = 1.0f / (se0 + se1);
        float sp0 = se0 * sinv, sp1 = se1 * sinv;

        #pragma unroll
        for (int j = 0; j < 4; ++j) {
            spec_logits[t * 4 + j] = l[j];
            spec_probs[t * 4 + j]  = p[j];
        }
        topk_idx[t * 2 + 0]   = (float)i0;
        topk_idx[t * 2 + 1]   = (float)i1;
        topk_probs[t * 2 + 0] = p[i0];
        topk_probs[t * 2 + 1] = p[i1];
        sh_logits[t * 2 + 0]  = sl0;
        sh_logits[t * 2 + 1]  = sl1;
        sh_probs[t * 2 + 0]   = sp0;
        sh_probs[t * 2 + 1]   = sp1;
        float gg[6] = {0, 0, 0, 0, sp0, sp1};
        gg[i0] = p[i0];
        gg[i1] = p[i1];
        #pragma unroll
        for (int j = 0; j < 6; ++j) gates[t * 6 + j] = gg[j];
        int c0 = i0 * NBKT + bucket;
        int pos0 = atomicAdd(&cnt2[c0], 1);
        tok2[c0 * BKTCAP + pos0]  = t * 2 + 0;
        gate2[c0 * BKTCAP + pos0] = p[i0];
        int c1 = i1 * NBKT + bucket;
        int pos1 = atomicAdd(&cnt2[c1], 1);
        tok2[c1 * BKTCAP + pos1]  = t * 2 + 1;
        gate2[c1 * BKTCAP + pos1] = p[i1];
    }
}

// ---------------------------------------------------------------- plan: parallel bucket scan, compact (no zero-fill)
__global__ void plan_kernel(const int* __restrict__ cnt2, int* __restrict__ e_of_tile,
                            const int* __restrict__ tok2, const float* __restrict__ gate2,
                            int* __restrict__ slot_tok, float* __restrict__ slot_gate,
                            int* __restrict__ back) {
    __shared__ int sbase[4 * NBKT];
    __shared__ int offsE[5];
    __shared__ int etot[4];
    int tid = threadIdx.x, lane = tid & 63, wid = tid >> 6;
    int c = cnt2[wid * NBKT + lane];
    int inc = c;
    #pragma unroll
    for (int o = 1; o < 64; o <<= 1) {
        int tv = __shfl_up(inc, o, 64);
        if (lane >= o) inc += tv;
    }
    int exc = inc - c;
    if (lane == 63) etot[wid] = inc;
    __syncthreads();
    if (tid == 0) {
        int o = 0;
        for (int e = 0; e < 4; ++e) { offsE[e] = o; o += (etot[e] + 127) & ~127; }
        offsE[4] = o;
    }
    __syncthreads();
    sbase[tid] = offsE[wid] + exc;
    for (int idx = tid; idx < NTILE_MAX; idx += 256) {
        int s0 = idx * 128, e = -1;
        for (int j = 0; j < 4; ++j)
            if (s0 >= offsE[j] && s0 < offsE[j + 1]) e = j;
        e_of_tile[idx] = e;
    }
    __syncthreads();
    int bs = sbase[tid];
    int cc = cnt2[tid];
    for (int i = 0; i < cc; ++i) {
        int gs = bs + i;
        int tk = tok2[tid * BKTCAP + i];
        slot_tok[gs] = tk >> 1;
        slot_gate[gs] = gate2[tid * BKTCAP + i];
        back[tk] = gs;
    }
}

// ---------------------------------------------------------------- MFMA helpers
__device__ __forceinline__ void stage_tile(const bf16* __restrict__ g, int ldg,
                                           bf16* lds, int tid) {
    int wave = tid >> 6, lane = tid & 63;
    #pragma unroll
    for (int q = 0; q < 2; ++q) {
        int chunk = wave * 2 + q;
        int row = chunk * 16 + (lane >> 2);
        int col = (lane & 3) * 8;
        __builtin_amdgcn_global_load_lds(GPTR(g + (size_t)row * ldg + col),
                                         LDSPTR(lds + chunk * 512), 16, 0, 0);
    }
}

__device__ __forceinline__ void mfma_step(const bf16* As, const bf16* Bs,
                                          int wr, int wc, int fr, int fq, f32x4 acc[4][4]) {
    short8v a[4], b[4];
    #pragma unroll
    for (int i = 0; i < 4; ++i) {
        a[i] = *(const short8v*)&As[(wr * 64 + i * 16 + fr) * 32 + fq * 8];
        b[i] = *(const short8v*)&Bs[(wc * 64 + i * 16 + fr) * 32 + fq * 8];
    }
    #pragma unroll
    for (int i = 0; i < 4; ++i)
        #pragma unroll
        for (int j = 0; j < 4; ++j)
            acc[i][j] = __builtin_amdgcn_mfma_f32_16x16x32_bf16(a[i], b[j], acc[i][j], 0, 0, 0);
}

__device__ __forceinline__ float gelu_exact(float v) {
    return 0.5f * v * (1.0f + erff(v * 0.70710678118654752f));
}

// ---------------------------------------------------------------- GEMM1 unified: y<NTILE_MAX -> grouped spec, else dense shared
__global__ __launch_bounds__(256) void gemm1_all(
    const bf16* __restrict__ xnb, const bf16* __restrict__ w1t,
    const float* __restrict__ spec_b1, const float* __restrict__ sh_b1,
    const int* __restrict__ e_of_tile, const int* __restrict__ slot_tok,
    bf16* __restrict__ Hspec, bf16* __restrict__ Hsh, int y_base) {
    int y = blockIdx.y + y_base;
    int tid = threadIdx.x;
    int wid = tid >> 6, lane = tid & 63;
    int wr = wid >> 1, wc = wid & 1;
    int fr = lane & 15, fq = lane >> 4;

    const bf16* Bg;
    const float* bias;
    bf16* hbase;
    bool grouped = (y < NTILE_MAX);
    int tokbase = 0;
    int e;
    if (grouped) {
        e = e_of_tile[y];
        if (e < 0) return;
        Bg = w1t + (size_t)e * HID * DIM + (size_t)(blockIdx.x * 128) * DIM;
        bias = spec_b1 + (size_t)e * HID;
        hbase = Hspec + (size_t)y * 128 * HID;
    } else {
        int ys = y - NTILE_MAX;
        int z = ys / NDT, ry = ys % NDT;
        Bg = w1t + (size_t)(4 + z) * HID * DIM + (size_t)(blockIdx.x * 128) * DIM;
        bias = sh_b1 + (size_t)z * HID;
        hbase = Hsh + (size_t)(z * NTOK + ry * 128) * HID;
        tokbase = ry * 128;
    }

    __shared__ bf16 As[128 * 32];
    __shared__ bf16 Bs[128 * 32];
    const bf16* asrc[2];
    #pragma unroll
    for (int q = 0; q < 2; ++q) {
        int r = (wid * 2 + q) * 16 + (lane >> 2);
        int tok = grouped ? slot_tok[y * 128 + r] : tokbase + r;
        asrc[q] = xnb + (size_t)tok * DIM + (lane & 3) * 8;
    }
    f32x4 acc[4][4] = {};
    for (int k0 = 0; k0 < DIM; k0 += 32) {
        #pragma unroll
        for (int q = 0; q < 2; ++q)
            __builtin_amdgcn_global_load_lds(GPTR(asrc[q] + k0),
                                             LDSPTR(As + (wid * 2 + q) * 512), 16, 0, 0);
        stage_tile(Bg + k0, DIM, Bs, tid);
        __syncthreads();
        mfma_step(As, Bs, wr, wc, fr, fq, acc);
        __syncthreads();
    }
    int rbase = wr * 64;
    int cbase = blockIdx.x * 128 + wc * 64;
    #pragma unroll
    for (int j = 0; j < 4; ++j) {
        int col = cbase + j * 16 + fr;
        float bv = bias[col];
        #pragma unroll
        for (int i = 0; i < 4; ++i)
            #pragma unroll
            for (int r = 0; r < 4; ++r) {
                int row = rbase + i * 16 + fq * 4 + r;
                hbase[(size_t)row * HID + col] = __float2bfloat16(gelu_exact(acc[i][j][r] + bv));
            }
    }
}

// ---------------------------------------------------------------- GEMM2 unified -> gated bf16 partials
__global__ __launch_bounds__(256) void gemm2_all(
    const bf16* __restrict__ Hspec, const bf16* __restrict__ Hsh,
    const bf16* __restrict__ w2t,
    const float* __restrict__ spec_b2, const float* __restrict__ sh_b2,
    const int* __restrict__ e_of_tile, const float* __restrict__ slot_gate,
    const float* __restrict__ sh_probs,
    bf16* __restrict__ spec_g, bf16* __restrict__ shg, int y_base) {
    int y = blockIdx.y + y_base;
    int tid = threadIdx.x;
    int wid = tid >> 6, lane = tid & 63;
    int wr = wid >> 1, wc = wid & 1;
    int fr = lane & 15, fq = lane >> 4;

    const bf16* Ag;
    const bf16* Bg;
    const float* bias;
    bf16* obase;
    bool grouped = (y < NTILE_MAX);
    int z = 0, ry = 0;
    if (grouped) {
        int e = e_of_tile[y];
        if (e < 0) return;
        Ag = Hspec + (size_t)y * 128 * HID;
        Bg = w2t + (size_t)e * DIM * HID + (size_t)(blockIdx.x * 128) * HID;
        bias = spec_b2 + (size_t)e * DIM;
        obase = spec_g + (size_t)y * 128 * DIM;
    } else {
        int ys = y - NTILE_MAX;
        z = ys / NDT; ry = ys % NDT;
        Ag = Hsh + (size_t)(z * NTOK + ry * 128) * HID;
        Bg = w2t + (size_t)(4 + z) * DIM * HID + (size_t)(blockIdx.x * 128) * HID;
        bias = sh_b2 + (size_t)z * DIM;
        obase = shg + (size_t)(z * NTOK + ry * 128) * DIM;
    }

    __shared__ bf16 As[128 * 32];
    __shared__ bf16 Bs[128 * 32];
    f32x4 acc[4][4] = {};
    for (int k0 = 0; k0 < HID; k0 += 32) {
        stage_tile(Ag + k0, HID, As, tid);
        stage_tile(Bg + k0, HID, Bs, tid);
        __syncthreads();
        mfma_step(As, Bs, wr, wc, fr, fq, acc);
        __syncthreads();
    }
    int rbase = wr * 64;
    int cbase = blockIdx.x * 128 + wc * 64;
    #pragma unroll
    for (int j = 0; j < 4; ++j) {
        int col = cbase + j * 16 + fr;
        float bv = bias[col];
        #pragma unroll
        for (int i = 0; i < 4; ++i)
            #pragma unroll
            for (int r = 0; r < 4; ++r) {
                int row = rbase + i * 16 + fq * 4 + r;
                float g = grouped ? slot_gate[y * 128 + row]
                                  : sh_probs[(size_t)(ry * 128 + row) * 2 + z];
                obase[(size_t)row * DIM + col] = __float2bfloat16(g * (acc[i][j][r] + bv));
            }
    }
}

// ---------------------------------------------------------------- plan-B dense kernels (fallback only)
__global__ __launch_bounds__(256) void gemm1_dense(
    const bf16* __restrict__ A, const bf16* __restrict__ BT,
    const float* __restrict__ bias, bf16* __restrict__ H) {
    __shared__ bf16 As[128 * 32];
    __shared__ bf16 Bs[128 * 32];
    int tid = threadIdx.x;
    int wid = tid >> 6, lane = tid & 63;
    int wr = wid >> 1, wc = wid & 1;
    int fr = lane & 15, fq = lane >> 4;
    const bf16* Ag = A + (size_t)(blockIdx.y * 128) * DIM;
    const bf16* Bg = BT + (size_t)(blockIdx.x * 128) * DIM;
    f32x4 acc[4][4] = {};
    for (int k0 = 0; k0 < DIM; k0 += 32) {
        stage_tile(Ag + k0, DIM, As, tid);
        stage_tile(Bg + k0, DIM, Bs, tid);
        __syncthreads();
        mfma_step(As, Bs, wr, wc, fr, fq, acc);
        __syncthreads();
    }
    int rbase = blockIdx.y * 128 + wr * 64;
    int cbase = blockIdx.x * 128 + wc * 64;
    #pragma unroll
    for (int j = 0; j < 4; ++j) {
        int col = cbase + j * 16 + fr;
        float bv = bias[col];
        #pragma unroll
        for (int i = 0; i < 4; ++i)
            #pragma unroll
            for (int r = 0; r < 4; ++r) {
                int row = rbase + i * 16 + fq * 4 + r;
                H[(size_t)row * HID + col] = __float2bfloat16(gelu_exact(acc[i][j][r] + bv));
            }
    }
}

__global__ __launch_bounds__(256) void gemm2_dense_out(
    const bf16* __restrict__ A, const bf16* __restrict__ BT,
    const float* __restrict__ bias, const float* __restrict__ gates,
    float* __restrict__ out, int gidx, int accum) {
    __shared__ bf16 As[128 * 32];
    __shared__ bf16 Bs[128 * 32];
    int tid = threadIdx.x;
    int wid = tid >> 6, lane = tid & 63;
    int wr = wid >> 1, wc = wid & 1;
    int fr = lane & 15, fq = lane >> 4;
    const bf16* Ag = A + (size_t)(blockIdx.y * 128) * HID;
    const bf16* Bg = BT + (size_t)(blockIdx.x * 128) * HID;
    f32x4 acc[4][4] = {};
    for (int k0 = 0; k0 < HID; k0 += 32) {
        stage_tile(Ag + k0, HID, As, tid);
        stage_tile(Bg + k0, HID, Bs, tid);
        __syncthreads();
        mfma_step(As, Bs, wr, wc, fr, fq, acc);
        __syncthreads();
    }
    int rbase = blockIdx.y * 128 + wr * 64;
    int cbase = blockIdx.x * 128 + wc * 64;
    #pragma unroll
    for (int j = 0; j < 4; ++j) {
        int col = cbase + j * 16 + fr;
        float bv = bias[col];
        #pragma unroll
        for (int i = 0; i < 4; ++i)
            #pragma unroll
            for (int r = 0; r < 4; ++r) {
                int row = rbase + i * 16 + fq * 4 + r;
                float g = gates[(size_t)row * 6 + gidx];
                float v = g * (acc[i][j][r] + bv);
                size_t idx = (size_t)row * DIM + col;
                out[idx] = accum ? out[idx] + v : v;
            }
    }
}

// ---------------------------------------------------------------- combine: flat, 8 elems/thread, vectorized
__global__ void combine_kernel(const bf16* __restrict__ spec_g, const bf16* __restrict__ shg,
                               const int* __restrict__ back, float* __restrict__ out) {
    int idx = blockIdx.x * 256 + threadIdx.x;   // one 8-elem chunk
    int tok = idx / 96;                          // 96 chunks of 8 per token
    int c = (idx % 96) * 8;
    int b0 = back[2 * tok], b1 = back[2 * tok + 1];
    short8v q0 = *(const short8v*)&spec_g[(size_t)b0 * DIM + c];
    short8v q1 = *(const short8v*)&spec_g[(size_t)b1 * DIM + c];
    short8v s0 = *(const short8v*)&shg[(size_t)tok * DIM + c];
    short8v s1 = *(const short8v*)&shg[(size_t)(NTOK + tok) * DIM + c];
    float o[8];
    #pragma unroll
    for (int k = 0; k < 8; ++k) {
        float f0 = __uint_as_float((unsigned)(unsigned short)q0[k] << 16);
        float f1 = __uint_as_float((unsigned)(unsigned short)q1[k] << 16);
        float f2 = __uint_as_float((unsigned)(unsigned short)s0[k] << 16);
        float f3 = __uint_as_float((unsigned)(unsigned short)s1[k] << 16);
        o[k] = f0 + f1 + f2 + f3;
    }
    float* op = out + (size_t)tok * DIM + c;
    *(float4*)(op)     = *(const float4*)(o);
    *(float4*)(op + 4) = *(const float4*)(o + 4);
}

// ---------------------------------------------------------------- launch
static inline size_t align256(size_t x) { return (x + 255) & ~(size_t)255; }

extern "C" void kernel_launch(void* const* d_in, const int* in_sizes, int n_in,
                              void* d_out, int out_size, void* d_ws, size_t ws_size,
                              hipStream_t stream) {
    const float* x      = (const float*)d_in[0];
    const float* gamma  = (const float*)d_in[1];
    const float* beta   = (const float*)d_in[2];
    const float* srw    = (const float*)d_in[3];
    const float* srb    = (const float*)d_in[4];
    const float* spec_w1 = (const float*)d_in[5];
    const float* spec_b1 = (const float*)d_in[6];
    const float* spec_w2 = (const float*)d_in[7];
    const float* spec_b2 = (const float*)d_in[8];
    const float* shw    = (const float*)d_in[9];
    const float* shb    = (const float*)d_in[10];
    const float* sh_w1  = (const float*)d_in[11];
    const float* sh_b1  = (const float*)d_in[12];
    const float* sh_w2  = (const float*)d_in[13];
    const float* sh_b2  = (const float*)d_in[14];

    // ---- workspace carve-up (common head)
    char* p = (char*)d_ws;
    size_t off = 0;
    bf16* xnb = (bf16*)(p + off);       off = align256(off + (size_t)NTOK * DIM * 2);
    bf16* w1t = (bf16*)(p + off);       off = align256(off + (size_t)6 * HID * DIM * 2);
    bf16* w2t = (bf16*)(p + off);       off = align256(off + (size_t)6 * DIM * HID * 2);
    int*  cnt2 = (int*)(p + off);       off = align256(off + (size_t)4 * NBKT * 4);
    float* gates = (float*)(p + off);   off = align256(off + (size_t)NTOK * 6 * 4);
    int*  tok2 = (int*)(p + off);       off = align256(off + (size_t)4 * NBKT * BKTCAP * 4);
    float* gate2 = (float*)(p + off);   off = align256(off + (size_t)4 * NBKT * BKTCAP * 4);
    int*  slot_tok = (int*)(p + off);   off = align256(off + (size_t)NSLOT_MAX * 4);
    float* slot_gate = (float*)(p + off); off = align256(off + (size_t)NSLOT_MAX * 4);
    int*  back = (int*)(p + off);       off = align256(off + (size_t)2 * NTOK * 4);
    int*  e_of_tile = (int*)(p + off);  off = align256(off + (size_t)NTILE_MAX * 4);
    size_t off_common = off;

    // plan A2: Hspec and Hsh coexist (2 merged GEMM launches)
    size_t offA2 = off_common;
    bf16* Hspec2 = (bf16*)(p + offA2);  offA2 = align256(offA2 + (size_t)NSLOT_MAX * HID * 2);
    bf16* Hsh2   = (bf16*)(p + offA2);  offA2 = align256(offA2 + (size_t)2 * NTOK * HID * 2);
    bf16* spec_g2 = (bf16*)(p + offA2); offA2 = align256(offA2 + (size_t)NSLOT_MAX * DIM * 2);
    bf16* shg2   = (bf16*)(p + offA2);  offA2 = align256(offA2 + (size_t)2 * NTOK * DIM * 2);
    size_t need_A2 = offA2;

    // plan A: Hsh aliases Hspec (4 GEMM launches, serialized reuse)
    size_t offA = off_common;
    bf16* HspecA = (bf16*)(p + offA);   offA = align256(offA + (size_t)NSLOT_MAX * HID * 2);
    bf16* spec_gA = (bf16*)(p + offA);  offA = align256(offA + (size_t)NSLOT_MAX * DIM * 2);
    bf16* shgA   = (bf16*)(p + offA);   offA = align256(offA + (size_t)2 * NTOK * DIM * 2);
    size_t need_A = offA;

    // d_out layout (flat concat, all f32)
    float* out         = (float*)d_out;
    float* spec_logits = out + (size_t)NTOK * DIM;
    float* spec_probs  = spec_logits + (size_t)NTOK * 4;
    float* topk_idx    = spec_probs  + (size_t)NTOK * 4;
    float* topk_probs  = topk_idx    + (size_t)NTOK * 2;
    float* sh_logits   = topk_probs  + (size_t)NTOK * 2;
    float* sh_probs    = sh_logits   + (size_t)NTOK * 2;

    // weights transpose+bf16 + housekeeping zero-fills (one launch)
    conv_all_kernel<<<dim3(576, 12), 256, 0, stream>>>(
        spec_w1, sh_w1, spec_w2, sh_w2, w1t, w2t, cnt2, slot_tok, slot_gate);

    router_ln_kernel<<<NTOK / 4, 256, 0, stream>>>(x, gamma, beta, srw, srb, shw, shb, xnb,
                                                   spec_logits, spec_probs, topk_idx,
                                                   topk_probs, sh_logits, sh_probs, gates,
                                                   cnt2, tok2, gate2);

    if (ws_size >= need_A2) {
        plan_kernel<<<1, 256, 0, stream>>>(cnt2, e_of_tile, tok2, gate2,
                                           slot_tok, slot_gate, back);
        gemm1_all<<<dim3(HID / 128, NTILE_MAX + 2 * NDT), 256, 0, stream>>>(
            xnb, w1t, spec_b1, sh_b1, e_of_tile, slot_tok, Hspec2, Hsh2, 0);
        gemm2_all<<<dim3(DIM / 128, NTILE_MAX + 2 * NDT), 256, 0, stream>>>(
            Hspec2, Hsh2, w2t, spec_b2, sh_b2, e_of_tile, slot_gate, sh_probs,
            spec_g2, shg2, 0);
        combine_kernel<<<NTOK * 96 / 256, 256, 0, stream>>>(spec_g2, shg2, back, out);
    } else if (ws_size >= need_A) {
        plan_kernel<<<1, 256, 0, stream>>>(cnt2, e_of_tile, tok2, gate2,
                                           slot_tok, slot_gate, back);
        gemm1_all<<<dim3(HID / 128, NTILE_MAX), 256, 0, stream>>>(
            xnb, w1t, spec_b1, sh_b1, e_of_tile, slot_tok, HspecA, HspecA, 0);
        gemm2_all<<<dim3(DIM / 128, NTILE_MAX), 256, 0, stream>>>(
            HspecA, HspecA, w2t, spec_b2, sh_b2, e_of_tile, slot_gate, sh_probs,
            spec_gA, shgA, 0);
        gemm1_all<<<dim3(HID / 128, 2 * NDT), 256, 0, stream>>>(
            xnb, w1t, spec_b1, sh_b1, e_of_tile, slot_tok, HspecA, HspecA, NTILE_MAX);
        gemm2_all<<<dim3(DIM / 128, 2 * NDT), 256, 0, stream>>>(
            HspecA, HspecA, w2t, spec_b2, sh_b2, e_of_tile, slot_gate, sh_probs,
            spec_gA, shgA, NTILE_MAX);
        combine_kernel<<<NTOK * 96 / 256, 256, 0, stream>>>(spec_gA, shgA, back, out);
    } else {
        // plan B: dense 6-expert loop
        bf16* HB = (bf16*)(p + off_common);
        for (int e = 0; e < 6; ++e) {
            const bf16* w1p = w1t + (size_t)e * HID * DIM;
            const bf16* w2p = w2t + (size_t)e * DIM * HID;
            const float* b1p = (e < 4) ? spec_b1 + (size_t)e * HID : sh_b1 + (size_t)(e - 4) * HID;
            const float* b2p = (e < 4) ? spec_b2 + (size_t)e * DIM : sh_b2 + (size_t)(e - 4) * DIM;
            gemm1_dense<<<dim3(HID / 128, NTOK / 128), 256, 0, stream>>>(xnb, w1p, b1p, HB);
            gemm2_dense_out<<<dim3(DIM / 128, NTOK / 128), 256, 0, stream>>>(
                HB, w2p, b2p, gates, out, e, e > 0);
        }
    }
}

// Round 7
// 1027.066 us; speedup vs baseline: 11.6894x; 1.3984x over previous
//
#include <hip/hip_runtime.h>
#include <hip/hip_bf16.h>
#include <math.h>

#define NTOK 12544
#define DIM 768
#define HID 3072
#define NSLOT_MAX 25600     // spec slots: 2*NTOK + pad
#define NTILE_MAX 200       // NSLOT_MAX/128 (spec virtual tiles)
#define NDT 98              // NTOK/128 dense row tiles per shared expert
#define NVT (NTILE_MAX + 2 * NDT)   // 396 virtual row tiles
#define NBKT 64
#define BKTCAP 256

typedef __hip_bfloat16 bf16;
typedef __attribute__((ext_vector_type(8))) short short8v;
typedef __attribute__((ext_vector_type(4))) float f32x4;

#define GPTR(p)  ((const __attribute__((address_space(1))) void*)(p))
#define LDSPTR(p) ((__attribute__((address_space(3))) void*)(p))

// ---------------------------------------------------------------- conv: all 12 weight matrices, transpose + f32->bf16
__global__ __launch_bounds__(256) void conv_all_kernel(
    const float* __restrict__ spec_w1, const float* __restrict__ sh_w1,
    const float* __restrict__ spec_w2, const float* __restrict__ sh_w2,
    bf16* __restrict__ w1t, bf16* __restrict__ w2t,
    int* __restrict__ cnt2, int* __restrict__ slot_tok, float* __restrict__ slot_gate) {
    int z = blockIdx.y;
    int ti = blockIdx.x;
    int t = threadIdx.x;
    if (z == 0) {
        if (ti == 0) cnt2[t] = 0;
        if (ti < 100) {
            int s = ti * 256 + t;
            if (s < NSLOT_MAX) { slot_tok[s] = 0; slot_gate[s] = 0.0f; }
        }
    }
    const float* src; bf16* dst; int R, C, tr, tc;
    if (z < 6) {
        R = DIM; C = HID;
        src = (z < 4) ? spec_w1 + (size_t)z * R * C : sh_w1 + (size_t)(z - 4) * R * C;
        dst = w1t + (size_t)z * R * C;
        tr = ti % 12; tc = ti / 12;
    } else {
        int e = z - 6;
        R = HID; C = DIM;
        src = (e < 4) ? spec_w2 + (size_t)e * R * C : sh_w2 + (size_t)(e - 4) * R * C;
        dst = w2t + (size_t)e * R * C;
        tr = ti % 48; tc = ti / 48;
    }
    __shared__ float tile[64][65];
    int r0 = tr * 64, c0 = tc * 64;
    int lr = t >> 4, lc = (t & 15) * 4;
    #pragma unroll
    for (int ii = 0; ii < 4; ++ii) {
        float4 v = *(const float4*)&src[(size_t)(r0 + lr + 16 * ii) * C + c0 + lc];
        tile[lc + 0][lr + 16 * ii] = v.x;
        tile[lc + 1][lr + 16 * ii] = v.y;
        tile[lc + 2][lr + 16 * ii] = v.z;
        tile[lc + 3][lr + 16 * ii] = v.w;
    }
    __syncthreads();
    int oc = t >> 4, orr = (t & 15) * 4;
    #pragma unroll
    for (int ii = 0; ii < 4; ++ii) {
        union { ushort4 u4; bf16 h[4]; } pk;
        #pragma unroll
        for (int k = 0; k < 4; ++k)
            pk.h[k] = __float2bfloat16(tile[oc + 16 * ii][orr + k]);
        *(ushort4*)&dst[(size_t)(c0 + oc + 16 * ii) * R + r0 + orr] = pk.u4;
    }
}

// ---------------------------------------------------------------- Router + LN(bf16 out) + bucketed routing lists
__global__ void router_ln_kernel(const float* __restrict__ x,
                                 const float* __restrict__ lng, const float* __restrict__ lnb,
                                 const float* __restrict__ srw, const float* __restrict__ srb,
                                 const float* __restrict__ shw, const float* __restrict__ shb,
                                 bf16* __restrict__ xnb,
                                 float* __restrict__ spec_logits, float* __restrict__ spec_probs,
                                 float* __restrict__ topk_idx, float* __restrict__ topk_probs,
                                 float* __restrict__ sh_logits, float* __restrict__ sh_probs,
                                 float* __restrict__ gates,
                                 int* __restrict__ cnt2, int* __restrict__ tok2,
                                 float* __restrict__ gate2) {
    int t = blockIdx.x * 4 + (threadIdx.x >> 6);
    int bucket = blockIdx.x & (NBKT - 1);
    int lane = threadIdx.x & 63;
    const float* xr = x + (size_t)t * DIM;
    bf16* xb = xnb + (size_t)t * DIM;
    float v[12];
    float s = 0.0f;
    #pragma unroll
    for (int i = 0; i < 6; ++i) {
        float2 xv = *(const float2*)&xr[lane * 2 + 128 * i];
        v[2 * i] = xv.x; v[2 * i + 1] = xv.y;
        s += xv.x + xv.y;
    }
    #pragma unroll
    for (int o = 32; o > 0; o >>= 1) s += __shfl_xor(s, o, 64);
    float mean = s * (1.0f / 768.0f);
    float sq = 0.0f;
    #pragma unroll
    for (int i = 0; i < 12; ++i) { float d = v[i] - mean; sq += d * d; }
    #pragma unroll
    for (int o = 32; o > 0; o >>= 1) sq += __shfl_xor(sq, o, 64);
    float rstd = rsqrtf(sq * (1.0f / 768.0f) + 1e-5f);

    float acc[6] = {0, 0, 0, 0, 0, 0};
    #pragma unroll
    for (int i = 0; i < 6; ++i) {
        int d0 = lane * 2 + 128 * i;
        float xn0 = (v[2 * i]     - mean) * rstd * lng[d0]     + lnb[d0];
        float xn1 = (v[2 * i + 1] - mean) * rstd * lng[d0 + 1] + lnb[d0 + 1];
        union { unsigned u; bf16 h[2]; } pk;
        pk.h[0] = __float2bfloat16(xn0);
        pk.h[1] = __float2bfloat16(xn1);
        *(unsigned*)&xb[d0] = pk.u;
        float4 a = *(const float4*)&srw[d0 * 4];
        float4 b = *(const float4*)&srw[d0 * 4 + 4];
        acc[0] += xn0 * a.x + xn1 * b.x;
        acc[1] += xn0 * a.y + xn1 * b.y;
        acc[2] += xn0 * a.z + xn1 * b.z;
        acc[3] += xn0 * a.w + xn1 * b.w;
        float4 sw = *(const float4*)&shw[d0 * 2];
        acc[4] += xn0 * sw.x + xn1 * sw.z;
        acc[5] += xn0 * sw.y + xn1 * sw.w;
    }
    #pragma unroll
    for (int j = 0; j < 6; ++j) {
        #pragma unroll
        for (int o = 32; o > 0; o >>= 1) acc[j] += __shfl_xor(acc[j], o, 64);
    }
    if (lane == 0) {
        float l[4];
        #pragma unroll
        for (int j = 0; j < 4; ++j) l[j] = acc[j] + srb[j];
        float m = fmaxf(fmaxf(l[0], l[1]), fmaxf(l[2], l[3]));
        float e[4], ssum = 0.0f;
        #pragma unroll
        for (int j = 0; j < 4; ++j) { e[j] = expf(l[j] - m); ssum += e[j]; }
        float inv = 1.0f / ssum;
        float p[4];
        #pragma unroll
        for (int j = 0; j < 4; ++j) p[j] = e[j] * inv;
        int i0 = 0;
        for (int j = 1; j < 4; ++j) if (p[j] > p[i0]) i0 = j;
        int i1 = -1;
        for (int j = 0; j < 4; ++j) {
            if (j == i0) continue;
            if (i1 < 0 || p[j] > p[i1]) i1 = j;
        }
        float sl0 = acc[4] + shb[0], sl1 = acc[5] + shb[1];
        float sm = fmaxf(sl0, sl1);
        float se0 = expf(sl0 - sm), se1 = expf(sl1 - sm);
        float sinv = 1.0f / (se0 + se1);
        float sp0 = se0 * sinv, sp1 = se1 * sinv;

        #pragma unroll
        for (int j = 0; j < 4; ++j) {
            spec_logits[t * 4 + j] = l[j];
            spec_probs[t * 4 + j]  = p[j];
        }
        topk_idx[t * 2 + 0]   = (float)i0;
        topk_idx[t * 2 + 1]   = (float)i1;
        topk_probs[t * 2 + 0] = p[i0];
        topk_probs[t * 2 + 1] = p[i1];
        sh_logits[t * 2 + 0]  = sl0;
        sh_logits[t * 2 + 1]  = sl1;
        sh_probs[t * 2 + 0]   = sp0;
        sh_probs[t * 2 + 1]   = sp1;
        float gg[6] = {0, 0, 0, 0, sp0, sp1};
        gg[i0] = p[i0];
        gg[i1] = p[i1];
        #pragma unroll
        for (int j = 0; j < 6; ++j) gates[t * 6 + j] = gg[j];
        int c0 = i0 * NBKT + bucket;
        int pos0 = atomicAdd(&cnt2[c0], 1);
        tok2[c0 * BKTCAP + pos0]  = t * 2 + 0;
        gate2[c0 * BKTCAP + pos0] = p[i0];
        int c1 = i1 * NBKT + bucket;
        int pos1 = atomicAdd(&cnt2[c1], 1);
        tok2[c1 * BKTCAP + pos1]  = t * 2 + 1;
        gate2[c1 * BKTCAP + pos1] = p[i1];
    }
}

// ---------------------------------------------------------------- plan: parallel bucket scan, compact
__global__ void plan_kernel(const int* __restrict__ cnt2, int* __restrict__ e_of_tile,
                            const int* __restrict__ tok2, const float* __restrict__ gate2,
                            int* __restrict__ slot_tok, float* __restrict__ slot_gate,
                            int* __restrict__ back) {
    __shared__ int sbase[4 * NBKT];
    __shared__ int offsE[5];
    __shared__ int etot[4];
    int tid = threadIdx.x, lane = tid & 63, wid = tid >> 6;
    int c = cnt2[wid * NBKT + lane];
    int inc = c;
    #pragma unroll
    for (int o = 1; o < 64; o <<= 1) {
        int tv = __shfl_up(inc, o, 64);
        if (lane >= o) inc += tv;
    }
    int exc = inc - c;
    if (lane == 63) etot[wid] = inc;
    __syncthreads();
    if (tid == 0) {
        int o = 0;
        for (int e = 0; e < 4; ++e) { offsE[e] = o; o += (etot[e] + 127) & ~127; }
        offsE[4] = o;
    }
    __syncthreads();
    sbase[tid] = offsE[wid] + exc;
    for (int idx = tid; idx < NTILE_MAX; idx += 256) {
        int s0 = idx * 128, e = -1;
        for (int j = 0; j < 4; ++j)
            if (s0 >= offsE[j] && s0 < offsE[j + 1]) e = j;
        e_of_tile[idx] = e;
    }
    __syncthreads();
    int bs = sbase[tid];
    int cc = cnt2[tid];
    for (int i = 0; i < cc; ++i) {
        int gs = bs + i;
        int tk = tok2[tid * BKTCAP + i];
        slot_tok[gs] = tk >> 1;
        slot_gate[gs] = gate2[tid * BKTCAP + i];
        back[tk] = gs;
    }
}

// ---------------------------------------------------------------- MFMA helpers
__device__ __forceinline__ void stage_tile(const bf16* __restrict__ g, int ldg,
                                           bf16* lds, int tid) {
    int wave = tid >> 6, lane = tid & 63;
    #pragma unroll
    for (int q = 0; q < 2; ++q) {
        int chunk = wave * 2 + q;
        int row = chunk * 16 + (lane >> 2);
        int col = (lane & 3) * 8;
        __builtin_amdgcn_global_load_lds(GPTR(g + (size_t)row * ldg + col),
                                         LDSPTR(lds + chunk * 512), 16, 0, 0);
    }
}

__device__ __forceinline__ void mfma_step(const bf16* As, const bf16* Bs,
                                          int wr, int wc, int fr, int fq, f32x4 acc[4][4]) {
    short8v a[4], b[4];
    #pragma unroll
    for (int i = 0; i < 4; ++i) {
        a[i] = *(const short8v*)&As[(wr * 64 + i * 16 + fr) * 32 + fq * 8];
        b[i] = *(const short8v*)&Bs[(wc * 64 + i * 16 + fr) * 32 + fq * 8];
    }
    #pragma unroll
    for (int i = 0; i < 4; ++i)
        #pragma unroll
        for (int j = 0; j < 4; ++j)
            acc[i][j] = __builtin_amdgcn_mfma_f32_16x16x32_bf16(a[i], b[j], acc[i][j], 0, 0, 0);
}

__device__ __forceinline__ float gelu_exact(float v) {
    return 0.5f * v * (1.0f + erff(v * 0.70710678118654752f));
}

// ---------------------------------------------------------------- GEMM1 unified, CHUNKED H (local blockIdx.y)
__global__ __launch_bounds__(256) void gemm1_all(
    const bf16* __restrict__ xnb, const bf16* __restrict__ w1t,
    const float* __restrict__ spec_b1, const float* __restrict__ sh_b1,
    const int* __restrict__ e_of_tile, const int* __restrict__ slot_tok,
    bf16* __restrict__ Hbuf, int y_base) {
    int y = blockIdx.y + y_base;
    int tid = threadIdx.x;
    int wid = tid >> 6, lane = tid & 63;
    int wr = wid >> 1, wc = wid & 1;
    int fr = lane & 15, fq = lane >> 4;

    const bf16* Bg;
    const float* bias;
    bool grouped = (y < NTILE_MAX);
    int tokbase = 0;
    if (grouped) {
        int e = e_of_tile[y];
        if (e < 0) return;
        Bg = w1t + (size_t)e * HID * DIM + (size_t)(blockIdx.x * 128) * DIM;
        bias = spec_b1 + (size_t)e * HID;
    } else {
        int ys = y - NTILE_MAX;
        int z = ys / NDT, ry = ys % NDT;
        Bg = w1t + (size_t)(4 + z) * HID * DIM + (size_t)(blockIdx.x * 128) * DIM;
        bias = sh_b1 + (size_t)z * HID;
        tokbase = ry * 128;
    }
    bf16* hbase = Hbuf + (size_t)blockIdx.y * 128 * HID;   // chunk-local

    __shared__ bf16 As[128 * 32];
    __shared__ bf16 Bs[128 * 32];
    const bf16* asrc[2];
    #pragma unroll
    for (int q = 0; q < 2; ++q) {
        int r = (wid * 2 + q) * 16 + (lane >> 2);
        int tok = grouped ? slot_tok[y * 128 + r] : tokbase + r;
        asrc[q] = xnb + (size_t)tok * DIM + (lane & 3) * 8;
    }
    f32x4 acc[4][4] = {};
    for (int k0 = 0; k0 < DIM; k0 += 32) {
        #pragma unroll
        for (int q = 0; q < 2; ++q)
            __builtin_amdgcn_global_load_lds(GPTR(asrc[q] + k0),
                                             LDSPTR(As + (wid * 2 + q) * 512), 16, 0, 0);
        stage_tile(Bg + k0, DIM, Bs, tid);
        __syncthreads();
        mfma_step(As, Bs, wr, wc, fr, fq, acc);
        __syncthreads();
    }
    int rbase = wr * 64;
    int cbase = blockIdx.x * 128 + wc * 64;
    #pragma unroll
    for (int j = 0; j < 4; ++j) {
        int col = cbase + j * 16 + fr;
        float bv = bias[col];
        #pragma unroll
        for (int i = 0; i < 4; ++i)
            #pragma unroll
            for (int r = 0; r < 4; ++r) {
                int row = rbase + i * 16 + fq * 4 + r;
                hbase[(size_t)row * HID + col] = __float2bfloat16(gelu_exact(acc[i][j][r] + bv));
            }
    }
}

// ---------------------------------------------------------------- GEMM2 unified, CHUNKED H -> gated bf16 partials
__global__ __launch_bounds__(256) void gemm2_all(
    const bf16* __restrict__ Hbuf, const bf16* __restrict__ w2t,
    const float* __restrict__ spec_b2, const float* __restrict__ sh_b2,
    const int* __restrict__ e_of_tile, const float* __restrict__ slot_gate,
    const float* __restrict__ sh_probs,
    bf16* __restrict__ spec_g, bf16* __restrict__ shg, int y_base) {
    int y = blockIdx.y + y_base;
    int tid = threadIdx.x;
    int wid = tid >> 6, lane = tid & 63;
    int wr = wid >> 1, wc = wid & 1;
    int fr = lane & 15, fq = lane >> 4;

    const bf16* Bg;
    const float* bias;
    bf16* obase;
    bool grouped = (y < NTILE_MAX);
    int z = 0, ry = 0;
    if (grouped) {
        int e = e_of_tile[y];
        if (e < 0) return;
        Bg = w2t + (size_t)e * DIM * HID + (size_t)(blockIdx.x * 128) * HID;
        bias = spec_b2 + (size_t)e * DIM;
        obase = spec_g + (size_t)y * 128 * DIM;
    } else {
        int ys = y - NTILE_MAX;
        z = ys / NDT; ry = ys % NDT;
        Bg = w2t + (size_t)(4 + z) * DIM * HID + (size_t)(blockIdx.x * 128) * HID;
        bias = sh_b2 + (size_t)z * DIM;
        obase = shg + (size_t)(z * NTOK + ry * 128) * DIM;
    }
    const bf16* Ag = Hbuf + (size_t)blockIdx.y * 128 * HID;   // chunk-local

    __shared__ bf16 As[128 * 32];
    __shared__ bf16 Bs[128 * 32];
    f32x4 acc[4][4] = {};
    for (int k0 = 0; k0 < HID; k0 += 32) {
        stage_tile(Ag + k0, HID, As, tid);
        stage_tile(Bg + k0, HID, Bs, tid);
        __syncthreads();
        mfma_step(As, Bs, wr, wc, fr, fq, acc);
        __syncthreads();
    }
    int rbase = wr * 64;
    int cbase = blockIdx.x * 128 + wc * 64;
    #pragma unroll
    for (int j = 0; j < 4; ++j) {
        int col = cbase + j * 16 + fr;
        float bv = bias[col];
        #pragma unroll
        for (int i = 0; i < 4; ++i)
            #pragma unroll
            for (int r = 0; r < 4; ++r) {
                int row = rbase + i * 16 + fq * 4 + r;
                float g = grouped ? slot_gate[y * 128 + row]
                                  : sh_probs[(size_t)(ry * 128 + row) * 2 + z];
                obase[(size_t)row * DIM + col] = __float2bfloat16(g * (acc[i][j][r] + bv));
            }
    }
}

// ---------------------------------------------------------------- plan-B dense kernels (fallback only)
__global__ __launch_bounds__(256) void gemm1_dense(
    const bf16* __restrict__ A, const bf16* __restrict__ BT,
    const float* __restrict__ bias, bf16* __restrict__ H) {
    __shared__ bf16 As[128 * 32];
    __shared__ bf16 Bs[128 * 32];
    int tid = threadIdx.x;
    int wid = tid >> 6, lane = tid & 63;
    int wr = wid >> 1, wc = wid & 1;
    int fr = lane & 15, fq = lane >> 4;
    const bf16* Ag = A + (size_t)(blockIdx.y * 128) * DIM;
    const bf16* Bg = BT + (size_t)(blockIdx.x * 128) * DIM;
    f32x4 acc[4][4] = {};
    for (int k0 = 0; k0 < DIM; k0 += 32) {
        stage_tile(Ag + k0, DIM, As, tid);
        stage_tile(Bg + k0, DIM, Bs, tid);
        __syncthreads();
        mfma_step(As, Bs, wr, wc, fr, fq, acc);
        __syncthreads();
    }
    int rbase = blockIdx.y * 128 + wr * 64;
    int cbase = blockIdx.x * 128 + wc * 64;
    #pragma unroll
    for (int j = 0; j < 4; ++j) {
        int col = cbase + j * 16 + fr;
        float bv = bias[col];
        #pragma unroll
        for (int i = 0; i < 4; ++i)
            #pragma unroll
            for (int r = 0; r < 4; ++r) {
                int row = rbase + i * 16 + fq * 4 + r;
                H[(size_t)row * HID + col] = __float2bfloat16(gelu_exact(acc[i][j][r] + bv));
            }
    }
}

__global__ __launch_bounds__(256) void gemm2_dense_out(
    const bf16* __restrict__ A, const bf16* __restrict__ BT,
    const float* __restrict__ bias, const float* __restrict__ gates,
    float* __restrict__ out, int gidx, int accum) {
    __shared__ bf16 As[128 * 32];
    __shared__ bf16 Bs[128 * 32];
    int tid = threadIdx.x;
    int wid = tid >> 6, lane = tid & 63;
    int wr = wid >> 1, wc = wid & 1;
    int fr = lane & 15, fq = lane >> 4;
    const bf16* Ag = A + (size_t)(blockIdx.y * 128) * HID;
    const bf16* Bg = BT + (size_t)(blockIdx.x * 128) * HID;
    f32x4 acc[4][4] = {};
    for (int k0 = 0; k0 < HID; k0 += 32) {
        stage_tile(Ag + k0, HID, As, tid);
        stage_tile(Bg + k0, HID, Bs, tid);
        __syncthreads();
        mfma_step(As, Bs, wr, wc, fr, fq, acc);
        __syncthreads();
    }
    int rbase = blockIdx.y * 128 + wr * 64;
    int cbase = blockIdx.x * 128 + wc * 64;
    #pragma unroll
    for (int j = 0; j < 4; ++j) {
        int col = cbase + j * 16 + fr;
        float bv = bias[col];
        #pragma unroll
        for (int i = 0; i < 4; ++i)
            #pragma unroll
            for (int r = 0; r < 4; ++r) {
                int row = rbase + i * 16 + fq * 4 + r;
                float g = gates[(size_t)row * 6 + gidx];
                float v = g * (acc[i][j][r] + bv);
                size_t idx = (size_t)row * DIM + col;
                out[idx] = accum ? out[idx] + v : v;
            }
    }
}

// ---------------------------------------------------------------- combine: flat, 8 elems/thread, vectorized
__global__ void combine_kernel(const bf16* __restrict__ spec_g, const bf16* __restrict__ shg,
                               const int* __restrict__ back, float* __restrict__ out) {
    int idx = blockIdx.x * 256 + threadIdx.x;
    int tok = idx / 96;
    int c = (idx % 96) * 8;
    int b0 = back[2 * tok], b1 = back[2 * tok + 1];
    short8v q0 = *(const short8v*)&spec_g[(size_t)b0 * DIM + c];
    short8v q1 = *(const short8v*)&spec_g[(size_t)b1 * DIM + c];
    short8v s0 = *(const short8v*)&shg[(size_t)tok * DIM + c];
    short8v s1 = *(const short8v*)&shg[(size_t)(NTOK + tok) * DIM + c];
    float o[8];
    #pragma unroll
    for (int k = 0; k < 8; ++k) {
        float f0 = __uint_as_float((unsigned)(unsigned short)q0[k] << 16);
        float f1 = __uint_as_float((unsigned)(unsigned short)q1[k] << 16);
        float f2 = __uint_as_float((unsigned)(unsigned short)s0[k] << 16);
        float f3 = __uint_as_float((unsigned)(unsigned short)s1[k] << 16);
        o[k] = f0 + f1 + f2 + f3;
    }
    float* op = out + (size_t)tok * DIM + c;
    *(float4*)(op)     = *(const float4*)(o);
    *(float4*)(op + 4) = *(const float4*)(o + 4);
}

// ---------------------------------------------------------------- launch
static inline size_t align256(size_t x) { return (x + 255) & ~(size_t)255; }

extern "C" void kernel_launch(void* const* d_in, const int* in_sizes, int n_in,
                              void* d_out, int out_size, void* d_ws, size_t ws_size,
                              hipStream_t stream) {
    const float* x      = (const float*)d_in[0];
    const float* gamma  = (const float*)d_in[1];
    const float* beta   = (const float*)d_in[2];
    const float* srw    = (const float*)d_in[3];
    const float* srb    = (const float*)d_in[4];
    const float* spec_w1 = (const float*)d_in[5];
    const float* spec_b1 = (const float*)d_in[6];
    const float* spec_w2 = (const float*)d_in[7];
    const float* spec_b2 = (const float*)d_in[8];
    const float* shw    = (const float*)d_in[9];
    const float* shb    = (const float*)d_in[10];
    const float* sh_w1  = (const float*)d_in[11];
    const float* sh_b1  = (const float*)d_in[12];
    const float* sh_w2  = (const float*)d_in[13];
    const float* sh_b2  = (const float*)d_in[14];

    // ---- fixed workspace (everything except the chunked H buffer)
    char* p = (char*)d_ws;
    size_t off = 0;
    bf16* xnb = (bf16*)(p + off);       off = align256(off + (size_t)NTOK * DIM * 2);
    bf16* w1t = (bf16*)(p + off);       off = align256(off + (size_t)6 * HID * DIM * 2);
    bf16* w2t = (bf16*)(p + off);       off = align256(off + (size_t)6 * DIM * HID * 2);
    int*  cnt2 = (int*)(p + off);       off = align256(off + (size_t)4 * NBKT * 4);
    float* gates = (float*)(p + off);   off = align256(off + (size_t)NTOK * 6 * 4);
    int*  tok2 = (int*)(p + off);       off = align256(off + (size_t)4 * NBKT * BKTCAP * 4);
    float* gate2 = (float*)(p + off);   off = align256(off + (size_t)4 * NBKT * BKTCAP * 4);
    int*  slot_tok = (int*)(p + off);   off = align256(off + (size_t)NSLOT_MAX * 4);
    float* slot_gate = (float*)(p + off); off = align256(off + (size_t)NSLOT_MAX * 4);
    int*  back = (int*)(p + off);       off = align256(off + (size_t)2 * NTOK * 4);
    int*  e_of_tile = (int*)(p + off);  off = align256(off + (size_t)NTILE_MAX * 4);
    bf16* spec_g = (bf16*)(p + off);    off = align256(off + (size_t)NSLOT_MAX * DIM * 2);
    bf16* shg   = (bf16*)(p + off);     off = align256(off + (size_t)2 * NTOK * DIM * 2);
    size_t fixed_end = off;
    bf16* Hbuf = (bf16*)(p + fixed_end);

    const size_t tile_bytes = (size_t)128 * HID * 2;   // 786432 B per row-tile
    size_t avail = (ws_size > fixed_end) ? (ws_size - fixed_end) : 0;
    int tcap = (int)(avail / tile_bytes);
    if (tcap > NTILE_MAX) tcap = NTILE_MAX;

    // d_out layout (flat concat, all f32)
    float* out         = (float*)d_out;
    float* spec_logits = out + (size_t)NTOK * DIM;
    float* spec_probs  = spec_logits + (size_t)NTOK * 4;
    float* topk_idx    = spec_probs  + (size_t)NTOK * 4;
    float* topk_probs  = topk_idx    + (size_t)NTOK * 2;
    float* sh_logits   = topk_probs  + (size_t)NTOK * 2;
    float* sh_probs    = sh_logits   + (size_t)NTOK * 2;

    conv_all_kernel<<<dim3(576, 12), 256, 0, stream>>>(
        spec_w1, sh_w1, spec_w2, sh_w2, w1t, w2t, cnt2, slot_tok, slot_gate);

    router_ln_kernel<<<NTOK / 4, 256, 0, stream>>>(x, gamma, beta, srw, srb, shw, shb, xnb,
                                                   spec_logits, spec_probs, topk_idx,
                                                   topk_probs, sh_logits, sh_probs, gates,
                                                   cnt2, tok2, gate2);

    if (tcap >= 16) {
        // grouped + shared unified, H chunked to fit workspace
        plan_kernel<<<1, 256, 0, stream>>>(cnt2, e_of_tile, tok2, gate2,
                                           slot_tok, slot_gate, back);
        for (int c0 = 0; c0 < NVT; c0 += tcap) {
            int n = NVT - c0 < tcap ? NVT - c0 : tcap;
            gemm1_all<<<dim3(HID / 128, n), 256, 0, stream>>>(
                xnb, w1t, spec_b1, sh_b1, e_of_tile, slot_tok, Hbuf, c0);
            gemm2_all<<<dim3(DIM / 128, n), 256, 0, stream>>>(
                Hbuf, w2t, spec_b2, sh_b2, e_of_tile, slot_gate, sh_probs,
                spec_g, shg, c0);
        }
        combine_kernel<<<NTOK * 96 / 256, 256, 0, stream>>>(spec_g, shg, back, out);
    } else {
        // plan B: dense 6-expert loop (reuses spec_g/shg region start as H)
        bf16* HB = spec_g;
        for (int e = 0; e < 6; ++e) {
            const bf16* w1p = w1t + (size_t)e * HID * DIM;
            const bf16* w2p = w2t + (size_t)e * DIM * HID;
            const float* b1p = (e < 4) ? spec_b1 + (size_t)e * HID : sh_b1 + (size_t)(e - 4) * HID;
            const float* b2p = (e < 4) ? spec_b2 + (size_t)e * DIM : sh_b2 + (size_t)(e - 4) * DIM;
            gemm1_dense<<<dim3(HID / 128, NTOK / 128), 256, 0, stream>>>(xnb, w1p, b1p, HB);
            gemm2_dense_out<<<dim3(DIM / 128, NTOK / 128), 256, 0, stream>>>(
                HB, w2p, b2p, gates, out, e, e > 0);
        }
    }
}

// Round 8
// 930.190 us; speedup vs baseline: 12.9068x; 1.1041x over previous
//
#include <hip/hip_runtime.h>
#include <hip/hip_bf16.h>
#include <math.h>

#define NTOK 12544
#define DIM 768
#define HID 3072
#define NTILE_MAX 102               // spec 256-row tiles: (2*NTOK + 4*255)/256 rounded up
#define NSLOT_MAX (NTILE_MAX * 256) // 26112 slots
#define NSDT 49                     // NTOK/256 dense row tiles per shared expert
#define NVT (NTILE_MAX + 2 * NSDT)  // 200 virtual 256-row tiles
#define NBKT 64
#define BKTCAP 256
#define LDSB 131072

typedef __hip_bfloat16 bf16;
typedef __attribute__((ext_vector_type(8))) short short8v;
typedef __attribute__((ext_vector_type(4))) float f32x4;

#define GPTR(p)  ((const __attribute__((address_space(1))) void*)(p))
#define LDSPTR(p) ((__attribute__((address_space(3))) void*)(p))

// ---------------------------------------------------------------- conv: 12 weight matrices, transpose + f32->bf16 (+zero fills)
__global__ __launch_bounds__(256) void conv_all_kernel(
    const float* __restrict__ spec_w1, const float* __restrict__ sh_w1,
    const float* __restrict__ spec_w2, const float* __restrict__ sh_w2,
    bf16* __restrict__ w1t, bf16* __restrict__ w2t,
    int* __restrict__ cnt2, int* __restrict__ slot_tok, float* __restrict__ slot_gate) {
    int z = blockIdx.y;
    int ti = blockIdx.x;
    int t = threadIdx.x;
    if (z == 0) {
        if (ti == 0) cnt2[t] = 0;
        if (ti < NTILE_MAX) {
            int s = ti * 256 + t;
            slot_tok[s] = 0; slot_gate[s] = 0.0f;
        }
    }
    const float* src; bf16* dst; int R, C, tr, tc;
    if (z < 6) {
        R = DIM; C = HID;
        src = (z < 4) ? spec_w1 + (size_t)z * R * C : sh_w1 + (size_t)(z - 4) * R * C;
        dst = w1t + (size_t)z * R * C;
        tr = ti % 12; tc = ti / 12;
    } else {
        int e = z - 6;
        R = HID; C = DIM;
        src = (e < 4) ? spec_w2 + (size_t)e * R * C : sh_w2 + (size_t)(e - 4) * R * C;
        dst = w2t + (size_t)e * R * C;
        tr = ti % 48; tc = ti / 48;
    }
    __shared__ float tile[64][65];
    int r0 = tr * 64, c0 = tc * 64;
    int lr = t >> 4, lc = (t & 15) * 4;
    #pragma unroll
    for (int ii = 0; ii < 4; ++ii) {
        float4 v = *(const float4*)&src[(size_t)(r0 + lr + 16 * ii) * C + c0 + lc];
        tile[lc + 0][lr + 16 * ii] = v.x;
        tile[lc + 1][lr + 16 * ii] = v.y;
        tile[lc + 2][lr + 16 * ii] = v.z;
        tile[lc + 3][lr + 16 * ii] = v.w;
    }
    __syncthreads();
    int oc = t >> 4, orr = (t & 15) * 4;
    #pragma unroll
    for (int ii = 0; ii < 4; ++ii) {
        union { ushort4 u4; bf16 h[4]; } pk;
        #pragma unroll
        for (int k = 0; k < 4; ++k)
            pk.h[k] = __float2bfloat16(tile[oc + 16 * ii][orr + k]);
        *(ushort4*)&dst[(size_t)(c0 + oc + 16 * ii) * R + r0 + orr] = pk.u4;
    }
}

// ---------------------------------------------------------------- Router + LN(bf16) + bucketed lists
__global__ void router_ln_kernel(const float* __restrict__ x,
                                 const float* __restrict__ lng, const float* __restrict__ lnb,
                                 const float* __restrict__ srw, const float* __restrict__ srb,
                                 const float* __restrict__ shw, const float* __restrict__ shb,
                                 bf16* __restrict__ xnb,
                                 float* __restrict__ spec_logits, float* __restrict__ spec_probs,
                                 float* __restrict__ topk_idx, float* __restrict__ topk_probs,
                                 float* __restrict__ sh_logits, float* __restrict__ sh_probs,
                                 float* __restrict__ gates,
                                 int* __restrict__ cnt2, int* __restrict__ tok2,
                                 float* __restrict__ gate2) {
    int t = blockIdx.x * 4 + (threadIdx.x >> 6);
    int bucket = blockIdx.x & (NBKT - 1);
    int lane = threadIdx.x & 63;
    const float* xr = x + (size_t)t * DIM;
    bf16* xb = xnb + (size_t)t * DIM;
    float v[12];
    float s = 0.0f;
    #pragma unroll
    for (int i = 0; i < 6; ++i) {
        float2 xv = *(const float2*)&xr[lane * 2 + 128 * i];
        v[2 * i] = xv.x; v[2 * i + 1] = xv.y;
        s += xv.x + xv.y;
    }
    #pragma unroll
    for (int o = 32; o > 0; o >>= 1) s += __shfl_xor(s, o, 64);
    float mean = s * (1.0f / 768.0f);
    float sq = 0.0f;
    #pragma unroll
    for (int i = 0; i < 12; ++i) { float d = v[i] - mean; sq += d * d; }
    #pragma unroll
    for (int o = 32; o > 0; o >>= 1) sq += __shfl_xor(sq, o, 64);
    float rstd = rsqrtf(sq * (1.0f / 768.0f) + 1e-5f);

    float acc[6] = {0, 0, 0, 0, 0, 0};
    #pragma unroll
    for (int i = 0; i < 6; ++i) {
        int d0 = lane * 2 + 128 * i;
        float xn0 = (v[2 * i]     - mean) * rstd * lng[d0]     + lnb[d0];
        float xn1 = (v[2 * i + 1] - mean) * rstd * lng[d0 + 1] + lnb[d0 + 1];
        union { unsigned u; bf16 h[2]; } pk;
        pk.h[0] = __float2bfloat16(xn0);
        pk.h[1] = __float2bfloat16(xn1);
        *(unsigned*)&xb[d0] = pk.u;
        float4 a = *(const float4*)&srw[d0 * 4];
        float4 b = *(const float4*)&srw[d0 * 4 + 4];
        acc[0] += xn0 * a.x + xn1 * b.x;
        acc[1] += xn0 * a.y + xn1 * b.y;
        acc[2] += xn0 * a.z + xn1 * b.z;
        acc[3] += xn0 * a.w + xn1 * b.w;
        float4 sw = *(const float4*)&shw[d0 * 2];
        acc[4] += xn0 * sw.x + xn1 * sw.z;
        acc[5] += xn0 * sw.y + xn1 * sw.w;
    }
    #pragma unroll
    for (int j = 0; j < 6; ++j) {
        #pragma unroll
        for (int o = 32; o > 0; o >>= 1) acc[j] += __shfl_xor(acc[j], o, 64);
    }
    if (lane == 0) {
        float l[4];
        #pragma unroll
        for (int j = 0; j < 4; ++j) l[j] = acc[j] + srb[j];
        float m = fmaxf(fmaxf(l[0], l[1]), fmaxf(l[2], l[3]));
        float e[4], ssum = 0.0f;
        #pragma unroll
        for (int j = 0; j < 4; ++j) { e[j] = expf(l[j] - m); ssum += e[j]; }
        float inv = 1.0f / ssum;
        float p[4];
        #pragma unroll
        for (int j = 0; j < 4; ++j) p[j] = e[j] * inv;
        int i0 = 0;
        for (int j = 1; j < 4; ++j) if (p[j] > p[i0]) i0 = j;
        int i1 = -1;
        for (int j = 0; j < 4; ++j) {
            if (j == i0) continue;
            if (i1 < 0 || p[j] > p[i1]) i1 = j;
        }
        float sl0 = acc[4] + shb[0], sl1 = acc[5] + shb[1];
        float sm = fmaxf(sl0, sl1);
        float se0 = expf(sl0 - sm), se1 = expf(sl1 - sm);
        float sinv = 1.0f / (se0 + se1);
        float sp0 = se0 * sinv, sp1 = se1 * sinv;

        #pragma unroll
        for (int j = 0; j < 4; ++j) {
            spec_logits[t * 4 + j] = l[j];
            spec_probs[t * 4 + j]  = p[j];
        }
        topk_idx[t * 2 + 0]   = (float)i0;
        topk_idx[t * 2 + 1]   = (float)i1;
        topk_probs[t * 2 + 0] = p[i0];
        topk_probs[t * 2 + 1] = p[i1];
        sh_logits[t * 2 + 0]  = sl0;
        sh_logits[t * 2 + 1]  = sl1;
        sh_probs[t * 2 + 0]   = sp0;
        sh_probs[t * 2 + 1]   = sp1;
        float gg[6] = {0, 0, 0, 0, sp0, sp1};
        gg[i0] = p[i0];
        gg[i1] = p[i1];
        #pragma unroll
        for (int j = 0; j < 6; ++j) gates[t * 6 + j] = gg[j];
        int c0 = i0 * NBKT + bucket;
        int pos0 = atomicAdd(&cnt2[c0], 1);
        tok2[c0 * BKTCAP + pos0]  = t * 2 + 0;
        gate2[c0 * BKTCAP + pos0] = p[i0];
        int c1 = i1 * NBKT + bucket;
        int pos1 = atomicAdd(&cnt2[c1], 1);
        tok2[c1 * BKTCAP + pos1]  = t * 2 + 1;
        gate2[c1 * BKTCAP + pos1] = p[i1];
    }
}

// ---------------------------------------------------------------- plan: bucket scan, 256-row padded compact
__global__ void plan_kernel(const int* __restrict__ cnt2, int* __restrict__ e_of_tile,
                            const int* __restrict__ tok2, const float* __restrict__ gate2,
                            int* __restrict__ slot_tok, float* __restrict__ slot_gate,
                            int* __restrict__ back) {
    __shared__ int sbase[4 * NBKT];
    __shared__ int offsE[5];
    __shared__ int etot[4];
    int tid = threadIdx.x, lane = tid & 63, wid = tid >> 6;
    int c = cnt2[wid * NBKT + lane];
    int inc = c;
    #pragma unroll
    for (int o = 1; o < 64; o <<= 1) {
        int tv = __shfl_up(inc, o, 64);
        if (lane >= o) inc += tv;
    }
    int exc = inc - c;
    if (lane == 63) etot[wid] = inc;
    __syncthreads();
    if (tid == 0) {
        int o = 0;
        for (int e = 0; e < 4; ++e) { offsE[e] = o; o += (etot[e] + 255) & ~255; }
        offsE[4] = o;
    }
    __syncthreads();
    sbase[tid] = offsE[wid] + exc;
    for (int idx = tid; idx < NTILE_MAX; idx += 256) {
        int s0 = idx * 256, e = -1;
        for (int j = 0; j < 4; ++j)
            if (s0 >= offsE[j] && s0 < offsE[j + 1]) e = j;
        e_of_tile[idx] = e;
    }
    __syncthreads();
    int bs = sbase[tid];
    int cc = cnt2[tid];
    for (int i = 0; i < cc; ++i) {
        int gs = bs + i;
        int tk = tok2[tid * BKTCAP + i];
        slot_tok[gs] = tk >> 1;
        slot_gate[gs] = gate2[tid * BKTCAP + i];
        back[tk] = gs;
    }
}

// ================================================================ 256x256 8-phase MFMA GEMM core
// LDS (bytes): A(buf,ks) at buf*32768 + ks*16384; B at 65536 + same. Each region
// [256 rows][32 k] bf16, 64B rows, double-XOR swizzled:
//   phys = log ^ ((log>>8)&1)<<4 ^ ((log>>9)&1)<<5   (involution, 16B-chunk aligned)
// Staging: global_load_lds writes LINEARLY; lane fetches the global data whose
// logical chunk L = P ^ ((P>>4)&1) ^ (((P>>5)&1)<<1) so swizzled reads see linear data.

__device__ __forceinline__ int swz(int off) {
    return off ^ (((off >> 8) & 1) << 4) ^ (((off >> 9) & 1) << 5);
}

__device__ __forceinline__ void stage2(bf16* lds, int base_elems, int wid,
                                       const bf16* s0, const bf16* s1) {
    __builtin_amdgcn_global_load_lds(GPTR(s0), LDSPTR(lds + base_elems + wid * 512), 16, 0, 0);
    __builtin_amdgcn_global_load_lds(GPTR(s1), LDSPTR(lds + base_elems + 4096 + wid * 512), 16, 0, 0);
}

__device__ __forceinline__ void read_a4(const bf16* lds, int buf, int ks, int wm, int mh,
                                        int lane, short8v a[4]) {
    const char* base = (const char*)lds + buf * 32768 + ks * 16384;
    #pragma unroll
    for (int i = 0; i < 4; ++i) {
        int off = (wm * 128 + mh * 64 + i * 16 + (lane & 15)) * 64 + ((lane >> 4) * 16);
        a[i] = *(const short8v*)(base + swz(off));
    }
}

__device__ __forceinline__ void read_b4(const bf16* lds, int buf, int ks, int wn,
                                        int lane, short8v b[4]) {
    const char* base = (const char*)lds + 65536 + buf * 32768 + ks * 16384;
    #pragma unroll
    for (int j = 0; j < 4; ++j) {
        int off = (wn * 64 + j * 16 + (lane & 15)) * 64 + ((lane >> 4) * 16);
        b[j] = *(const short8v*)(base + swz(off));
    }
}

__device__ __forceinline__ void mfma16(const short8v a[4], const short8v b[4], f32x4 (*am)[4]) {
    #pragma unroll
    for (int i = 0; i < 4; ++i)
        #pragma unroll
        for (int j = 0; j < 4; ++j)
            am[i][j] = __builtin_amdgcn_mfma_f32_16x16x32_bf16(a[i], b[j], am[i][j], 0, 0, 0);
}

#define BARRIER() __builtin_amdgcn_s_barrier()
#define VMCNT4() asm volatile("s_waitcnt vmcnt(4)" ::: "memory")
#define VMCNT0() asm volatile("s_waitcnt vmcnt(0)" ::: "memory")

template<int NT>
__device__ __forceinline__ void kloop8p(bf16* lds, const bf16* a0, const bf16* a1,
                                        const bf16* b0, const bf16* b1,
                                        int wm, int wn, int wid, int lane,
                                        f32x4 acc[8][4]) {
    // prologue: stage K-tile 0 (order: A_k0, B_k0, A_k1, B_k1)
    stage2(lds, 0, wid, a0, a1);
    stage2(lds, 32768, wid, b0, b1);
    stage2(lds, 8192, wid, a0 + 32, a1 + 32);
    stage2(lds, 32768 + 8192, wid, b0 + 32, b1 + 32);
    VMCNT4();        // A_k0,B_k0 of tile 0 landed
    BARRIER();
    for (int t = 0; t < NT; ++t) {
        int buf = t & 1, nb = buf ^ 1;
        bool pre = (t + 1 < NT);
        short8v af[4], bfv[4];
        // ---- P0: ks=0, mh=0 ; stage A_k0(t+1)
        if (pre) stage2(lds, nb * 16384, wid, a0 + (t + 1) * 64, a1 + (t + 1) * 64);
        read_a4(lds, buf, 0, wm, 0, lane, af);
        read_b4(lds, buf, 0, wn, lane, bfv);
        BARRIER();
        __builtin_amdgcn_s_setprio(1);
        mfma16(af, bfv, &acc[0]);
        __builtin_amdgcn_s_setprio(0);
        BARRIER();
        // ---- P1: ks=0, mh=1 ; stage B_k0(t+1)
        if (pre) stage2(lds, 32768 + nb * 16384, wid, b0 + (t + 1) * 64, b1 + (t + 1) * 64);
        read_a4(lds, buf, 0, wm, 1, lane, af);
        BARRIER();
        __builtin_amdgcn_s_setprio(1);
        mfma16(af, bfv, &acc[4]);
        __builtin_amdgcn_s_setprio(0);
        if (pre) VMCNT4(); else VMCNT0();   // A_k1,B_k1(t) landed
        BARRIER();
        // ---- P2: ks=1, mh=0 ; stage A_k1(t+1)
        if (pre) stage2(lds, nb * 16384 + 8192, wid, a0 + (t + 1) * 64 + 32, a1 + (t + 1) * 64 + 32);
        read_a4(lds, buf, 1, wm, 0, lane, af);
        read_b4(lds, buf, 1, wn, lane, bfv);
        BARRIER();
        __builtin_amdgcn_s_setprio(1);
        mfma16(af, bfv, &acc[0]);
        __builtin_amdgcn_s_setprio(0);
        BARRIER();
        // ---- P3: ks=1, mh=1 ; stage B_k1(t+1)
        if (pre) stage2(lds, 32768 + nb * 16384 + 8192, wid, b0 + (t + 1) * 64 + 32, b1 + (t + 1) * 64 + 32);
        read_a4(lds, buf, 1, wm, 1, lane, af);
        BARRIER();
        __builtin_amdgcn_s_setprio(1);
        mfma16(af, bfv, &acc[4]);
        __builtin_amdgcn_s_setprio(0);
        if (pre) VMCNT4();                  // A_k0,B_k0(t+1) landed
        BARRIER();
    }
}

__device__ __forceinline__ float gelu_exact(float v) {
    return 0.5f * v * (1.0f + erff(v * 0.70710678118654752f));
}

// ---------------------------------------------------------------- GEMM1 8-phase: xn -> gelu(H), 256-tile chunks
__global__ __launch_bounds__(512, 2) void gemm1_8p(
    const bf16* __restrict__ xnb, const bf16* __restrict__ w1t,
    const float* __restrict__ spec_b1, const float* __restrict__ sh_b1,
    const int* __restrict__ e_of_tile, const int* __restrict__ slot_tok,
    bf16* __restrict__ Hbuf, int y_base) {
    extern __shared__ bf16 lds[];
    int y = blockIdx.y + y_base;
    int tid = threadIdx.x, wid = tid >> 6, lane = tid & 63;
    int wm = wid >> 2, wn = wid & 3;
    int P0c = tid, P1c = 512 + tid;
    int L0 = P0c ^ ((P0c >> 4) & 1) ^ (((P0c >> 5) & 1) << 1);
    int L1 = P1c ^ ((P1c >> 4) & 1) ^ (((P1c >> 5) & 1) << 1);
    int r0 = L0 >> 2, c0 = (L0 & 3) * 8;
    int r1 = L1 >> 2, c1 = (L1 & 3) * 8;

    const bf16 *a0, *a1, *Bw;
    const float* bias;
    if (y < NTILE_MAX) {
        int e = e_of_tile[y];
        if (e < 0) return;
        a0 = xnb + (size_t)slot_tok[y * 256 + r0] * DIM + c0;
        a1 = xnb + (size_t)slot_tok[y * 256 + r1] * DIM + c1;
        Bw = w1t + (size_t)e * HID * DIM;
        bias = spec_b1 + (size_t)e * HID;
    } else {
        int ys = y - NTILE_MAX;
        int z = ys / NSDT, ry = ys % NSDT;
        a0 = xnb + (size_t)(ry * 256 + r0) * DIM + c0;
        a1 = xnb + (size_t)(ry * 256 + r1) * DIM + c1;
        Bw = w1t + (size_t)(4 + z) * HID * DIM;
        bias = sh_b1 + (size_t)z * HID;
    }
    const bf16* b0 = Bw + (size_t)(blockIdx.x * 256 + r0) * DIM + c0;
    const bf16* b1 = Bw + (size_t)(blockIdx.x * 256 + r1) * DIM + c1;

    f32x4 acc[8][4] = {};
    kloop8p<DIM / 64>(lds, a0, a1, b0, b1, wm, wn, wid, lane, acc);

    bf16* hb = Hbuf + (size_t)blockIdx.y * 256 * HID;
    int fr = lane & 15, fq = lane >> 4;
    int cb = blockIdx.x * 256 + wn * 64;
    #pragma unroll
    for (int j = 0; j < 4; ++j) {
        int col = cb + j * 16 + fr;
        float bv = bias[col];
        #pragma unroll
        for (int ii = 0; ii < 8; ++ii) {
            #pragma unroll
            for (int rr = 0; rr < 4; ++rr) {
                int row = wm * 128 + (ii >> 2) * 64 + (ii & 3) * 16 + fq * 4 + rr;
                hb[(size_t)row * HID + col] = __float2bfloat16(gelu_exact(acc[ii][j][rr] + bv));
            }
        }
    }
}

// ---------------------------------------------------------------- GEMM2 8-phase: H -> gated bf16 partials
__global__ __launch_bounds__(512, 2) void gemm2_8p(
    const bf16* __restrict__ Hbuf, const bf16* __restrict__ w2t,
    const float* __restrict__ spec_b2, const float* __restrict__ sh_b2,
    const int* __restrict__ e_of_tile, const float* __restrict__ slot_gate,
    const float* __restrict__ sh_probs,
    bf16* __restrict__ spec_g, bf16* __restrict__ shg, int y_base) {
    extern __shared__ bf16 lds[];
    int y = blockIdx.y + y_base;
    int tid = threadIdx.x, wid = tid >> 6, lane = tid & 63;
    int wm = wid >> 2, wn = wid & 3;
    int P0c = tid, P1c = 512 + tid;
    int L0 = P0c ^ ((P0c >> 4) & 1) ^ (((P0c >> 5) & 1) << 1);
    int L1 = P1c ^ ((P1c >> 4) & 1) ^ (((P1c >> 5) & 1) << 1);
    int r0 = L0 >> 2, c0 = (L0 & 3) * 8;
    int r1 = L1 >> 2, c1 = (L1 & 3) * 8;

    const bf16 *Bw;
    const float* bias;
    bf16* obase;
    bool grouped = (y < NTILE_MAX);
    int z = 0, ry = 0;
    if (grouped) {
        int e = e_of_tile[y];
        if (e < 0) return;
        Bw = w2t + (size_t)e * DIM * HID;
        bias = spec_b2 + (size_t)e * DIM;
        obase = spec_g + (size_t)y * 256 * DIM;
    } else {
        int ys = y - NTILE_MAX;
        z = ys / NSDT; ry = ys % NSDT;
        Bw = w2t + (size_t)(4 + z) * DIM * HID;
        bias = sh_b2 + (size_t)z * DIM;
        obase = shg + (size_t)(z * NTOK + ry * 256) * DIM;
    }
    const bf16* Ah = Hbuf + (size_t)blockIdx.y * 256 * HID;
    const bf16* a0 = Ah + (size_t)r0 * HID + c0;
    const bf16* a1 = Ah + (size_t)r1 * HID + c1;
    const bf16* b0 = Bw + (size_t)(blockIdx.x * 256 + r0) * HID + c0;
    const bf16* b1 = Bw + (size_t)(blockIdx.x * 256 + r1) * HID + c1;

    f32x4 acc[8][4] = {};
    kloop8p<HID / 64>(lds, a0, a1, b0, b1, wm, wn, wid, lane, acc);

    int fr = lane & 15, fq = lane >> 4;
    int cb = blockIdx.x * 256 + wn * 64;
    #pragma unroll
    for (int j = 0; j < 4; ++j) {
        int col = cb + j * 16 + fr;
        float bv = bias[col];
        #pragma unroll
        for (int ii = 0; ii < 8; ++ii) {
            #pragma unroll
            for (int rr = 0; rr < 4; ++rr) {
                int row = wm * 128 + (ii >> 2) * 64 + (ii & 3) * 16 + fq * 4 + rr;
                float g = grouped ? slot_gate[y * 256 + row]
                                  : sh_probs[(size_t)(ry * 256 + row) * 2 + z];
                obase[(size_t)row * DIM + col] = __float2bfloat16(g * (acc[ii][j][rr] + bv));
            }
        }
    }
}

// ---------------------------------------------------------------- plan-B dense fallback (128^2 m97, known-good)
__device__ __forceinline__ void stage_tile(const bf16* __restrict__ g, int ldg,
                                           bf16* lds, int tid) {
    int wave = tid >> 6, lane = tid & 63;
    #pragma unroll
    for (int q = 0; q < 2; ++q) {
        int chunk = wave * 2 + q;
        int row = chunk * 16 + (lane >> 2);
        int col = (lane & 3) * 8;
        __builtin_amdgcn_global_load_lds(GPTR(g + (size_t)row * ldg + col),
                                         LDSPTR(lds + chunk * 512), 16, 0, 0);
    }
}

__device__ __forceinline__ void mfma_step(const bf16* As, const bf16* Bs,
                                          int wr, int wc, int fr, int fq, f32x4 acc[4][4]) {
    short8v a[4], b[4];
    #pragma unroll
    for (int i = 0; i < 4; ++i) {
        a[i] = *(const short8v*)&As[(wr * 64 + i * 16 + fr) * 32 + fq * 8];
        b[i] = *(const short8v*)&Bs[(wc * 64 + i * 16 + fr) * 32 + fq * 8];
    }
    #pragma unroll
    for (int i = 0; i < 4; ++i)
        #pragma unroll
        for (int j = 0; j < 4; ++j)
            acc[i][j] = __builtin_amdgcn_mfma_f32_16x16x32_bf16(a[i], b[j], acc[i][j], 0, 0, 0);
}

__global__ __launch_bounds__(256) void gemm1_dense(
    const bf16* __restrict__ A, const bf16* __restrict__ BT,
    const float* __restrict__ bias, bf16* __restrict__ H) {
    __shared__ bf16 As[128 * 32];
    __shared__ bf16 Bs[128 * 32];
    int tid = threadIdx.x;
    int wid = tid >> 6, lane = tid & 63;
    int wr = wid >> 1, wc = wid & 1;
    int fr = lane & 15, fq = lane >> 4;
    const bf16* Ag = A + (size_t)(blockIdx.y * 128) * DIM;
    const bf16* Bg = BT + (size_t)(blockIdx.x * 128) * DIM;
    f32x4 acc[4][4] = {};
    for (int k0 = 0; k0 < DIM; k0 += 32) {
        stage_tile(Ag + k0, DIM, As, tid);
        stage_tile(Bg + k0, DIM, Bs, tid);
        __syncthreads();
        mfma_step(As, Bs, wr, wc, fr, fq, acc);
        __syncthreads();
    }
    int rbase = blockIdx.y * 128 + wr * 64;
    int cbase = blockIdx.x * 128 + wc * 64;
    #pragma unroll
    for (int j = 0; j < 4; ++j) {
        int col = cbase + j * 16 + fr;
        float bv = bias[col];
        #pragma unroll
        for (int i = 0; i < 4; ++i)
            #pragma unroll
            for (int r = 0; r < 4; ++r) {
                int row = rbase + i * 16 + fq * 4 + r;
                H[(size_t)row * HID + col] = __float2bfloat16(gelu_exact(acc[i][j][r] + bv));
            }
    }
}

__global__ __launch_bounds__(256) void gemm2_dense_out(
    const bf16* __restrict__ A, const bf16* __restrict__ BT,
    const float* __restrict__ bias, const float* __restrict__ gates,
    float* __restrict__ out, int gidx, int accum) {
    __shared__ bf16 As[128 * 32];
    __shared__ bf16 Bs[128 * 32];
    int tid = threadIdx.x;
    int wid = tid >> 6, lane = tid & 63;
    int wr = wid >> 1, wc = wid & 1;
    int fr = lane & 15, fq = lane >> 4;
    const bf16* Ag = A + (size_t)(blockIdx.y * 128) * HID;
    const bf16* Bg = BT + (size_t)(blockIdx.x * 128) * HID;
    f32x4 acc[4][4] = {};
    for (int k0 = 0; k0 < HID; k0 += 32) {
        stage_tile(Ag + k0, HID, As, tid);
        stage_tile(Bg + k0, HID, Bs, tid);
        __syncthreads();
        mfma_step(As, Bs, wr, wc, fr, fq, acc);
        __syncthreads();
    }
    int rbase = blockIdx.y * 128 + wr * 64;
    int cbase = blockIdx.x * 128 + wc * 64;
    #pragma unroll
    for (int j = 0; j < 4; ++j) {
        int col = cbase + j * 16 + fr;
        float bv = bias[col];
        #pragma unroll
        for (int i = 0; i < 4; ++i)
            #pragma unroll
            for (int r = 0; r < 4; ++r) {
                int row = rbase + i * 16 + fq * 4 + r;
                float g = gates[(size_t)row * 6 + gidx];
                float v = g * (acc[i][j][r] + bv);
                size_t idx = (size_t)row * DIM + col;
                out[idx] = accum ? out[idx] + v : v;
            }
    }
}

// ---------------------------------------------------------------- combine
__global__ void combine_kernel(const bf16* __restrict__ spec_g, const bf16* __restrict__ shg,
                               const int* __restrict__ back, float* __restrict__ out) {
    int idx = blockIdx.x * 256 + threadIdx.x;
    int tok = idx / 96;
    int c = (idx % 96) * 8;
    int b0 = back[2 * tok], b1 = back[2 * tok + 1];
    short8v q0 = *(const short8v*)&spec_g[(size_t)b0 * DIM + c];
    short8v q1 = *(const short8v*)&spec_g[(size_t)b1 * DIM + c];
    short8v s0 = *(const short8v*)&shg[(size_t)tok * DIM + c];
    short8v s1 = *(const short8v*)&shg[(size_t)(NTOK + tok) * DIM + c];
    float o[8];
    #pragma unroll
    for (int k = 0; k < 8; ++k) {
        float f0 = __uint_as_float((unsigned)(unsigned short)q0[k] << 16);
        float f1 = __uint_as_float((unsigned)(unsigned short)q1[k] << 16);
        float f2 = __uint_as_float((unsigned)(unsigned short)s0[k] << 16);
        float f3 = __uint_as_float((unsigned)(unsigned short)s1[k] << 16);
        o[k] = f0 + f1 + f2 + f3;
    }
    float* op = out + (size_t)tok * DIM + c;
    *(float4*)(op)     = *(const float4*)(o);
    *(float4*)(op + 4) = *(const float4*)(o + 4);
}

// ---------------------------------------------------------------- launch
static inline size_t align256(size_t x) { return (x + 255) & ~(size_t)255; }

extern "C" void kernel_launch(void* const* d_in, const int* in_sizes, int n_in,
                              void* d_out, int out_size, void* d_ws, size_t ws_size,
                              hipStream_t stream) {
    const float* x      = (const float*)d_in[0];
    const float* gamma  = (const float*)d_in[1];
    const float* beta   = (const float*)d_in[2];
    const float* srw    = (const float*)d_in[3];
    const float* srb    = (const float*)d_in[4];
    const float* spec_w1 = (const float*)d_in[5];
    const float* spec_b1 = (const float*)d_in[6];
    const float* spec_w2 = (const float*)d_in[7];
    const float* spec_b2 = (const float*)d_in[8];
    const float* shw    = (const float*)d_in[9];
    const float* shb    = (const float*)d_in[10];
    const float* sh_w1  = (const float*)d_in[11];
    const float* sh_b1  = (const float*)d_in[12];
    const float* sh_w2  = (const float*)d_in[13];
    const float* sh_b2  = (const float*)d_in[14];

    char* p = (char*)d_ws;
    size_t off = 0;
    bf16* xnb = (bf16*)(p + off);       off = align256(off + (size_t)NTOK * DIM * 2);
    bf16* w1t = (bf16*)(p + off);       off = align256(off + (size_t)6 * HID * DIM * 2);
    bf16* w2t = (bf16*)(p + off);       off = align256(off + (size_t)6 * DIM * HID * 2);
    int*  cnt2 = (int*)(p + off);       off = align256(off + (size_t)4 * NBKT * 4);
    float* gates = (float*)(p + off);   off = align256(off + (size_t)NTOK * 6 * 4);
    int*  tok2 = (int*)(p + off);       off = align256(off + (size_t)4 * NBKT * BKTCAP * 4);
    float* gate2 = (float*)(p + off);   off = align256(off + (size_t)4 * NBKT * BKTCAP * 4);
    int*  slot_tok = (int*)(p + off);   off = align256(off + (size_t)NSLOT_MAX * 4);
    float* slot_gate = (float*)(p + off); off = align256(off + (size_t)NSLOT_MAX * 4);
    int*  back = (int*)(p + off);       off = align256(off + (size_t)2 * NTOK * 4);
    int*  e_of_tile = (int*)(p + off);  off = align256(off + (size_t)NTILE_MAX * 4);
    bf16* spec_g = (bf16*)(p + off);    off = align256(off + (size_t)NSLOT_MAX * DIM * 2);
    bf16* shg   = (bf16*)(p + off);     off = align256(off + (size_t)2 * NTOK * DIM * 2);
    size_t fixed_end = off;
    bf16* Hbuf = (bf16*)(p + fixed_end);

    const size_t tile_bytes = (size_t)256 * HID * 2;   // 1.57 MB per 256-row tile
    size_t avail = (ws_size > fixed_end) ? (ws_size - fixed_end) : 0;
    int tcap = (int)(avail / tile_bytes);
    if (tcap > NVT) tcap = NVT;

    float* out         = (float*)d_out;
    float* spec_logits = out + (size_t)NTOK * DIM;
    float* spec_probs  = spec_logits + (size_t)NTOK * 4;
    float* topk_idx    = spec_probs  + (size_t)NTOK * 4;
    float* topk_probs  = topk_idx    + (size_t)NTOK * 2;
    float* sh_logits   = topk_probs  + (size_t)NTOK * 2;
    float* sh_probs    = sh_logits   + (size_t)NTOK * 2;

    conv_all_kernel<<<dim3(576, 12), 256, 0, stream>>>(
        spec_w1, sh_w1, spec_w2, sh_w2, w1t, w2t, cnt2, slot_tok, slot_gate);

    router_ln_kernel<<<NTOK / 4, 256, 0, stream>>>(x, gamma, beta, srw, srb, shw, shb, xnb,
                                                   spec_logits, spec_probs, topk_idx,
                                                   topk_probs, sh_logits, sh_probs, gates,
                                                   cnt2, tok2, gate2);

    if (tcap >= 16) {
        plan_kernel<<<1, 256, 0, stream>>>(cnt2, e_of_tile, tok2, gate2,
                                           slot_tok, slot_gate, back);
        for (int c0 = 0; c0 < NVT; c0 += tcap) {
            int n = NVT - c0 < tcap ? NVT - c0 : tcap;
            gemm1_8p<<<dim3(HID / 256, n), 512, LDSB, stream>>>(
                xnb, w1t, spec_b1, sh_b1, e_of_tile, slot_tok, Hbuf, c0);
            gemm2_8p<<<dim3(DIM / 256, n), 512, LDSB, stream>>>(
                Hbuf, w2t, spec_b2, sh_b2, e_of_tile, slot_gate, sh_probs,
                spec_g, shg, c0);
        }
        combine_kernel<<<NTOK * 96 / 256, 256, 0, stream>>>(spec_g, shg, back, out);
    } else {
        // plan B: dense 6-expert loop (reuses spec_g/shg region as H)
        bf16* HB = spec_g;
        for (int e = 0; e < 6; ++e) {
            const bf16* w1p = w1t + (size_t)e * HID * DIM;
            const bf16* w2p = w2t + (size_t)e * DIM * HID;
            const float* b1p = (e < 4) ? spec_b1 + (size_t)e * HID : sh_b1 + (size_t)(e - 4) * HID;
            const float* b2p = (e < 4) ? spec_b2 + (size_t)e * DIM : sh_b2 + (size_t)(e - 4) * DIM;
            gemm1_dense<<<dim3(HID / 128, NTOK / 128), 256, 0, stream>>>(xnb, w1p, b1p, HB);
            gemm2_dense_out<<<dim3(DIM / 128, NTOK / 128), 256, 0, stream>>>(
                HB, w2p, b2p, gates, out, e, e > 0);
        }
    }
}